// Round 1
// baseline (1125.382 us; speedup 1.0000x reference)
//
#include <hip/hip_runtime.h>
#include <math.h>

#define B_   2
#define S_   2048
#define H_   16
#define DH_  64
#define D_   1024
#define OUT_ 1024
#define M_   (B_ * S_)   // 4096

// ---------------------------------------------------------------------------
// f32 GEMM: C[M,N] = A[M,K] @ W[K,N] + bias[N]
// 64x64 tile, 256 threads, 4x4 per thread, K-step 16. LDS stride 68 keeps
// float4 (16B) alignment while breaking power-of-2 bank strides.
// ---------------------------------------------------------------------------
__global__ __launch_bounds__(256)
void gemm_f32(const float* __restrict__ A, const float* __restrict__ W,
              const float* __restrict__ bias, float* __restrict__ C,
              int M, int K, int N)
{
    const int tid = threadIdx.x;
    const int tx = tid & 15, ty = tid >> 4;
    const int m0 = blockIdx.x * 64, n0 = blockIdx.y * 64;

    __shared__ float As[16][68];   // [k][m]
    __shared__ float Bs[16][68];   // [k][n]

    float acc[4][4] = {};

    for (int kt = 0; kt < K; kt += 16) {
        __syncthreads();
        {   // A tile 64 rows x 16 k, transposed into As[k][m]
            const int r = tid >> 2, c = (tid & 3) * 4;
            const float4 a = *(const float4*)&A[(size_t)(m0 + r) * K + kt + c];
            As[c + 0][r] = a.x; As[c + 1][r] = a.y;
            As[c + 2][r] = a.z; As[c + 3][r] = a.w;
        }
        {   // W tile 16 k x 64 n, direct into Bs[k][n]
            const int r = tid >> 4, c = (tid & 15) * 4;
            *(float4*)&Bs[r][c] = *(const float4*)&W[(size_t)(kt + r) * N + n0 + c];
        }
        __syncthreads();

        #pragma unroll
        for (int kk = 0; kk < 16; ++kk) {
            const float4 a4 = *(const float4*)&As[kk][ty * 4];
            const float4 b4 = *(const float4*)&Bs[kk][tx * 4];
            const float av[4] = {a4.x, a4.y, a4.z, a4.w};
            const float bv[4] = {b4.x, b4.y, b4.z, b4.w};
            #pragma unroll
            for (int i = 0; i < 4; ++i)
                #pragma unroll
                for (int j = 0; j < 4; ++j)
                    acc[i][j] = fmaf(av[i], bv[j], acc[i][j]);
        }
    }

    #pragma unroll
    for (int i = 0; i < 4; ++i) {
        const int m = m0 + ty * 4 + i;
        const int n = n0 + tx * 4;
        float4 o;
        o.x = acc[i][0] + bias[n + 0];
        o.y = acc[i][1] + bias[n + 1];
        o.z = acc[i][2] + bias[n + 2];
        o.w = acc[i][3] + bias[n + 3];
        *(float4*)&C[(size_t)m * N + n] = o;
    }
}

// ---------------------------------------------------------------------------
// Flash-style masked attention, f32.
// Grid: (B*H, S/64). Block: 256 threads = 16x16, 4x4 register tiles.
// Q,K,V are [B,S,D] row-major (head h occupies cols h*64..h*64+63).
// msgs out: [B,S,D] row-major.
// ---------------------------------------------------------------------------
__global__ __launch_bounds__(256)
void attn_f32(const float* __restrict__ Q, const float* __restrict__ Km,
              const float* __restrict__ V, const float* __restrict__ mask,
              float* __restrict__ msgs)
{
    const int tid = threadIdx.x;
    const int tx = tid & 15, ty = tid >> 4;
    const int bh = blockIdx.x;           // b*H + h
    const int b = bh >> 4, h = bh & 15;
    const int q0 = blockIdx.y * 64;

    __shared__ float Qs[64][68];  // [d][q]
    __shared__ float Ks[64][68];  // [d][k]
    __shared__ float Vs[64][68];  // [k][d]
    __shared__ float Ws[64][68];  // [k][q]
    __shared__ float mq[64], mk[64];

    // Q tile (64 q-rows x 64 d), transposed into Qs[d][q]
    for (int t = tid; t < 1024; t += 256) {
        const int r = t >> 4, c = (t & 15) * 4;
        const float4 qv = *(const float4*)&Q[((size_t)b * S_ + q0 + r) * D_ + h * DH_ + c];
        Qs[c + 0][r] = qv.x; Qs[c + 1][r] = qv.y;
        Qs[c + 2][r] = qv.z; Qs[c + 3][r] = qv.w;
    }
    if (tid < 64) mq[tid] = mask[(size_t)b * S_ + q0 + tid];

    float m_i[4], l_i[4], O[4][4] = {};
    #pragma unroll
    for (int i = 0; i < 4; ++i) { m_i[i] = -1e30f; l_i[i] = 0.f; }

    for (int kt = 0; kt < S_; kt += 64) {
        __syncthreads();   // previous iteration done with Ks/Vs/Ws/mk
        for (int t = tid; t < 1024; t += 256) {
            const int r = t >> 4, c = (t & 15) * 4;
            const float4 kv = *(const float4*)&Km[((size_t)b * S_ + kt + r) * D_ + h * DH_ + c];
            Ks[c + 0][r] = kv.x; Ks[c + 1][r] = kv.y;
            Ks[c + 2][r] = kv.z; Ks[c + 3][r] = kv.w;
            *(float4*)&Vs[r][c] = *(const float4*)&V[((size_t)b * S_ + kt + r) * D_ + h * DH_ + c];
        }
        if (tid < 64) mk[tid] = mask[(size_t)b * S_ + kt + tid];
        __syncthreads();

        // scores s[i][j] = sum_d Q[q0+ty*4+i][d] * K[kt+tx*4+j][d]
        float s[4][4] = {};
        #pragma unroll 8
        for (int d = 0; d < 64; ++d) {
            const float4 a4 = *(const float4*)&Qs[d][ty * 4];
            const float4 b4 = *(const float4*)&Ks[d][tx * 4];
            const float av[4] = {a4.x, a4.y, a4.z, a4.w};
            const float bv[4] = {b4.x, b4.y, b4.z, b4.w};
            #pragma unroll
            for (int i = 0; i < 4; ++i)
                #pragma unroll
                for (int j = 0; j < 4; ++j)
                    s[i][j] = fmaf(av[i], bv[j], s[i][j]);
        }

        float mqv[4], mkv[4];
        #pragma unroll
        for (int i = 0; i < 4; ++i) mqv[i] = mq[ty * 4 + i];
        #pragma unroll
        for (int j = 0; j < 4; ++j) mkv[j] = mk[tx * 4 + j];

        // mask + scale + online softmax update (row = q, reduce over tx lanes)
        #pragma unroll
        for (int i = 0; i < 4; ++i) {
            float rm = -1e30f;
            #pragma unroll
            for (int j = 0; j < 4; ++j) {
                const bool valid = (mqv[i] != 0.f) && (mkv[j] != 0.f);
                const float sv = valid ? s[i][j] * 0.125f : -1e30f;
                s[i][j] = sv;
                rm = fmaxf(rm, sv);
            }
            rm = fmaxf(rm, __shfl_xor(rm, 1));
            rm = fmaxf(rm, __shfl_xor(rm, 2));
            rm = fmaxf(rm, __shfl_xor(rm, 4));
            rm = fmaxf(rm, __shfl_xor(rm, 8));
            const float mnew = fmaxf(m_i[i], rm);
            const float sc = expf(m_i[i] - mnew);
            float rs = 0.f;
            #pragma unroll
            for (int j = 0; j < 4; ++j) {
                const float p = (s[i][j] > -1e29f) ? expf(s[i][j] - mnew) : 0.f;
                s[i][j] = p;
                rs += p;
            }
            rs += __shfl_xor(rs, 1);
            rs += __shfl_xor(rs, 2);
            rs += __shfl_xor(rs, 4);
            rs += __shfl_xor(rs, 8);
            l_i[i] = l_i[i] * sc + rs;
            m_i[i] = mnew;
            #pragma unroll
            for (int j = 0; j < 4; ++j) O[i][j] *= sc;
        }

        // stage p into Ws[k][q] for the PV GEMM
        #pragma unroll
        for (int i = 0; i < 4; ++i)
            #pragma unroll
            for (int j = 0; j < 4; ++j)
                Ws[tx * 4 + j][ty * 4 + i] = s[i][j];
        __syncthreads();

        // O[i][j] += sum_k Ws[k][q] * Vs[k][d]
        #pragma unroll 8
        for (int k = 0; k < 64; ++k) {
            const float4 a4 = *(const float4*)&Ws[k][ty * 4];
            const float4 b4 = *(const float4*)&Vs[k][tx * 4];
            const float av[4] = {a4.x, a4.y, a4.z, a4.w};
            const float bv[4] = {b4.x, b4.y, b4.z, b4.w};
            #pragma unroll
            for (int i = 0; i < 4; ++i)
                #pragma unroll
                for (int j = 0; j < 4; ++j)
                    O[i][j] = fmaf(av[i], bv[j], O[i][j]);
        }
    }

    // epilogue: msgs[b, q, h*64 + d] = O / l  (0 for masked q rows)
    #pragma unroll
    for (int i = 0; i < 4; ++i) {
        const int qr = q0 + ty * 4 + i;
        const float inv = (mq[ty * 4 + i] != 0.f && l_i[i] > 0.f) ? 1.f / l_i[i] : 0.f;
        float4 o;
        o.x = O[i][0] * inv; o.y = O[i][1] * inv;
        o.z = O[i][2] * inv; o.w = O[i][3] * inv;
        *(float4*)&msgs[((size_t)b * S_ + qr) * D_ + h * DH_ + tx * 4] = o;
    }
}

// ---------------------------------------------------------------------------
extern "C" void kernel_launch(void* const* d_in, const int* in_sizes, int n_in,
                              void* d_out, int out_size, void* d_ws, size_t ws_size,
                              hipStream_t stream)
{
    const float* x    = (const float*)d_in[0];
    const float* mask = (const float*)d_in[1];
    const float* Wq   = (const float*)d_in[2];
    const float* bq   = (const float*)d_in[3];
    const float* Wk   = (const float*)d_in[4];
    const float* bk   = (const float*)d_in[5];
    const float* Wv   = (const float*)d_in[6];
    const float* bv   = (const float*)d_in[7];
    const float* Wo   = (const float*)d_in[8];
    const float* bo   = (const float*)d_in[9];
    float* out = (float*)d_out;

    float* qws = (float*)d_ws;                    // [M, D]
    float* kws = qws + (size_t)M_ * D_;           // [M, D]
    float* vws = kws + (size_t)M_ * D_;           // [M, D]
    float* mws = vws + (size_t)M_ * D_;           // [M, D] msgs

    const dim3 blk(256);
    const dim3 gproj(M_ / 64, D_ / 64);
    gemm_f32<<<gproj, blk, 0, stream>>>(x, Wq, bq, qws, M_, D_, D_);
    gemm_f32<<<gproj, blk, 0, stream>>>(x, Wk, bk, kws, M_, D_, D_);
    gemm_f32<<<gproj, blk, 0, stream>>>(x, Wv, bv, vws, M_, D_, D_);

    attn_f32<<<dim3(B_ * H_, S_ / 64), blk, 0, stream>>>(qws, kws, vws, mask, mws);

    gemm_f32<<<dim3(M_ / 64, OUT_ / 64), blk, 0, stream>>>(mws, Wo, bo, out, M_, D_, OUT_);
}

// Round 2
// 349.416 us; speedup vs baseline: 3.2208x; 3.2208x over previous
//
#include <hip/hip_runtime.h>
#include <math.h>

#define B_   2
#define S_   2048
#define H_   16
#define DH_  64
#define D_   1024
#define OUT_ 1024
#define M_   (B_ * S_)   // 4096

typedef __attribute__((ext_vector_type(8))) short bf16x8;
typedef __attribute__((ext_vector_type(4))) float f32x4;
typedef __attribute__((ext_vector_type(4))) short short4v;

#define MFMA(a, b, c) __builtin_amdgcn_mfma_f32_16x16x32_bf16((a), (b), (c), 0, 0, 0)

// truncation split: x = hi(bf16) + lo(bf16) + O(2^-16 x)
__device__ __forceinline__ void split2(float x, unsigned short& h, unsigned short& l) {
    unsigned u = __float_as_uint(x);
    h = (unsigned short)(u >> 16);
    float lo = x - __uint_as_float(u & 0xFFFF0000u);
    l = (unsigned short)(__float_as_uint(lo) >> 16);
}

__device__ __forceinline__ void split8(const float4 a, const float4 b, bf16x8& h8, bf16x8& l8) {
    unsigned short h[8], l[8];
    split2(a.x, h[0], l[0]); split2(a.y, h[1], l[1]);
    split2(a.z, h[2], l[2]); split2(a.w, h[3], l[3]);
    split2(b.x, h[4], l[4]); split2(b.y, h[5], l[5]);
    split2(b.z, h[6], l[6]); split2(b.w, h[7], l[7]);
    h8 = (bf16x8){(short)h[0],(short)h[1],(short)h[2],(short)h[3],(short)h[4],(short)h[5],(short)h[6],(short)h[7]};
    l8 = (bf16x8){(short)l[0],(short)l[1],(short)l[2],(short)l[3],(short)l[4],(short)l[5],(short)l[6],(short)l[7]};
}

// swizzles: rows of 32 / 64 bf16; chunk(16B) XORed by row bits -> <=2-way banks
#define SWZ32(row, k) (((row) << 5) + (((((k) >> 3) ^ (((row) >> 1) & 3)) << 3) | ((k) & 7)))
#define SWZ64(row, k) (((row) << 6) + (((((k) >> 3) ^ ((row) & 7)) << 3) | ((k) & 7)))

// ---------------------------------------------------------------------------
// transpose + split convert: W[K,N] f32 -> Th/Tl [N,K] bf16
// ---------------------------------------------------------------------------
__global__ __launch_bounds__(256)
void tconv_w(const float* __restrict__ W, unsigned short* __restrict__ Th,
             unsigned short* __restrict__ Tl, int K, int N)
{
    __shared__ float T[64][65];
    const int tid = threadIdx.x;
    const int k0 = blockIdx.x * 64, n0 = blockIdx.y * 64;
    #pragma unroll
    for (int p = 0; p < 4; ++p) {
        const int f = p * 256 + tid;
        const int r = f >> 4, c4 = (f & 15) << 2;
        const float4 v = *(const float4*)&W[(size_t)(k0 + r) * N + n0 + c4];
        T[r][c4] = v.x; T[r][c4 + 1] = v.y; T[r][c4 + 2] = v.z; T[r][c4 + 3] = v.w;
    }
    __syncthreads();
    #pragma unroll
    for (int p = 0; p < 4; ++p) {
        const int f = p * 256 + tid;
        const int r = f >> 4, c4 = (f & 15) << 2;   // r = n row, c4 = k col
        unsigned short h[4], l[4];
        #pragma unroll
        for (int i = 0; i < 4; ++i) split2(T[c4 + i][r], h[i], l[i]);
        *(short4v*)&Th[(size_t)(n0 + r) * K + k0 + c4] =
            (short4v){(short)h[0],(short)h[1],(short)h[2],(short)h[3]};
        *(short4v*)&Tl[(size_t)(n0 + r) * K + k0 + c4] =
            (short4v){(short)l[0],(short)l[1],(short)l[2],(short)l[3]};
    }
}

// ---------------------------------------------------------------------------
// C[M,N] = A[M,K](f32, split on the fly) @ Bt[N,K](pre-split bf16 hi/lo) + bias
// 128x128 tile, 4 waves (2x2), each wave 64x64 via 4x4 16x16x32 MFMA frags.
// ---------------------------------------------------------------------------
__global__ __launch_bounds__(256, 2)
void gemm_asplit(const float* __restrict__ A, const unsigned short* __restrict__ Bh,
                 const unsigned short* __restrict__ Bl, const float* __restrict__ bias,
                 float* __restrict__ C, int M, int K, int N)
{
    __shared__ unsigned short As_h[4096], As_l[4096], Bs_h[4096], Bs_l[4096];
    const int tid = threadIdx.x;
    const int lane = tid & 63;
    const int w = tid >> 6, wm = w >> 1, wn = w & 1;
    const int l15 = lane & 15, l4 = lane >> 4;
    const int m0 = blockIdx.x * 128, n0 = blockIdx.y * 128;

    f32x4 acc[4][4];
    #pragma unroll
    for (int i = 0; i < 4; ++i)
        #pragma unroll
        for (int j = 0; j < 4; ++j) acc[i][j] = (f32x4){0.f, 0.f, 0.f, 0.f};

    for (int kt = 0; kt < K; kt += 32) {
        __syncthreads();
        #pragma unroll
        for (int p = 0; p < 4; ++p) {               // A: 128x32 f32 -> hi/lo
            const int f = p * 256 + tid;
            const int r = f >> 3, c4 = (f & 7) << 2;
            const float4 v = *(const float4*)&A[(size_t)(m0 + r) * K + kt + c4];
            unsigned short h0, h1, h2, h3, l0, l1, l2, l3;
            split2(v.x, h0, l0); split2(v.y, h1, l1);
            split2(v.z, h2, l2); split2(v.w, h3, l3);
            const int idx = SWZ32(r, c4);
            *(short4v*)&As_h[idx] = (short4v){(short)h0,(short)h1,(short)h2,(short)h3};
            *(short4v*)&As_l[idx] = (short4v){(short)l0,(short)l1,(short)l2,(short)l3};
        }
        #pragma unroll
        for (int p = 0; p < 2; ++p) {               // B: 128x32 bf16 hi/lo copy
            const int f = p * 256 + tid;
            const int r = f >> 2, c8 = (f & 3) << 3;
            const int idx = SWZ32(r, c8);
            *(bf16x8*)&Bs_h[idx] = *(const bf16x8*)&Bh[(size_t)(n0 + r) * K + kt + c8];
            *(bf16x8*)&Bs_l[idx] = *(const bf16x8*)&Bl[(size_t)(n0 + r) * K + kt + c8];
        }
        __syncthreads();

        bf16x8 ah[4], al[4], bh[4], bl[4];
        #pragma unroll
        for (int i = 0; i < 4; ++i) {
            const int row = wm * 64 + i * 16 + l15;
            const int idx = SWZ32(row, l4 << 3);
            ah[i] = *(const bf16x8*)&As_h[idx];
            al[i] = *(const bf16x8*)&As_l[idx];
        }
        #pragma unroll
        for (int j = 0; j < 4; ++j) {
            const int row = wn * 64 + j * 16 + l15;
            const int idx = SWZ32(row, l4 << 3);
            bh[j] = *(const bf16x8*)&Bs_h[idx];
            bl[j] = *(const bf16x8*)&Bs_l[idx];
        }
        #pragma unroll
        for (int i = 0; i < 4; ++i)
            #pragma unroll
            for (int j = 0; j < 4; ++j) {
                acc[i][j] = MFMA(ah[i], bh[j], acc[i][j]);
                acc[i][j] = MFMA(ah[i], bl[j], acc[i][j]);
                acc[i][j] = MFMA(al[i], bh[j], acc[i][j]);
            }
    }

    #pragma unroll
    for (int i = 0; i < 4; ++i) {
        const int row = m0 + wm * 64 + i * 16 + l4 * 4;
        #pragma unroll
        for (int j = 0; j < 4; ++j) {
            const int col = n0 + wn * 64 + j * 16 + l15;
            const float bv = bias[col];
            #pragma unroll
            for (int r = 0; r < 4; ++r)
                C[(size_t)(row + r) * N + col] = acc[i][j][r] + bv;
        }
    }
}

// ---------------------------------------------------------------------------
// Flash attention, split-bf16 MFMA. Grid (B*H, S/128). 4 waves x 32 q rows.
// ---------------------------------------------------------------------------
__global__ __launch_bounds__(256, 2)
void attn_mfma(const float* __restrict__ Q, const float* __restrict__ Kf,
               const float* __restrict__ V, const float* __restrict__ mask,
               float* __restrict__ Mo)
{
    __shared__ unsigned short Ks_h[4096], Ks_l[4096], Vs_h[4096], Vs_l[4096];
    __shared__ float Ps[128][36];
    __shared__ float mk_s[64];

    const int tid = threadIdx.x;
    const int lane = tid & 63, w = tid >> 6;
    const int l15 = lane & 15, l4 = lane >> 4;
    const int t15 = tid & 15;
    const int bh = blockIdx.x, b = bh >> 4, h = bh & 15;
    const int q0 = blockIdx.y * 128;
    const int qw = q0 + w * 32;

    // Q fragments (hi/lo) straight from global, plus per-row q-mask
    bf16x8 qh[2][2], ql[2][2];
    float mqv[2][4];
    #pragma unroll
    for (int mi = 0; mi < 2; ++mi) {
        const int qr = qw + mi * 16 + l15;
        const float* qp = &Q[((size_t)b * S_ + qr) * D_ + h * DH_];
        #pragma unroll
        for (int kk = 0; kk < 2; ++kk) {
            const float4 v0 = *(const float4*)&qp[kk * 32 + l4 * 8];
            const float4 v1 = *(const float4*)&qp[kk * 32 + l4 * 8 + 4];
            split8(v0, v1, qh[mi][kk], ql[mi][kk]);
        }
        #pragma unroll
        for (int r = 0; r < 4; ++r)
            mqv[mi][r] = mask[(size_t)b * S_ + qw + mi * 16 + l4 * 4 + r];
    }

    float m_i[2][4], l_i[2][4];
    f32x4 O[2][4];
    #pragma unroll
    for (int mi = 0; mi < 2; ++mi)
        #pragma unroll
        for (int r = 0; r < 4; ++r) {
            m_i[mi][r] = -1e30f; l_i[mi][r] = 0.f;
            O[mi][r] = (f32x4){0.f, 0.f, 0.f, 0.f};
        }

    for (int kt = 0; kt < S_; kt += 64) {
        __syncthreads();
        // stage K (convert) and V (transpose + convert), both swizzled
        #pragma unroll
        for (int p = 0; p < 4; ++p) {
            const int f = p * 256 + tid;
            const int key = f >> 4, c4 = (f & 15) << 2;
            const size_t gofs = ((size_t)b * S_ + kt + key) * D_ + h * DH_ + c4;
            const float4 kv = *(const float4*)&Kf[gofs];
            unsigned short h0, h1, h2, h3, l0, l1, l2, l3;
            split2(kv.x, h0, l0); split2(kv.y, h1, l1);
            split2(kv.z, h2, l2); split2(kv.w, h3, l3);
            const int idx = SWZ64(key, c4);
            *(short4v*)&Ks_h[idx] = (short4v){(short)h0,(short)h1,(short)h2,(short)h3};
            *(short4v*)&Ks_l[idx] = (short4v){(short)l0,(short)l1,(short)l2,(short)l3};

            const float4 vv = *(const float4*)&V[gofs];
            unsigned short vh[4], vl[4];
            split2(vv.x, vh[0], vl[0]); split2(vv.y, vh[1], vl[1]);
            split2(vv.z, vh[2], vl[2]); split2(vv.w, vh[3], vl[3]);
            #pragma unroll
            for (int ii = 0; ii < 4; ++ii) {
                const int i2 = (ii + (t15 >> 1)) & 3;   // rotate to spread banks
                const int dh = c4 + i2;
                const int vidx = SWZ64(dh, key);
                Vs_h[vidx] = vh[i2]; Vs_l[vidx] = vl[i2];
            }
        }
        if (tid < 64) mk_s[tid] = mask[(size_t)b * S_ + kt + tid];
        __syncthreads();

        // QK^T: s[mi][nf], rows = q, cols = key
        f32x4 s[2][4];
        #pragma unroll
        for (int mi = 0; mi < 2; ++mi)
            #pragma unroll
            for (int nf = 0; nf < 4; ++nf) s[mi][nf] = (f32x4){0.f, 0.f, 0.f, 0.f};
        #pragma unroll
        for (int nf = 0; nf < 4; ++nf) {
            const int krow = nf * 16 + l15;
            #pragma unroll
            for (int kk = 0; kk < 2; ++kk) {
                const int idx = SWZ64(krow, kk * 32 + l4 * 8);
                const bf16x8 kh = *(const bf16x8*)&Ks_h[idx];
                const bf16x8 kl = *(const bf16x8*)&Ks_l[idx];
                #pragma unroll
                for (int mi = 0; mi < 2; ++mi) {
                    s[mi][nf] = MFMA(qh[mi][kk], kh, s[mi][nf]);
                    s[mi][nf] = MFMA(qh[mi][kk], kl, s[mi][nf]);
                    s[mi][nf] = MFMA(ql[mi][kk], kh, s[mi][nf]);
                }
            }
        }

        // masked online softmax (row = q handled by (l4, r); reduce over l15)
        float mkv[4];
        #pragma unroll
        for (int nf = 0; nf < 4; ++nf) mkv[nf] = mk_s[nf * 16 + l15];
        #pragma unroll
        for (int mi = 0; mi < 2; ++mi)
            #pragma unroll
            for (int r = 0; r < 4; ++r) {
                float vals[4];
                #pragma unroll
                for (int nf = 0; nf < 4; ++nf) {
                    const bool valid = (mqv[mi][r] != 0.f) && (mkv[nf] != 0.f);
                    vals[nf] = valid ? s[mi][nf][r] * 0.125f : -1e30f;
                }
                float rm = fmaxf(fmaxf(vals[0], vals[1]), fmaxf(vals[2], vals[3]));
                rm = fmaxf(rm, __shfl_xor(rm, 1));
                rm = fmaxf(rm, __shfl_xor(rm, 2));
                rm = fmaxf(rm, __shfl_xor(rm, 4));
                rm = fmaxf(rm, __shfl_xor(rm, 8));
                const float mnew = fmaxf(m_i[mi][r], rm);
                const float sc = __expf(m_i[mi][r] - mnew);
                float rs = 0.f;
                #pragma unroll
                for (int nf = 0; nf < 4; ++nf) {
                    const float pv = (vals[nf] > -1e29f) ? __expf(vals[nf] - mnew) : 0.f;
                    vals[nf] = pv; rs += pv;
                }
                rs += __shfl_xor(rs, 1);
                rs += __shfl_xor(rs, 2);
                rs += __shfl_xor(rs, 4);
                rs += __shfl_xor(rs, 8);
                l_i[mi][r] = l_i[mi][r] * sc + rs;
                m_i[mi][r] = mnew;
                #pragma unroll
                for (int df = 0; df < 4; ++df) O[mi][df][r] *= sc;
                #pragma unroll
                for (int nf = 0; nf < 4; ++nf) s[mi][nf][r] = vals[nf];  // keep P in regs
            }

        // PV in two key-halves; P staged through Ps (wave-private rows)
        #pragma unroll
        for (int kk = 0; kk < 2; ++kk) {
            #pragma unroll
            for (int mi = 0; mi < 2; ++mi)
                #pragma unroll
                for (int nh = 0; nh < 2; ++nh)
                    #pragma unroll
                    for (int r = 0; r < 4; ++r)
                        Ps[qw - q0 + mi * 16 + l4 * 4 + r][nh * 16 + l15] = s[mi][kk * 2 + nh][r];
            bf16x8 ph[2], pl[2];
            #pragma unroll
            for (int mi = 0; mi < 2; ++mi) {
                const float* pr = &Ps[qw - q0 + mi * 16 + l15][l4 * 8];
                const float4 p0 = *(const float4*)pr;
                const float4 p1 = *(const float4*)(pr + 4);
                split8(p0, p1, ph[mi], pl[mi]);
            }
            #pragma unroll
            for (int df = 0; df < 4; ++df) {
                const int vrow = df * 16 + l15;
                const int idx = SWZ64(vrow, kk * 32 + l4 * 8);
                const bf16x8 vh = *(const bf16x8*)&Vs_h[idx];
                const bf16x8 vl = *(const bf16x8*)&Vs_l[idx];
                #pragma unroll
                for (int mi = 0; mi < 2; ++mi) {
                    O[mi][df] = MFMA(ph[mi], vh, O[mi][df]);
                    O[mi][df] = MFMA(ph[mi], vl, O[mi][df]);
                    O[mi][df] = MFMA(pl[mi], vh, O[mi][df]);
                }
            }
        }
    }

    // epilogue: normalize; masked/empty rows have l=0 -> output 0
    #pragma unroll
    for (int mi = 0; mi < 2; ++mi)
        #pragma unroll
        for (int r = 0; r < 4; ++r) {
            const float inv = (l_i[mi][r] > 0.f) ? 1.f / l_i[mi][r] : 0.f;
            const int qr = qw + mi * 16 + l4 * 4 + r;
            #pragma unroll
            for (int df = 0; df < 4; ++df)
                Mo[((size_t)b * S_ + qr) * D_ + h * DH_ + df * 16 + l15] = O[mi][df][r] * inv;
        }
}

// ---------------------------------------------------------------------------
extern "C" void kernel_launch(void* const* d_in, const int* in_sizes, int n_in,
                              void* d_out, int out_size, void* d_ws, size_t ws_size,
                              hipStream_t stream)
{
    const float* x    = (const float*)d_in[0];
    const float* mask = (const float*)d_in[1];
    const float* Wq   = (const float*)d_in[2];
    const float* bq   = (const float*)d_in[3];
    const float* Wk   = (const float*)d_in[4];
    const float* bk   = (const float*)d_in[5];
    const float* Wv   = (const float*)d_in[6];
    const float* bv   = (const float*)d_in[7];
    const float* Wo   = (const float*)d_in[8];
    const float* bo   = (const float*)d_in[9];
    float* out = (float*)d_out;

    char* ws = (char*)d_ws;
    float* qf = (float*)(ws);                         // [0,16M)
    float* kf = (float*)(ws + ((size_t)16 << 20));    // [16M,32M)
    float* vf = (float*)(ws + ((size_t)32 << 20));    // [32M,48M)
    unsigned short* wqt_h = (unsigned short*)(ws + ((size_t)48 << 20));
    unsigned short* wqt_l = wqt_h + (1 << 20);
    unsigned short* wkt_h = (unsigned short*)(ws + ((size_t)52 << 20));
    unsigned short* wkt_l = wkt_h + (1 << 20);
    unsigned short* wvt_h = (unsigned short*)(ws + ((size_t)56 << 20));
    unsigned short* wvt_l = wvt_h + (1 << 20);
    float* msgs = (float*)(ws + ((size_t)48 << 20));  // aliases wqt.. (dead by then)
    unsigned short* wot_h = (unsigned short*)(ws);    // aliases qf (dead by then)
    unsigned short* wot_l = wot_h + (1 << 20);

    const dim3 blk(256);
    const dim3 gtc(16, 16);
    tconv_w<<<gtc, blk, 0, stream>>>(Wq, wqt_h, wqt_l, D_, D_);
    tconv_w<<<gtc, blk, 0, stream>>>(Wk, wkt_h, wkt_l, D_, D_);
    tconv_w<<<gtc, blk, 0, stream>>>(Wv, wvt_h, wvt_l, D_, D_);

    const dim3 gg(M_ / 128, D_ / 128);
    gemm_asplit<<<gg, blk, 0, stream>>>(x, wqt_h, wqt_l, bq, qf, M_, D_, D_);
    gemm_asplit<<<gg, blk, 0, stream>>>(x, wkt_h, wkt_l, bk, kf, M_, D_, D_);
    gemm_asplit<<<gg, blk, 0, stream>>>(x, wvt_h, wvt_l, bv, vf, M_, D_, D_);

    attn_mfma<<<dim3(B_ * H_, S_ / 128), blk, 0, stream>>>(qf, kf, vf, mask, msgs);

    tconv_w<<<gtc, blk, 0, stream>>>(Wo, wot_h, wot_l, OUT_, D_);

    gemm_asplit<<<dim3(M_ / 128, OUT_ / 128), blk, 0, stream>>>(msgs, wot_h, wot_l, bo, out, M_, D_, OUT_);
}

// Round 3
// 319.976 us; speedup vs baseline: 3.5171x; 1.0920x over previous
//
#include <hip/hip_runtime.h>
#include <math.h>

#define B_   2
#define S_   2048
#define H_   16
#define DH_  64
#define D_   1024
#define OUT_ 1024
#define M_   (B_ * S_)   // 4096

typedef __attribute__((ext_vector_type(8))) short bf16x8;
typedef __attribute__((ext_vector_type(4))) float f32x4;
typedef __attribute__((ext_vector_type(4))) short short4v;

#define MFMA(a, b, c) __builtin_amdgcn_mfma_f32_16x16x32_bf16((a), (b), (c), 0, 0, 0)

// async global->LDS, 16B per lane, LDS dest = uniform base + lane*16
__device__ __forceinline__ void gl_lds16(const void* g, void* l) {
    __builtin_amdgcn_global_load_lds(
        (const __attribute__((address_space(1))) unsigned int*)g,
        (__attribute__((address_space(3))) unsigned int*)l, 16, 0, 0);
}

// truncation split: x = hi(bf16) + lo(bf16) + O(2^-16 x)
__device__ __forceinline__ void split2(float x, unsigned short& h, unsigned short& l) {
    unsigned u = __float_as_uint(x);
    h = (unsigned short)(u >> 16);
    float lo = x - __uint_as_float(u & 0xFFFF0000u);
    l = (unsigned short)(__float_as_uint(lo) >> 16);
}

__device__ __forceinline__ unsigned short bf16_rne(float x) {
    unsigned u = __float_as_uint(x);
    return (unsigned short)((u + 0x7FFFu + ((u >> 16) & 1u)) >> 16);
}

__device__ __forceinline__ void split8(const float4 a, const float4 b, bf16x8& h8, bf16x8& l8) {
    unsigned short h[8], l[8];
    split2(a.x, h[0], l[0]); split2(a.y, h[1], l[1]);
    split2(a.z, h[2], l[2]); split2(a.w, h[3], l[3]);
    split2(b.x, h[4], l[4]); split2(b.y, h[5], l[5]);
    split2(b.z, h[6], l[6]); split2(b.w, h[7], l[7]);
    h8 = (bf16x8){(short)h[0],(short)h[1],(short)h[2],(short)h[3],(short)h[4],(short)h[5],(short)h[6],(short)h[7]};
    l8 = (bf16x8){(short)l[0],(short)l[1],(short)l[2],(short)l[3],(short)l[4],(short)l[5],(short)l[6],(short)l[7]};
}

// ---------------------------------------------------------------------------
// x f32 -> xh, xl bf16
// ---------------------------------------------------------------------------
__global__ __launch_bounds__(256)
void split_x(const float* __restrict__ X, unsigned short* __restrict__ Xh,
             unsigned short* __restrict__ Xl, int n4)
{
    const int i = blockIdx.x * 256 + threadIdx.x;
    if (i >= n4) return;
    const float4 v = ((const float4*)X)[i];
    unsigned short h[4], l[4];
    split2(v.x, h[0], l[0]); split2(v.y, h[1], l[1]);
    split2(v.z, h[2], l[2]); split2(v.w, h[3], l[3]);
    ((short4v*)Xh)[i] = (short4v){(short)h[0],(short)h[1],(short)h[2],(short)h[3]};
    ((short4v*)Xl)[i] = (short4v){(short)l[0],(short)l[1],(short)l[2],(short)l[3]};
}

// ---------------------------------------------------------------------------
// transpose + split convert: W[K,N] f32 -> Th/Tl [N,K] bf16
// ---------------------------------------------------------------------------
__global__ __launch_bounds__(256)
void tconv_w(const float* __restrict__ W, unsigned short* __restrict__ Th,
             unsigned short* __restrict__ Tl, int K, int N)
{
    __shared__ float T[64][65];
    const int tid = threadIdx.x;
    const int k0 = blockIdx.x * 64, n0 = blockIdx.y * 64;
    #pragma unroll
    for (int p = 0; p < 4; ++p) {
        const int f = p * 256 + tid;
        const int r = f >> 4, c4 = (f & 15) << 2;
        const float4 v = *(const float4*)&W[(size_t)(k0 + r) * N + n0 + c4];
        T[r][c4] = v.x; T[r][c4 + 1] = v.y; T[r][c4 + 2] = v.z; T[r][c4 + 3] = v.w;
    }
    __syncthreads();
    #pragma unroll
    for (int p = 0; p < 4; ++p) {
        const int f = p * 256 + tid;
        const int r = f >> 4, c4 = (f & 15) << 2;   // r = n row, c4 = k col
        unsigned short h[4], l[4];
        #pragma unroll
        for (int i = 0; i < 4; ++i) split2(T[c4 + i][r], h[i], l[i]);
        *(short4v*)&Th[(size_t)(n0 + r) * K + k0 + c4] =
            (short4v){(short)h[0],(short)h[1],(short)h[2],(short)h[3]};
        *(short4v*)&Tl[(size_t)(n0 + r) * K + k0 + c4] =
            (short4v){(short)l[0],(short)l[1],(short)l[2],(short)l[3]};
    }
}

// ---------------------------------------------------------------------------
// split GEMM via global_load_lds: C[m][n] = sum_k A[m][k]*Bt[n][k] (3-term)
// BM=128, BN=64, BK=64; 4 waves 2x2, wave tile 64x32.
// MODE 0: f32 out + bias. MODE 1: hi/lo bf16 head-blocked out + bias.
// MODE 2: hi-only RNE bf16 head-blocked out + bias.
// LDS linear [row][64]; XOR-swizzle applied on the SOURCE address (rule #21).
// ---------------------------------------------------------------------------
template<int MODE>
__global__ __launch_bounds__(256, 3)
void gemm_gl(const unsigned short* __restrict__ Ah, const unsigned short* __restrict__ Al,
             const unsigned short* __restrict__ Bh, const unsigned short* __restrict__ Bl,
             const float* __restrict__ bias, float* __restrict__ Cf,
             unsigned short* __restrict__ Oh, unsigned short* __restrict__ Ol,
             int M, int K, int N)
{
    __shared__ unsigned short As_h[128 * 64], As_l[128 * 64];
    __shared__ unsigned short Bs_h[64 * 64],  Bs_l[64 * 64];

    const int tid = threadIdx.x;
    const int lane = tid & 63, w = tid >> 6;
    const int wm = w >> 1, wn = w & 1;
    const int l15 = lane & 15, l4 = lane >> 4;
    const int lr = lane >> 3, lc = lane & 7;      // staging decode: 8 lanes/row
    const int m0 = blockIdx.x * 128, n0 = blockIdx.y * 64;

    f32x4 acc[4][2];
    #pragma unroll
    for (int i = 0; i < 4; ++i)
        #pragma unroll
        for (int j = 0; j < 2; ++j) acc[i][j] = (f32x4){0.f, 0.f, 0.f, 0.f};

    for (int kt = 0; kt < K; kt += 64) {
        __syncthreads();
        #pragma unroll
        for (int t = 0; t < 4; ++t) {           // A: 128 rows, wave covers 32
            const int row = w * 32 + t * 8 + lr;
            const int kc = lc ^ (row & 7);      // pre-swizzled source chunk
            const size_t g = (size_t)(m0 + row) * K + kt + kc * 8;
            gl_lds16(&Ah[g], &As_h[(w * 32 + t * 8) * 64]);
            gl_lds16(&Al[g], &As_l[(w * 32 + t * 8) * 64]);
        }
        #pragma unroll
        for (int t = 0; t < 2; ++t) {           // B: 64 rows, wave covers 16
            const int row = w * 16 + t * 8 + lr;
            const int kc = lc ^ (row & 7);
            const size_t g = (size_t)(n0 + row) * K + kt + kc * 8;
            gl_lds16(&Bh[g], &Bs_h[(w * 16 + t * 8) * 64]);
            gl_lds16(&Bl[g], &Bs_l[(w * 16 + t * 8) * 64]);
        }
        __syncthreads();

        #pragma unroll
        for (int kk = 0; kk < 2; ++kk) {
            bf16x8 ah[4], al[4], bh2[2], bl2[2];
            #pragma unroll
            for (int i = 0; i < 4; ++i) {
                const int row = wm * 64 + i * 16 + l15;
                const int off = row * 64 + (((kk * 4 + l4) ^ (row & 7)) << 3);
                ah[i] = *(const bf16x8*)&As_h[off];
                al[i] = *(const bf16x8*)&As_l[off];
            }
            #pragma unroll
            for (int j = 0; j < 2; ++j) {
                const int row = wn * 32 + j * 16 + l15;
                const int off = row * 64 + (((kk * 4 + l4) ^ (row & 7)) << 3);
                bh2[j] = *(const bf16x8*)&Bs_h[off];
                bl2[j] = *(const bf16x8*)&Bs_l[off];
            }
            #pragma unroll
            for (int i = 0; i < 4; ++i)
                #pragma unroll
                for (int j = 0; j < 2; ++j) {
                    acc[i][j] = MFMA(ah[i], bh2[j], acc[i][j]);
                    acc[i][j] = MFMA(ah[i], bl2[j], acc[i][j]);
                    acc[i][j] = MFMA(al[i], bh2[j], acc[i][j]);
                }
        }
    }

    #pragma unroll
    for (int i = 0; i < 4; ++i) {
        const int m = m0 + wm * 64 + i * 16 + l4 * 4;
        #pragma unroll
        for (int j = 0; j < 2; ++j) {
            const int n = n0 + wn * 32 + j * 16 + l15;
            const float bv = bias[n];
            if constexpr (MODE == 0) {
                #pragma unroll
                for (int r = 0; r < 4; ++r)
                    Cf[(size_t)(m + r) * N + n] = acc[i][j][r] + bv;
            } else {
                const int hh = n >> 6, dd = n & 63, bb = m >> 11;
                const size_t base = ((size_t)(bb * H_ + hh) * S_ + (m & 2047)) * 64 + dd;
                #pragma unroll
                for (int r = 0; r < 4; ++r) {
                    const float val = acc[i][j][r] + bv;
                    if constexpr (MODE == 1) {
                        unsigned short vh, vl;
                        split2(val, vh, vl);
                        Oh[base + (size_t)r * 64] = vh;
                        Ol[base + (size_t)r * 64] = vl;
                    } else {
                        Oh[base + (size_t)r * 64] = bf16_rne(val);
                    }
                }
            }
        }
    }
}

// ---------------------------------------------------------------------------
// Flash attention. Q/K pre-split bf16 hi/lo, V bf16 hi-only, head-blocked
// [bh][s][64]. Grid (B*H, S/128), 4 waves x 32 q rows. Defer-max (THR=8).
// ---------------------------------------------------------------------------
__global__ __launch_bounds__(256, 3)
void attn_mfma(const unsigned short* __restrict__ Qh, const unsigned short* __restrict__ Ql,
               const unsigned short* __restrict__ Kh, const unsigned short* __restrict__ Kl,
               const unsigned short* __restrict__ Vh, const float* __restrict__ mask,
               unsigned short* __restrict__ Mh, unsigned short* __restrict__ Ml)
{
    __shared__ unsigned short Ks_h[64 * 64], Ks_l[64 * 64], Vt_s[64 * 64];
    __shared__ float Ps[128][36];
    __shared__ float mk_s[64];

    const int tid = threadIdx.x;
    const int lane = tid & 63, w = tid >> 6;
    const int l15 = lane & 15, l4 = lane >> 4;
    const int lr = lane >> 3, lc = lane & 7;
    const int bh = blockIdx.x, b = bh >> 4, h = bh & 15;
    const int q0 = blockIdx.y * 128;
    const int qw = q0 + w * 32;

    // Q fragments straight from pre-split global; per-row q-mask
    bf16x8 qh[2][2], ql[2][2];
    float mqv[2][4];
    #pragma unroll
    for (int mi = 0; mi < 2; ++mi) {
        const int qr = qw + mi * 16 + l15;
        const size_t qbase = ((size_t)bh * S_ + qr) * 64;
        #pragma unroll
        for (int kk = 0; kk < 2; ++kk) {
            qh[mi][kk] = *(const bf16x8*)&Qh[qbase + kk * 32 + l4 * 8];
            ql[mi][kk] = *(const bf16x8*)&Ql[qbase + kk * 32 + l4 * 8];
        }
        #pragma unroll
        for (int r = 0; r < 4; ++r)
            mqv[mi][r] = mask[(size_t)b * S_ + qw + mi * 16 + l4 * 4 + r];
    }

    float m_i[2][4], l_i[2][4];
    f32x4 O[2][4];
    #pragma unroll
    for (int mi = 0; mi < 2; ++mi)
        #pragma unroll
        for (int r = 0; r < 4; ++r) {
            m_i[mi][r] = -1e30f; l_i[mi][r] = 0.f;
            O[mi][r] = (f32x4){0.f, 0.f, 0.f, 0.f};
        }

    for (int kt = 0; kt < S_; kt += 64) {
        __syncthreads();
        // K tiles via async global->LDS (pre-swizzled source)
        #pragma unroll
        for (int t = 0; t < 2; ++t) {
            const int row = w * 16 + t * 8 + lr;
            const int kc = lc ^ (row & 7);
            const size_t g = ((size_t)bh * S_ + kt + row) * 64 + kc * 8;
            gl_lds16(&Kh[g], &Ks_h[(w * 16 + t * 8) * 64]);
            gl_lds16(&Kl[g], &Ks_l[(w * 16 + t * 8) * 64]);
        }
        // V transpose-scatter into Vt[d][key] (swizzled rows)
        #pragma unroll
        for (int t = 0; t < 2; ++t) {
            const int f = t * 256 + tid;
            const int key = f >> 3, d0v = (f & 7) * 8;
            const bf16x8 v8 = *(const bf16x8*)&Vh[((size_t)bh * S_ + kt + key) * 64 + d0v];
            #pragma unroll
            for (int i = 0; i < 8; ++i) {
                const int d = d0v + i;
                Vt_s[d * 64 + ((((key >> 3) ^ (d & 7)) << 3) | (key & 7))] = (unsigned short)v8[i];
            }
        }
        if (tid < 64) mk_s[tid] = mask[(size_t)b * S_ + kt + tid];
        __syncthreads();

        // QK^T: s[mi][nf], rows=q (l4,r), cols=key (nf*16+l15)
        f32x4 s[2][4];
        #pragma unroll
        for (int mi = 0; mi < 2; ++mi)
            #pragma unroll
            for (int nf = 0; nf < 4; ++nf) s[mi][nf] = (f32x4){0.f, 0.f, 0.f, 0.f};
        #pragma unroll
        for (int nf = 0; nf < 4; ++nf) {
            const int krow = nf * 16 + l15;
            #pragma unroll
            for (int kk = 0; kk < 2; ++kk) {
                const int off = krow * 64 + (((kk * 4 + l4) ^ (krow & 7)) << 3);
                const bf16x8 kh8 = *(const bf16x8*)&Ks_h[off];
                const bf16x8 kl8 = *(const bf16x8*)&Ks_l[off];
                #pragma unroll
                for (int mi = 0; mi < 2; ++mi) {
                    s[mi][nf] = MFMA(qh[mi][kk], kh8, s[mi][nf]);
                    s[mi][nf] = MFMA(qh[mi][kk], kl8, s[mi][nf]);
                    s[mi][nf] = MFMA(ql[mi][kk], kh8, s[mi][nf]);
                }
            }
        }

        // mask + scale; defer-max online softmax
        float mkv[4];
        #pragma unroll
        for (int nf = 0; nf < 4; ++nf) mkv[nf] = mk_s[nf * 16 + l15];

        float vals[2][4][4], lm[2][4];
        bool need = false;
        #pragma unroll
        for (int mi = 0; mi < 2; ++mi)
            #pragma unroll
            for (int r = 0; r < 4; ++r) {
                float rm = -1e30f;
                #pragma unroll
                for (int nf = 0; nf < 4; ++nf) {
                    const bool valid = (mqv[mi][r] != 0.f) && (mkv[nf] != 0.f);
                    const float sv = valid ? s[mi][nf][r] * 0.125f : -1e30f;
                    vals[mi][r][nf] = sv;
                    rm = fmaxf(rm, sv);
                }
                lm[mi][r] = rm;
                need |= (rm > m_i[mi][r] + 8.f);
            }

        if (__any(need)) {
            #pragma unroll
            for (int mi = 0; mi < 2; ++mi)
                #pragma unroll
                for (int r = 0; r < 4; ++r) {
                    float rm = lm[mi][r];
                    rm = fmaxf(rm, __shfl_xor(rm, 1));
                    rm = fmaxf(rm, __shfl_xor(rm, 2));
                    rm = fmaxf(rm, __shfl_xor(rm, 4));
                    rm = fmaxf(rm, __shfl_xor(rm, 8));
                    const float mnew = fmaxf(m_i[mi][r], rm);
                    const float sc = __expf(m_i[mi][r] - mnew);
                    l_i[mi][r] *= sc;
                    m_i[mi][r] = mnew;
                    #pragma unroll
                    for (int df = 0; df < 4; ++df) O[mi][df][r] *= sc;
                }
        }

        #pragma unroll
        for (int mi = 0; mi < 2; ++mi)
            #pragma unroll
            for (int r = 0; r < 4; ++r) {
                float rs = 0.f;
                #pragma unroll
                for (int nf = 0; nf < 4; ++nf) {
                    // guard keeps fully-masked entries exactly 0
                    const float pv = (vals[mi][r][nf] > -1e29f)
                                   ? __expf(vals[mi][r][nf] - m_i[mi][r]) : 0.f;
                    s[mi][nf][r] = pv;
                    rs += pv;
                }
                rs += __shfl_xor(rs, 1);
                rs += __shfl_xor(rs, 2);
                rs += __shfl_xor(rs, 4);
                rs += __shfl_xor(rs, 8);
                l_i[mi][r] += rs;
            }

        // PV: P through Ps roundtrip (wave-private rows), V hi-only (2 MFMA)
        #pragma unroll
        for (int kk = 0; kk < 2; ++kk) {
            #pragma unroll
            for (int mi = 0; mi < 2; ++mi)
                #pragma unroll
                for (int nh = 0; nh < 2; ++nh)
                    #pragma unroll
                    for (int r = 0; r < 4; ++r)
                        Ps[qw - q0 + mi * 16 + l4 * 4 + r][nh * 16 + l15] = s[mi][kk * 2 + nh][r];
            bf16x8 ph[2], pl[2];
            #pragma unroll
            for (int mi = 0; mi < 2; ++mi) {
                const float* pr = &Ps[qw - q0 + mi * 16 + l15][l4 * 8];
                split8(*(const float4*)pr, *(const float4*)(pr + 4), ph[mi], pl[mi]);
            }
            #pragma unroll
            for (int df = 0; df < 4; ++df) {
                const int vrow = df * 16 + l15;
                const int off = vrow * 64 + (((kk * 4 + l4) ^ (vrow & 7)) << 3);
                const bf16x8 vh8 = *(const bf16x8*)&Vt_s[off];
                #pragma unroll
                for (int mi = 0; mi < 2; ++mi) {
                    O[mi][df] = MFMA(ph[mi], vh8, O[mi][df]);
                    O[mi][df] = MFMA(pl[mi], vh8, O[mi][df]);
                }
            }
        }
    }

    // epilogue: normalize + split-write msgs (row-major [M][D])
    #pragma unroll
    for (int mi = 0; mi < 2; ++mi)
        #pragma unroll
        for (int r = 0; r < 4; ++r) {
            const float inv = (l_i[mi][r] > 0.f) ? 1.f / l_i[mi][r] : 0.f;
            const int qr = qw + mi * 16 + l4 * 4 + r;
            const size_t base = ((size_t)b * S_ + qr) * D_ + h * DH_;
            #pragma unroll
            for (int df = 0; df < 4; ++df) {
                unsigned short vh, vl;
                split2(O[mi][df][r] * inv, vh, vl);
                Mh[base + df * 16 + l15] = vh;
                Ml[base + df * 16 + l15] = vl;
            }
        }
}

// ---------------------------------------------------------------------------
extern "C" void kernel_launch(void* const* d_in, const int* in_sizes, int n_in,
                              void* d_out, int out_size, void* d_ws, size_t ws_size,
                              hipStream_t stream)
{
    const float* x    = (const float*)d_in[0];
    const float* mask = (const float*)d_in[1];
    const float* Wq   = (const float*)d_in[2];
    const float* bq   = (const float*)d_in[3];
    const float* Wk   = (const float*)d_in[4];
    const float* bk   = (const float*)d_in[5];
    const float* Wv   = (const float*)d_in[6];
    const float* bv   = (const float*)d_in[7];
    const float* Wo   = (const float*)d_in[8];
    const float* bo   = (const float*)d_in[9];
    float* out = (float*)d_out;

    char* ws = (char*)d_ws;
    // [0,8M) xh -> mh ; [8M,16M) xl -> ml ; [16..56M) qh ql kh kl vh ; [56,60M) W slot
    unsigned short* xh = (unsigned short*)(ws);
    unsigned short* xl = (unsigned short*)(ws + ((size_t)8 << 20));
    unsigned short* qh = (unsigned short*)(ws + ((size_t)16 << 20));
    unsigned short* ql = (unsigned short*)(ws + ((size_t)24 << 20));
    unsigned short* kh = (unsigned short*)(ws + ((size_t)32 << 20));
    unsigned short* kl = (unsigned short*)(ws + ((size_t)40 << 20));
    unsigned short* vh = (unsigned short*)(ws + ((size_t)48 << 20));
    unsigned short* wt_h = (unsigned short*)(ws + ((size_t)56 << 20));
    unsigned short* wt_l = (unsigned short*)(ws + ((size_t)58 << 20));
    unsigned short* mh = xh;   // x dead after V-GEMM
    unsigned short* ml = xl;

    const dim3 blk(256);
    split_x<<<dim3((M_ * D_ / 4 + 255) / 256), blk, 0, stream>>>(x, xh, xl, M_ * D_ / 4);

    const dim3 gtc(16, 16);
    const dim3 gg(M_ / 128, D_ / 64);

    tconv_w<<<gtc, blk, 0, stream>>>(Wq, wt_h, wt_l, D_, D_);
    gemm_gl<1><<<gg, blk, 0, stream>>>(xh, xl, wt_h, wt_l, bq, nullptr, qh, ql, M_, D_, D_);
    tconv_w<<<gtc, blk, 0, stream>>>(Wk, wt_h, wt_l, D_, D_);
    gemm_gl<1><<<gg, blk, 0, stream>>>(xh, xl, wt_h, wt_l, bk, nullptr, kh, kl, M_, D_, D_);
    tconv_w<<<gtc, blk, 0, stream>>>(Wv, wt_h, wt_l, D_, D_);
    gemm_gl<2><<<gg, blk, 0, stream>>>(xh, xl, wt_h, wt_l, bv, nullptr, vh, nullptr, M_, D_, D_);

    attn_mfma<<<dim3(B_ * H_, S_ / 128), blk, 0, stream>>>(qh, ql, kh, kl, vh, mask, mh, ml);

    tconv_w<<<gtc, blk, 0, stream>>>(Wo, wt_h, wt_l, D_, OUT_);
    gemm_gl<0><<<dim3(M_ / 128, OUT_ / 64), blk, 0, stream>>>(mh, ml, wt_h, wt_l, bo, out, nullptr, nullptr, M_, D_, OUT_);
}

// Round 5
// 237.066 us; speedup vs baseline: 4.7471x; 1.3497x over previous
//
#include <hip/hip_runtime.h>
#include <math.h>

#define B_   2
#define S_   2048
#define H_   16
#define DH_  64
#define D_   1024
#define OUT_ 1024
#define M_   (B_ * S_)   // 4096

typedef __attribute__((ext_vector_type(8))) short bf16x8;
typedef __attribute__((ext_vector_type(4))) float f32x4;
typedef __attribute__((ext_vector_type(4))) short short4v;

#define MFMA(a, b, c) __builtin_amdgcn_mfma_f32_16x16x32_bf16((a), (b), (c), 0, 0, 0)

// async global->LDS, 16B per lane, LDS dest = wave-uniform base + lane*16
__device__ __forceinline__ void gl_lds16(const void* g, void* l) {
    __builtin_amdgcn_global_load_lds(
        (const __attribute__((address_space(1))) unsigned int*)g,
        (__attribute__((address_space(3))) unsigned int*)l, 16, 0, 0);
}

// truncation split: x = hi(bf16) + lo(bf16) + O(2^-16 x)
__device__ __forceinline__ void split2(float x, unsigned short& h, unsigned short& l) {
    unsigned u = __float_as_uint(x);
    h = (unsigned short)(u >> 16);
    float lo = x - __uint_as_float(u & 0xFFFF0000u);
    l = (unsigned short)(__float_as_uint(lo) >> 16);
}

__device__ __forceinline__ unsigned short bf16_rne(float x) {
    unsigned u = __float_as_uint(x);
    return (unsigned short)((u + 0x7FFFu + ((u >> 16) & 1u)) >> 16);
}

__device__ __forceinline__ void split8(const float4 a, const float4 b, bf16x8& h8, bf16x8& l8) {
    unsigned short h[8], l[8];
    split2(a.x, h[0], l[0]); split2(a.y, h[1], l[1]);
    split2(a.z, h[2], l[2]); split2(a.w, h[3], l[3]);
    split2(b.x, h[4], l[4]); split2(b.y, h[5], l[5]);
    split2(b.z, h[6], l[6]); split2(b.w, h[7], l[7]);
    h8 = (bf16x8){(short)h[0],(short)h[1],(short)h[2],(short)h[3],(short)h[4],(short)h[5],(short)h[6],(short)h[7]};
    l8 = (bf16x8){(short)l[0],(short)l[1],(short)l[2],(short)l[3],(short)l[4],(short)l[5],(short)l[6],(short)l[7]};
}

// ---------------------------------------------------------------------------
__global__ __launch_bounds__(256)
void split_x(const float* __restrict__ X, unsigned short* __restrict__ Xh,
             unsigned short* __restrict__ Xl, int n4)
{
    const int i = blockIdx.x * 256 + threadIdx.x;
    if (i >= n4) return;
    const float4 v = ((const float4*)X)[i];
    unsigned short h[4], l[4];
    split2(v.x, h[0], l[0]); split2(v.y, h[1], l[1]);
    split2(v.z, h[2], l[2]); split2(v.w, h[3], l[3]);
    ((short4v*)Xh)[i] = (short4v){(short)h[0],(short)h[1],(short)h[2],(short)h[3]};
    ((short4v*)Xl)[i] = (short4v){(short)l[0],(short)l[1],(short)l[2],(short)l[3]};
}

// ---------------------------------------------------------------------------
// transpose + split convert: W[K,N] f32 -> Th/Tl [N,K] bf16 (single weight)
// ---------------------------------------------------------------------------
__global__ __launch_bounds__(256)
void tconv_w(const float* __restrict__ W, unsigned short* __restrict__ Th,
             unsigned short* __restrict__ Tl, int K, int N)
{
    __shared__ float T[64][65];
    const int tid = threadIdx.x;
    const int k0 = blockIdx.x * 64, n0 = blockIdx.y * 64;
    #pragma unroll
    for (int p = 0; p < 4; ++p) {
        const int f = p * 256 + tid;
        const int r = f >> 4, c4 = (f & 15) << 2;
        const float4 v = *(const float4*)&W[(size_t)(k0 + r) * N + n0 + c4];
        T[r][c4] = v.x; T[r][c4 + 1] = v.y; T[r][c4 + 2] = v.z; T[r][c4 + 3] = v.w;
    }
    __syncthreads();
    #pragma unroll
    for (int p = 0; p < 4; ++p) {
        const int f = p * 256 + tid;
        const int r = f >> 4, c4 = (f & 15) << 2;
        unsigned short h[4], l[4];
        #pragma unroll
        for (int i = 0; i < 4; ++i) split2(T[c4 + i][r], h[i], l[i]);
        *(short4v*)&Th[(size_t)(n0 + r) * K + k0 + c4] =
            (short4v){(short)h[0],(short)h[1],(short)h[2],(short)h[3]};
        *(short4v*)&Tl[(size_t)(n0 + r) * K + k0 + c4] =
            (short4v){(short)l[0],(short)l[1],(short)l[2],(short)l[3]};
    }
}

// same, for the 3 QKV weights in one launch (z selects weight; out at z<<20)
__global__ __launch_bounds__(256)
void tconv_qkv(const float* __restrict__ W0, const float* __restrict__ W1,
               const float* __restrict__ W2, unsigned short* __restrict__ Th,
               unsigned short* __restrict__ Tl)
{
    __shared__ float T[64][65];
    const int z = blockIdx.z;
    const float* W = (z == 0) ? W0 : (z == 1) ? W1 : W2;
    unsigned short* th = Th + ((size_t)z << 20);
    unsigned short* tl = Tl + ((size_t)z << 20);
    const int tid = threadIdx.x;
    const int k0 = blockIdx.x * 64, n0 = blockIdx.y * 64;
    #pragma unroll
    for (int p = 0; p < 4; ++p) {
        const int f = p * 256 + tid;
        const int r = f >> 4, c4 = (f & 15) << 2;
        const float4 v = *(const float4*)&W[(size_t)(k0 + r) * D_ + n0 + c4];
        T[r][c4] = v.x; T[r][c4 + 1] = v.y; T[r][c4 + 2] = v.z; T[r][c4 + 3] = v.w;
    }
    __syncthreads();
    #pragma unroll
    for (int p = 0; p < 4; ++p) {
        const int f = p * 256 + tid;
        const int r = f >> 4, c4 = (f & 15) << 2;
        unsigned short h[4], l[4];
        #pragma unroll
        for (int i = 0; i < 4; ++i) split2(T[c4 + i][r], h[i], l[i]);
        *(short4v*)&th[(size_t)(n0 + r) * D_ + k0 + c4] =
            (short4v){(short)h[0],(short)h[1],(short)h[2],(short)h[3]};
        *(short4v*)&tl[(size_t)(n0 + r) * D_ + k0 + c4] =
            (short4v){(short)l[0],(short)l[1],(short)l[2],(short)l[3]};
    }
}

// ---------------------------------------------------------------------------
// Merged QKV GEMM. A = xh/xl [4096][1024], B = wc_h/wc_l [3072][1024].
// Q -> hi/lo head-blocked [bh][s][64]; K -> hi RNE head-blocked;
// V -> hi RNE TRANSPOSED [bh][d][s] (so attention needs no transpose).
// ---------------------------------------------------------------------------
__global__ __launch_bounds__(256, 3)
void gemm_qkv(const unsigned short* __restrict__ Ah, const unsigned short* __restrict__ Al,
              const unsigned short* __restrict__ Bh, const unsigned short* __restrict__ Bl,
              const float* __restrict__ bq, const float* __restrict__ bk,
              const float* __restrict__ bv,
              unsigned short* __restrict__ Oqh, unsigned short* __restrict__ Oql,
              unsigned short* __restrict__ Okh, unsigned short* __restrict__ Ovt)
{
    __shared__ unsigned short As_h[128 * 64], As_l[128 * 64];
    __shared__ unsigned short Bs_h[64 * 64],  Bs_l[64 * 64];

    const int tid = threadIdx.x;
    const int lane = tid & 63, w = tid >> 6;
    const int wm = w >> 1, wn = w & 1;
    const int l15 = lane & 15, l4 = lane >> 4;
    const int lr = lane >> 3, lc = lane & 7;
    const int m0 = blockIdx.x * 128, n0 = blockIdx.y * 64;

    f32x4 acc[4][2];
    #pragma unroll
    for (int i = 0; i < 4; ++i)
        #pragma unroll
        for (int j = 0; j < 2; ++j) acc[i][j] = (f32x4){0.f, 0.f, 0.f, 0.f};

    for (int kt = 0; kt < D_; kt += 64) {
        __syncthreads();
        #pragma unroll
        for (int t = 0; t < 4; ++t) {
            const int row = w * 32 + t * 8 + lr;
            const int kc = lc ^ (row & 7);
            const size_t g = (size_t)(m0 + row) * D_ + kt + kc * 8;
            gl_lds16(&Ah[g], &As_h[(w * 32 + t * 8) * 64]);
            gl_lds16(&Al[g], &As_l[(w * 32 + t * 8) * 64]);
        }
        #pragma unroll
        for (int t = 0; t < 2; ++t) {
            const int row = w * 16 + t * 8 + lr;
            const int kc = lc ^ (row & 7);
            const size_t g = (size_t)(n0 + row) * D_ + kt + kc * 8;
            gl_lds16(&Bh[g], &Bs_h[(w * 16 + t * 8) * 64]);
            gl_lds16(&Bl[g], &Bs_l[(w * 16 + t * 8) * 64]);
        }
        __syncthreads();

        #pragma unroll
        for (int kk = 0; kk < 2; ++kk) {
            bf16x8 ah[4], al[4], bh2[2], bl2[2];
            #pragma unroll
            for (int i = 0; i < 4; ++i) {
                const int row = wm * 64 + i * 16 + l15;
                const int off = row * 64 + (((kk * 4 + l4) ^ (row & 7)) << 3);
                ah[i] = *(const bf16x8*)&As_h[off];
                al[i] = *(const bf16x8*)&As_l[off];
            }
            #pragma unroll
            for (int j = 0; j < 2; ++j) {
                const int row = wn * 32 + j * 16 + l15;
                const int off = row * 64 + (((kk * 4 + l4) ^ (row & 7)) << 3);
                bh2[j] = *(const bf16x8*)&Bs_h[off];
                bl2[j] = *(const bf16x8*)&Bs_l[off];
            }
            #pragma unroll
            for (int i = 0; i < 4; ++i)
                #pragma unroll
                for (int j = 0; j < 2; ++j) {
                    acc[i][j] = MFMA(ah[i], bh2[j], acc[i][j]);
                    acc[i][j] = MFMA(ah[i], bl2[j], acc[i][j]);
                    acc[i][j] = MFMA(al[i], bh2[j], acc[i][j]);
                }
        }
    }

    const int idx = n0 >> 10;   // 0=Q 1=K 2=V (uniform per block)
    const float* bp = (idx == 0) ? bq : (idx == 1) ? bk : bv;
    #pragma unroll
    for (int i = 0; i < 4; ++i) {
        const int m = m0 + wm * 64 + i * 16 + l4 * 4;
        #pragma unroll
        for (int j = 0; j < 2; ++j) {
            const int nG = n0 + wn * 32 + j * 16 + l15;
            const int c = nG & 1023;
            const float bvv = bp[c];
            const int hh = c >> 6, dd = c & 63, bb = m >> 11;
            if (idx == 0) {
                const size_t base = ((size_t)(bb * H_ + hh) * S_ + (m & 2047)) * 64 + dd;
                #pragma unroll
                for (int r = 0; r < 4; ++r) {
                    unsigned short vh, vl;
                    split2(acc[i][j][r] + bvv, vh, vl);
                    Oqh[base + (size_t)r * 64] = vh;
                    Oql[base + (size_t)r * 64] = vl;
                }
            } else if (idx == 1) {
                const size_t base = ((size_t)(bb * H_ + hh) * S_ + (m & 2047)) * 64 + dd;
                #pragma unroll
                for (int r = 0; r < 4; ++r)
                    Okh[base + (size_t)r * 64] = bf16_rne(acc[i][j][r] + bvv);
            } else {
                // V^T: [bh][d][s]; 4 consecutive s -> one 8B store
                unsigned short pv[4];
                #pragma unroll
                for (int r = 0; r < 4; ++r) pv[r] = bf16_rne(acc[i][j][r] + bvv);
                *(short4v*)&Ovt[((size_t)(bb * H_ + hh) * 64 + dd) * (size_t)S_ + (m & 2047)] =
                    (short4v){(short)pv[0],(short)pv[1],(short)pv[2],(short)pv[3]};
            }
        }
    }
}

// ---------------------------------------------------------------------------
// Output GEMM: out[M][1024] f32 = msgs(hi/lo) @ WoT(hi/lo) + bo
// ---------------------------------------------------------------------------
__global__ __launch_bounds__(256, 3)
void gemm_out(const unsigned short* __restrict__ Ah, const unsigned short* __restrict__ Al,
              const unsigned short* __restrict__ Bh, const unsigned short* __restrict__ Bl,
              const float* __restrict__ bias, float* __restrict__ Cf)
{
    __shared__ unsigned short As_h[128 * 64], As_l[128 * 64];
    __shared__ unsigned short Bs_h[64 * 64],  Bs_l[64 * 64];

    const int tid = threadIdx.x;
    const int lane = tid & 63, w = tid >> 6;
    const int wm = w >> 1, wn = w & 1;
    const int l15 = lane & 15, l4 = lane >> 4;
    const int lr = lane >> 3, lc = lane & 7;
    const int m0 = blockIdx.x * 128, n0 = blockIdx.y * 64;

    f32x4 acc[4][2];
    #pragma unroll
    for (int i = 0; i < 4; ++i)
        #pragma unroll
        for (int j = 0; j < 2; ++j) acc[i][j] = (f32x4){0.f, 0.f, 0.f, 0.f};

    for (int kt = 0; kt < D_; kt += 64) {
        __syncthreads();
        #pragma unroll
        for (int t = 0; t < 4; ++t) {
            const int row = w * 32 + t * 8 + lr;
            const int kc = lc ^ (row & 7);
            const size_t g = (size_t)(m0 + row) * D_ + kt + kc * 8;
            gl_lds16(&Ah[g], &As_h[(w * 32 + t * 8) * 64]);
            gl_lds16(&Al[g], &As_l[(w * 32 + t * 8) * 64]);
        }
        #pragma unroll
        for (int t = 0; t < 2; ++t) {
            const int row = w * 16 + t * 8 + lr;
            const int kc = lc ^ (row & 7);
            const size_t g = (size_t)(n0 + row) * D_ + kt + kc * 8;
            gl_lds16(&Bh[g], &Bs_h[(w * 16 + t * 8) * 64]);
            gl_lds16(&Bl[g], &Bs_l[(w * 16 + t * 8) * 64]);
        }
        __syncthreads();

        #pragma unroll
        for (int kk = 0; kk < 2; ++kk) {
            bf16x8 ah[4], al[4], bh2[2], bl2[2];
            #pragma unroll
            for (int i = 0; i < 4; ++i) {
                const int row = wm * 64 + i * 16 + l15;
                const int off = row * 64 + (((kk * 4 + l4) ^ (row & 7)) << 3);
                ah[i] = *(const bf16x8*)&As_h[off];
                al[i] = *(const bf16x8*)&As_l[off];
            }
            #pragma unroll
            for (int j = 0; j < 2; ++j) {
                const int row = wn * 32 + j * 16 + l15;
                const int off = row * 64 + (((kk * 4 + l4) ^ (row & 7)) << 3);
                bh2[j] = *(const bf16x8*)&Bs_h[off];
                bl2[j] = *(const bf16x8*)&Bs_l[off];
            }
            #pragma unroll
            for (int i = 0; i < 4; ++i)
                #pragma unroll
                for (int j = 0; j < 2; ++j) {
                    acc[i][j] = MFMA(ah[i], bh2[j], acc[i][j]);
                    acc[i][j] = MFMA(ah[i], bl2[j], acc[i][j]);
                    acc[i][j] = MFMA(al[i], bh2[j], acc[i][j]);
                }
        }
    }

    #pragma unroll
    for (int i = 0; i < 4; ++i) {
        const int m = m0 + wm * 64 + i * 16 + l4 * 4;
        #pragma unroll
        for (int j = 0; j < 2; ++j) {
            const int n = n0 + wn * 32 + j * 16 + l15;
            const float bvv = bias[n];
            #pragma unroll
            for (int r = 0; r < 4; ++r)
                Cf[(size_t)(m + r) * OUT_ + n] = acc[i][j][r] + bvv;
        }
    }
}

// ---------------------------------------------------------------------------
// Flash attention. Q hi/lo [bh][s][64], K hi [bh][s][64], V^T hi [bh][d][s].
// Grid (B*H, S/128); 4 waves x 32 q rows. K and V^T staged identically via
// linear global_load_lds + source XOR-swizzle; swizzled ds_read_b128 frags.
// Defer-max (THR=8); l-sum partials reduced once in epilogue.
// ---------------------------------------------------------------------------
__global__ __launch_bounds__(256, 3)
void attn_mfma(const unsigned short* __restrict__ Qh, const unsigned short* __restrict__ Ql,
               const unsigned short* __restrict__ Kh, const unsigned short* __restrict__ Vt,
               const float* __restrict__ mask,
               unsigned short* __restrict__ Mh, unsigned short* __restrict__ Ml)
{
    __shared__ unsigned short Ks[64 * 64];    // [key][k-chunks swizzled]
    __shared__ unsigned short Vts[64 * 64];   // [d][key-chunks swizzled]
    __shared__ float Ps[128][36];
    __shared__ float mk_s[64];

    const int tid = threadIdx.x;
    const int lane = tid & 63, w = tid >> 6;
    const int l15 = lane & 15, l4 = lane >> 4;
    const int bh = blockIdx.x, b = bh >> 4;
    const int q0 = blockIdx.y * 128;
    const int qw = q0 + w * 32;

    // Q fragments (hi/lo) from pre-split global; per-row q-mask
    bf16x8 qh[2][2], ql[2][2];
    float mqv[2][4];
    #pragma unroll
    for (int mi = 0; mi < 2; ++mi) {
        const int qr = qw + mi * 16 + l15;
        const size_t qbase = ((size_t)bh * S_ + qr) * 64;
        #pragma unroll
        for (int kk = 0; kk < 2; ++kk) {
            qh[mi][kk] = *(const bf16x8*)&Qh[qbase + kk * 32 + l4 * 8];
            ql[mi][kk] = *(const bf16x8*)&Ql[qbase + kk * 32 + l4 * 8];
        }
        #pragma unroll
        for (int r = 0; r < 4; ++r)
            mqv[mi][r] = mask[(size_t)b * S_ + qw + mi * 16 + l4 * 4 + r];
    }

    float m_i[2][4], lp[2][4];
    f32x4 O[2][4];
    #pragma unroll
    for (int mi = 0; mi < 2; ++mi)
        #pragma unroll
        for (int r = 0; r < 4; ++r) {
            m_i[mi][r] = -1e30f; lp[mi][r] = 0.f;
            O[mi][r] = (f32x4){0.f, 0.f, 0.f, 0.f};
        }

    for (int kt = 0; kt < S_; kt += 64) {
        __syncthreads();
        // K hi: rows = key; V^T hi: rows = d. Same linear staging pattern.
        #pragma unroll
        for (int t = 0; t < 2; ++t) {
            const int row = w * 16 + t * 8 + (lane >> 3);
            const int kc = (lane & 7) ^ (row & 7);
            gl_lds16(&Kh[((size_t)bh * S_ + kt + row) * 64 + kc * 8],
                     &Ks[(w * 16 + t * 8) * 64]);
            gl_lds16(&Vt[((size_t)bh * 64 + row) * (size_t)S_ + kt + kc * 8],
                     &Vts[(w * 16 + t * 8) * 64]);
        }
        if (tid < 64) mk_s[tid] = mask[(size_t)b * S_ + kt + tid];
        __syncthreads();

        // QK^T (K hi-only): s rows=q (l4,r), cols=key (nf*16+l15)
        f32x4 s[2][4];
        #pragma unroll
        for (int mi = 0; mi < 2; ++mi)
            #pragma unroll
            for (int nf = 0; nf < 4; ++nf) s[mi][nf] = (f32x4){0.f, 0.f, 0.f, 0.f};
        #pragma unroll
        for (int nf = 0; nf < 4; ++nf) {
            const int krow = nf * 16 + l15;
            #pragma unroll
            for (int kk = 0; kk < 2; ++kk) {
                const int off = krow * 64 + (((kk * 4 + l4) ^ (krow & 7)) << 3);
                const bf16x8 kh8 = *(const bf16x8*)&Ks[off];
                #pragma unroll
                for (int mi = 0; mi < 2; ++mi) {
                    s[mi][nf] = MFMA(qh[mi][kk], kh8, s[mi][nf]);
                    s[mi][nf] = MFMA(ql[mi][kk], kh8, s[mi][nf]);
                }
            }
        }

        // mask + scale in place; defer-max gate
        float mkv[4];
        #pragma unroll
        for (int nf = 0; nf < 4; ++nf) mkv[nf] = mk_s[nf * 16 + l15];
        float lm[2][4];
        bool need = false;
        #pragma unroll
        for (int mi = 0; mi < 2; ++mi)
            #pragma unroll
            for (int r = 0; r < 4; ++r) {
                float rm = -1e30f;
                #pragma unroll
                for (int nf = 0; nf < 4; ++nf) {
                    const bool valid = (mqv[mi][r] != 0.f) && (mkv[nf] != 0.f);
                    const float sv = valid ? s[mi][nf][r] * 0.125f : -1e30f;
                    s[mi][nf][r] = sv;
                    rm = fmaxf(rm, sv);
                }
                lm[mi][r] = rm;
                need |= (rm > m_i[mi][r] + 8.f);
            }

        if (__any(need)) {   // occasional: full row-max reduce + rescale
            #pragma unroll
            for (int mi = 0; mi < 2; ++mi)
                #pragma unroll
                for (int r = 0; r < 4; ++r) {
                    float rm = lm[mi][r];
                    rm = fmaxf(rm, __shfl_xor(rm, 1));
                    rm = fmaxf(rm, __shfl_xor(rm, 2));
                    rm = fmaxf(rm, __shfl_xor(rm, 4));
                    rm = fmaxf(rm, __shfl_xor(rm, 8));
                    const float mnew = fmaxf(m_i[mi][r], rm);
                    const float sc = __expf(m_i[mi][r] - mnew);
                    lp[mi][r] *= sc;
                    m_i[mi][r] = mnew;
                    #pragma unroll
                    for (int df = 0; df < 4; ++df) O[mi][df][r] *= sc;
                }
        }

        // exp + per-lane partial l (cross-lane reduce deferred to epilogue)
        #pragma unroll
        for (int mi = 0; mi < 2; ++mi)
            #pragma unroll
            for (int r = 0; r < 4; ++r) {
                float rs = 0.f;
                #pragma unroll
                for (int nf = 0; nf < 4; ++nf) {
                    const float pv = (s[mi][nf][r] > -1e29f)
                                   ? __expf(s[mi][nf][r] - m_i[mi][r]) : 0.f;
                    s[mi][nf][r] = pv;
                    rs += pv;
                }
                lp[mi][r] += rs;
            }

        // PV per key-half: P via wave-private LDS transpose; V^T frags b128
        #pragma unroll
        for (int kk = 0; kk < 2; ++kk) {
            #pragma unroll
            for (int mi = 0; mi < 2; ++mi)
                #pragma unroll
                for (int nh = 0; nh < 2; ++nh)
                    #pragma unroll
                    for (int r = 0; r < 4; ++r)
                        Ps[w * 32 + mi * 16 + l4 * 4 + r][nh * 16 + l15] = s[mi][kk * 2 + nh][r];

            bf16x8 ph[2], pl[2];
            #pragma unroll
            for (int mi = 0; mi < 2; ++mi) {
                const float* pr = &Ps[w * 32 + mi * 16 + l15][l4 * 8];
                split8(*(const float4*)pr, *(const float4*)(pr + 4), ph[mi], pl[mi]);
            }

            #pragma unroll
            for (int df = 0; df < 4; ++df) {
                const int vrow = df * 16 + l15;
                const int off = vrow * 64 + (((kk * 4 + l4) ^ (vrow & 7)) << 3);
                const bf16x8 vb = *(const bf16x8*)&Vts[off];
                #pragma unroll
                for (int mi = 0; mi < 2; ++mi) {
                    O[mi][df] = MFMA(ph[mi], vb, O[mi][df]);
                    O[mi][df] = MFMA(pl[mi], vb, O[mi][df]);
                }
            }
        }
    }

    // epilogue: reduce l partials across the row's 16 lanes; normalize; write
    #pragma unroll
    for (int mi = 0; mi < 2; ++mi)
        #pragma unroll
        for (int r = 0; r < 4; ++r) {
            float t = lp[mi][r];
            t += __shfl_xor(t, 1);
            t += __shfl_xor(t, 2);
            t += __shfl_xor(t, 4);
            t += __shfl_xor(t, 8);
            const float inv = (t > 0.f) ? 1.f / t : 0.f;
            const int qr = qw + mi * 16 + l4 * 4 + r;
            const size_t base = ((size_t)b * S_ + qr) * D_ + (bh & 15) * DH_;
            #pragma unroll
            for (int df = 0; df < 4; ++df) {
                unsigned short vh, vl;
                split2(O[mi][df][r] * inv, vh, vl);
                Mh[base + df * 16 + l15] = vh;
                Ml[base + df * 16 + l15] = vl;
            }
        }
}

// ---------------------------------------------------------------------------
extern "C" void kernel_launch(void* const* d_in, const int* in_sizes, int n_in,
                              void* d_out, int out_size, void* d_ws, size_t ws_size,
                              hipStream_t stream)
{
    const float* x    = (const float*)d_in[0];
    const float* mask = (const float*)d_in[1];
    const float* Wq   = (const float*)d_in[2];
    const float* bq   = (const float*)d_in[3];
    const float* Wk   = (const float*)d_in[4];
    const float* bk   = (const float*)d_in[5];
    const float* Wv   = (const float*)d_in[6];
    const float* bv   = (const float*)d_in[7];
    const float* Wo   = (const float*)d_in[8];
    const float* bo   = (const float*)d_in[9];
    float* out = (float*)d_out;

    char* ws = (char*)d_ws;
    unsigned short* xh = (unsigned short*)(ws);                      // 8MB (later mh)
    unsigned short* xl = (unsigned short*)(ws + ((size_t) 8 << 20)); // 8MB (later ml)
    unsigned short* qh = (unsigned short*)(ws + ((size_t)16 << 20));
    unsigned short* qll= (unsigned short*)(ws + ((size_t)24 << 20));
    unsigned short* kh = (unsigned short*)(ws + ((size_t)32 << 20));
    unsigned short* vt = (unsigned short*)(ws + ((size_t)40 << 20)); // V^T [bh][d][s]
    unsigned short* wc_h = (unsigned short*)(ws + ((size_t)48 << 20)); // 6MB
    unsigned short* wc_l = (unsigned short*)(ws + ((size_t)54 << 20)); // 6MB
    unsigned short* wo_h = wc_h;            // reuse after QKV GEMM (2MB)
    unsigned short* wo_l = (unsigned short*)(ws + ((size_t)50 << 20));
    unsigned short* mh = xh;                // x dead after QKV GEMM
    unsigned short* ml = xl;

    const dim3 blk(256);
    split_x<<<dim3(M_ * D_ / 4 / 256), blk, 0, stream>>>(x, xh, xl, M_ * D_ / 4);
    tconv_qkv<<<dim3(16, 16, 3), blk, 0, stream>>>(Wq, Wk, Wv, wc_h, wc_l);

    gemm_qkv<<<dim3(M_ / 128, 3 * D_ / 64), blk, 0, stream>>>(
        xh, xl, wc_h, wc_l, bq, bk, bv, qh, qll, kh, vt);

    tconv_w<<<dim3(16, 16), blk, 0, stream>>>(Wo, wo_h, wo_l, D_, OUT_);

    attn_mfma<<<dim3(B_ * H_, S_ / 128), blk, 0, stream>>>(
        qh, qll, kh, vt, mask, mh, ml);

    gemm_out<<<dim3(M_ / 128, OUT_ / 64), blk, 0, stream>>>(
        mh, ml, wo_h, wo_l, bo, out);
}

// Round 6
// 229.689 us; speedup vs baseline: 4.8996x; 1.0321x over previous
//
#include <hip/hip_runtime.h>
#include <math.h>

#define B_   2
#define S_   2048
#define H_   16
#define DH_  64
#define D_   1024
#define OUT_ 1024
#define M_   (B_ * S_)   // 4096

typedef __attribute__((ext_vector_type(8))) short bf16x8;
typedef __attribute__((ext_vector_type(4))) float f32x4;
typedef __attribute__((ext_vector_type(4))) short short4v;

#define MFMA(a, b, c) __builtin_amdgcn_mfma_f32_16x16x32_bf16((a), (b), (c), 0, 0, 0)

// async global->LDS, 16B per lane, LDS dest = wave-uniform base + lane*16
__device__ __forceinline__ void gl_lds16(const void* g, void* l) {
    __builtin_amdgcn_global_load_lds(
        (const __attribute__((address_space(1))) unsigned int*)g,
        (__attribute__((address_space(3))) unsigned int*)l, 16, 0, 0);
}

// truncation split: x = hi(bf16) + lo(bf16) + O(2^-16 x)
__device__ __forceinline__ void split2(float x, unsigned short& h, unsigned short& l) {
    unsigned u = __float_as_uint(x);
    h = (unsigned short)(u >> 16);
    float lo = x - __uint_as_float(u & 0xFFFF0000u);
    l = (unsigned short)(__float_as_uint(lo) >> 16);
}

__device__ __forceinline__ unsigned short bf16_rne(float x) {
    unsigned u = __float_as_uint(x);
    return (unsigned short)((u + 0x7FFFu + ((u >> 16) & 1u)) >> 16);
}

__device__ __forceinline__ float fast_exp2(float x) {
#if __has_builtin(__builtin_amdgcn_exp2f)
    return __builtin_amdgcn_exp2f(x);
#else
    return exp2f(x);
#endif
}

__device__ __forceinline__ void split8(const float4 a, const float4 b, bf16x8& h8, bf16x8& l8) {
    unsigned short h[8], l[8];
    split2(a.x, h[0], l[0]); split2(a.y, h[1], l[1]);
    split2(a.z, h[2], l[2]); split2(a.w, h[3], l[3]);
    split2(b.x, h[4], l[4]); split2(b.y, h[5], l[5]);
    split2(b.z, h[6], l[6]); split2(b.w, h[7], l[7]);
    h8 = (bf16x8){(short)h[0],(short)h[1],(short)h[2],(short)h[3],(short)h[4],(short)h[5],(short)h[6],(short)h[7]};
    l8 = (bf16x8){(short)l[0],(short)l[1],(short)l[2],(short)l[3],(short)l[4],(short)l[5],(short)l[6],(short)l[7]};
}

// pack 8 f32 -> bf16x8 with RNE (unbiased; truncation would bias P*V sums)
__device__ __forceinline__ bf16x8 pack8_rne(const float4 a, const float4 b) {
    return (bf16x8){(short)bf16_rne(a.x), (short)bf16_rne(a.y),
                    (short)bf16_rne(a.z), (short)bf16_rne(a.w),
                    (short)bf16_rne(b.x), (short)bf16_rne(b.y),
                    (short)bf16_rne(b.z), (short)bf16_rne(b.w)};
}

// ---------------------------------------------------------------------------
__global__ __launch_bounds__(256)
void split_x(const float* __restrict__ X, unsigned short* __restrict__ Xh,
             unsigned short* __restrict__ Xl, int n4)
{
    const int i = blockIdx.x * 256 + threadIdx.x;
    if (i >= n4) return;
    const float4 v = ((const float4*)X)[i];
    unsigned short h[4], l[4];
    split2(v.x, h[0], l[0]); split2(v.y, h[1], l[1]);
    split2(v.z, h[2], l[2]); split2(v.w, h[3], l[3]);
    ((short4v*)Xh)[i] = (short4v){(short)h[0],(short)h[1],(short)h[2],(short)h[3]};
    ((short4v*)Xl)[i] = (short4v){(short)l[0],(short)l[1],(short)l[2],(short)l[3]};
}

// ---------------------------------------------------------------------------
// transpose + split convert: W[K,N] f32 -> Th/Tl [N,K] bf16 (single weight)
// ---------------------------------------------------------------------------
__global__ __launch_bounds__(256)
void tconv_w(const float* __restrict__ W, unsigned short* __restrict__ Th,
             unsigned short* __restrict__ Tl, int K, int N)
{
    __shared__ float T[64][65];
    const int tid = threadIdx.x;
    const int k0 = blockIdx.x * 64, n0 = blockIdx.y * 64;
    #pragma unroll
    for (int p = 0; p < 4; ++p) {
        const int f = p * 256 + tid;
        const int r = f >> 4, c4 = (f & 15) << 2;
        const float4 v = *(const float4*)&W[(size_t)(k0 + r) * N + n0 + c4];
        T[r][c4] = v.x; T[r][c4 + 1] = v.y; T[r][c4 + 2] = v.z; T[r][c4 + 3] = v.w;
    }
    __syncthreads();
    #pragma unroll
    for (int p = 0; p < 4; ++p) {
        const int f = p * 256 + tid;
        const int r = f >> 4, c4 = (f & 15) << 2;
        unsigned short h[4], l[4];
        #pragma unroll
        for (int i = 0; i < 4; ++i) split2(T[c4 + i][r], h[i], l[i]);
        *(short4v*)&Th[(size_t)(n0 + r) * K + k0 + c4] =
            (short4v){(short)h[0],(short)h[1],(short)h[2],(short)h[3]};
        *(short4v*)&Tl[(size_t)(n0 + r) * K + k0 + c4] =
            (short4v){(short)l[0],(short)l[1],(short)l[2],(short)l[3]};
    }
}

// same, for the 3 QKV weights in one launch (z selects weight; out at z<<20)
__global__ __launch_bounds__(256)
void tconv_qkv(const float* __restrict__ W0, const float* __restrict__ W1,
               const float* __restrict__ W2, unsigned short* __restrict__ Th,
               unsigned short* __restrict__ Tl)
{
    __shared__ float T[64][65];
    const int z = blockIdx.z;
    const float* W = (z == 0) ? W0 : (z == 1) ? W1 : W2;
    unsigned short* th = Th + ((size_t)z << 20);
    unsigned short* tl = Tl + ((size_t)z << 20);
    const int tid = threadIdx.x;
    const int k0 = blockIdx.x * 64, n0 = blockIdx.y * 64;
    #pragma unroll
    for (int p = 0; p < 4; ++p) {
        const int f = p * 256 + tid;
        const int r = f >> 4, c4 = (f & 15) << 2;
        const float4 v = *(const float4*)&W[(size_t)(k0 + r) * D_ + n0 + c4];
        T[r][c4] = v.x; T[r][c4 + 1] = v.y; T[r][c4 + 2] = v.z; T[r][c4 + 3] = v.w;
    }
    __syncthreads();
    #pragma unroll
    for (int p = 0; p < 4; ++p) {
        const int f = p * 256 + tid;
        const int r = f >> 4, c4 = (f & 15) << 2;
        unsigned short h[4], l[4];
        #pragma unroll
        for (int i = 0; i < 4; ++i) split2(T[c4 + i][r], h[i], l[i]);
        *(short4v*)&th[(size_t)(n0 + r) * D_ + k0 + c4] =
            (short4v){(short)h[0],(short)h[1],(short)h[2],(short)h[3]};
        *(short4v*)&tl[(size_t)(n0 + r) * D_ + k0 + c4] =
            (short4v){(short)l[0],(short)l[1],(short)l[2],(short)l[3]};
    }
}

// ---------------------------------------------------------------------------
// Merged QKV GEMM. A = xh/xl [4096][1024], B = wc_h/wc_l [3072][1024].
// Q -> hi/lo head-blocked [bh][s][64]; K -> hi RNE head-blocked;
// V -> hi RNE TRANSPOSED [bh][d][s] (so attention needs no transpose).
// ---------------------------------------------------------------------------
__global__ __launch_bounds__(256, 3)
void gemm_qkv(const unsigned short* __restrict__ Ah, const unsigned short* __restrict__ Al,
              const unsigned short* __restrict__ Bh, const unsigned short* __restrict__ Bl,
              const float* __restrict__ bq, const float* __restrict__ bk,
              const float* __restrict__ bv,
              unsigned short* __restrict__ Oqh, unsigned short* __restrict__ Oql,
              unsigned short* __restrict__ Okh, unsigned short* __restrict__ Ovt)
{
    __shared__ unsigned short As_h[128 * 64], As_l[128 * 64];
    __shared__ unsigned short Bs_h[64 * 64],  Bs_l[64 * 64];

    const int tid = threadIdx.x;
    const int lane = tid & 63, w = tid >> 6;
    const int wm = w >> 1, wn = w & 1;
    const int l15 = lane & 15, l4 = lane >> 4;
    const int lr = lane >> 3, lc = lane & 7;
    const int m0 = blockIdx.x * 128, n0 = blockIdx.y * 64;

    f32x4 acc[4][2];
    #pragma unroll
    for (int i = 0; i < 4; ++i)
        #pragma unroll
        for (int j = 0; j < 2; ++j) acc[i][j] = (f32x4){0.f, 0.f, 0.f, 0.f};

    for (int kt = 0; kt < D_; kt += 64) {
        __syncthreads();
        #pragma unroll
        for (int t = 0; t < 4; ++t) {
            const int row = w * 32 + t * 8 + lr;
            const int kc = lc ^ (row & 7);
            const size_t g = (size_t)(m0 + row) * D_ + kt + kc * 8;
            gl_lds16(&Ah[g], &As_h[(w * 32 + t * 8) * 64]);
            gl_lds16(&Al[g], &As_l[(w * 32 + t * 8) * 64]);
        }
        #pragma unroll
        for (int t = 0; t < 2; ++t) {
            const int row = w * 16 + t * 8 + lr;
            const int kc = lc ^ (row & 7);
            const size_t g = (size_t)(n0 + row) * D_ + kt + kc * 8;
            gl_lds16(&Bh[g], &Bs_h[(w * 16 + t * 8) * 64]);
            gl_lds16(&Bl[g], &Bs_l[(w * 16 + t * 8) * 64]);
        }
        __syncthreads();

        #pragma unroll
        for (int kk = 0; kk < 2; ++kk) {
            bf16x8 ah[4], al[4], bh2[2], bl2[2];
            #pragma unroll
            for (int i = 0; i < 4; ++i) {
                const int row = wm * 64 + i * 16 + l15;
                const int off = row * 64 + (((kk * 4 + l4) ^ (row & 7)) << 3);
                ah[i] = *(const bf16x8*)&As_h[off];
                al[i] = *(const bf16x8*)&As_l[off];
            }
            #pragma unroll
            for (int j = 0; j < 2; ++j) {
                const int row = wn * 32 + j * 16 + l15;
                const int off = row * 64 + (((kk * 4 + l4) ^ (row & 7)) << 3);
                bh2[j] = *(const bf16x8*)&Bs_h[off];
                bl2[j] = *(const bf16x8*)&Bs_l[off];
            }
            #pragma unroll
            for (int i = 0; i < 4; ++i)
                #pragma unroll
                for (int j = 0; j < 2; ++j) {
                    acc[i][j] = MFMA(ah[i], bh2[j], acc[i][j]);
                    acc[i][j] = MFMA(ah[i], bl2[j], acc[i][j]);
                    acc[i][j] = MFMA(al[i], bh2[j], acc[i][j]);
                }
        }
    }

    const int idx = n0 >> 10;   // 0=Q 1=K 2=V (uniform per block)
    const float* bp = (idx == 0) ? bq : (idx == 1) ? bk : bv;
    #pragma unroll
    for (int i = 0; i < 4; ++i) {
        const int m = m0 + wm * 64 + i * 16 + l4 * 4;
        #pragma unroll
        for (int j = 0; j < 2; ++j) {
            const int nG = n0 + wn * 32 + j * 16 + l15;
            const int c = nG & 1023;
            const float bvv = bp[c];
            const int hh = c >> 6, dd = c & 63, bb = m >> 11;
            if (idx == 0) {
                const size_t base = ((size_t)(bb * H_ + hh) * S_ + (m & 2047)) * 64 + dd;
                #pragma unroll
                for (int r = 0; r < 4; ++r) {
                    unsigned short vh, vl;
                    split2(acc[i][j][r] + bvv, vh, vl);
                    Oqh[base + (size_t)r * 64] = vh;
                    Oql[base + (size_t)r * 64] = vl;
                }
            } else if (idx == 1) {
                const size_t base = ((size_t)(bb * H_ + hh) * S_ + (m & 2047)) * 64 + dd;
                #pragma unroll
                for (int r = 0; r < 4; ++r)
                    Okh[base + (size_t)r * 64] = bf16_rne(acc[i][j][r] + bvv);
            } else {
                // V^T: [bh][d][s]; 4 consecutive s -> one 8B store
                unsigned short pv[4];
                #pragma unroll
                for (int r = 0; r < 4; ++r) pv[r] = bf16_rne(acc[i][j][r] + bvv);
                *(short4v*)&Ovt[((size_t)(bb * H_ + hh) * 64 + dd) * (size_t)S_ + (m & 2047)] =
                    (short4v){(short)pv[0],(short)pv[1],(short)pv[2],(short)pv[3]};
            }
        }
    }
}

// ---------------------------------------------------------------------------
// Output GEMM: out[M][1024] f32 = msgs(hi/lo) @ WoT(hi/lo) + bo
// ---------------------------------------------------------------------------
__global__ __launch_bounds__(256, 3)
void gemm_out(const unsigned short* __restrict__ Ah, const unsigned short* __restrict__ Al,
              const unsigned short* __restrict__ Bh, const unsigned short* __restrict__ Bl,
              const float* __restrict__ bias, float* __restrict__ Cf)
{
    __shared__ unsigned short As_h[128 * 64], As_l[128 * 64];
    __shared__ unsigned short Bs_h[64 * 64],  Bs_l[64 * 64];

    const int tid = threadIdx.x;
    const int lane = tid & 63, w = tid >> 6;
    const int wm = w >> 1, wn = w & 1;
    const int l15 = lane & 15, l4 = lane >> 4;
    const int lr = lane >> 3, lc = lane & 7;
    const int m0 = blockIdx.x * 128, n0 = blockIdx.y * 64;

    f32x4 acc[4][2];
    #pragma unroll
    for (int i = 0; i < 4; ++i)
        #pragma unroll
        for (int j = 0; j < 2; ++j) acc[i][j] = (f32x4){0.f, 0.f, 0.f, 0.f};

    for (int kt = 0; kt < D_; kt += 64) {
        __syncthreads();
        #pragma unroll
        for (int t = 0; t < 4; ++t) {
            const int row = w * 32 + t * 8 + lr;
            const int kc = lc ^ (row & 7);
            const size_t g = (size_t)(m0 + row) * D_ + kt + kc * 8;
            gl_lds16(&Ah[g], &As_h[(w * 32 + t * 8) * 64]);
            gl_lds16(&Al[g], &As_l[(w * 32 + t * 8) * 64]);
        }
        #pragma unroll
        for (int t = 0; t < 2; ++t) {
            const int row = w * 16 + t * 8 + lr;
            const int kc = lc ^ (row & 7);
            const size_t g = (size_t)(n0 + row) * D_ + kt + kc * 8;
            gl_lds16(&Bh[g], &Bs_h[(w * 16 + t * 8) * 64]);
            gl_lds16(&Bl[g], &Bs_l[(w * 16 + t * 8) * 64]);
        }
        __syncthreads();

        #pragma unroll
        for (int kk = 0; kk < 2; ++kk) {
            bf16x8 ah[4], al[4], bh2[2], bl2[2];
            #pragma unroll
            for (int i = 0; i < 4; ++i) {
                const int row = wm * 64 + i * 16 + l15;
                const int off = row * 64 + (((kk * 4 + l4) ^ (row & 7)) << 3);
                ah[i] = *(const bf16x8*)&As_h[off];
                al[i] = *(const bf16x8*)&As_l[off];
            }
            #pragma unroll
            for (int j = 0; j < 2; ++j) {
                const int row = wn * 32 + j * 16 + l15;
                const int off = row * 64 + (((kk * 4 + l4) ^ (row & 7)) << 3);
                bh2[j] = *(const bf16x8*)&Bs_h[off];
                bl2[j] = *(const bf16x8*)&Bs_l[off];
            }
            #pragma unroll
            for (int i = 0; i < 4; ++i)
                #pragma unroll
                for (int j = 0; j < 2; ++j) {
                    acc[i][j] = MFMA(ah[i], bh2[j], acc[i][j]);
                    acc[i][j] = MFMA(ah[i], bl2[j], acc[i][j]);
                    acc[i][j] = MFMA(al[i], bh2[j], acc[i][j]);
                }
        }
    }

    #pragma unroll
    for (int i = 0; i < 4; ++i) {
        const int m = m0 + wm * 64 + i * 16 + l4 * 4;
        #pragma unroll
        for (int j = 0; j < 2; ++j) {
            const int n = n0 + wn * 32 + j * 16 + l15;
            const float bvv = bias[n];
            #pragma unroll
            for (int r = 0; r < 4; ++r)
                Cf[(size_t)(m + r) * OUT_ + n] = acc[i][j][r] + bvv;
        }
    }
}

// ---------------------------------------------------------------------------
// Flash attention. Q hi/lo [bh][s][64], K hi [bh][s][64], V^T hi [bh][d][s].
// Grid (B*H, S/128); 4 waves x 32 q rows. Log2-domain softmax with ADDITIVE
// masking (masked -> -1e30 -> exp2 underflows to exactly 0; no per-element
// guard). m2 init -1e5 so fully-masked rows give p=0, l=0 -> output 0.
// P converted hi-only (RNE, unbiased). Defer-max; l reduced in epilogue.
// ---------------------------------------------------------------------------
__global__ __launch_bounds__(256, 3)
void attn_mfma(const unsigned short* __restrict__ Qh, const unsigned short* __restrict__ Ql,
               const unsigned short* __restrict__ Kh, const unsigned short* __restrict__ Vt,
               const float* __restrict__ mask,
               unsigned short* __restrict__ Mh, unsigned short* __restrict__ Ml)
{
    __shared__ unsigned short Ks[64 * 64];    // [key][k-chunks swizzled]
    __shared__ unsigned short Vts[64 * 64];   // [d][key-chunks swizzled]
    __shared__ float Ps[128][36];
    __shared__ float mk_s[64];

    const float SC2  = 0.125f * 1.4426950408889634f;  // score->log2 domain
    const float THR2 = 11.5415603f;                   // 8 * log2(e)
    const float MINIT = -1e5f;
    const float NEGB  = -1e30f;

    const int tid = threadIdx.x;
    const int lane = tid & 63, w = tid >> 6;
    const int l15 = lane & 15, l4 = lane >> 4;
    const int bh = blockIdx.x, b = bh >> 4;
    const int q0 = blockIdx.y * 128;
    const int qw = q0 + w * 32;

    // Q fragments (hi/lo) from pre-split global; additive q-mask per row
    bf16x8 qh[2][2], ql[2][2];
    float addq[2][4];
    #pragma unroll
    for (int mi = 0; mi < 2; ++mi) {
        const int qr = qw + mi * 16 + l15;
        const size_t qbase = ((size_t)bh * S_ + qr) * 64;
        #pragma unroll
        for (int kk = 0; kk < 2; ++kk) {
            qh[mi][kk] = *(const bf16x8*)&Qh[qbase + kk * 32 + l4 * 8];
            ql[mi][kk] = *(const bf16x8*)&Ql[qbase + kk * 32 + l4 * 8];
        }
        #pragma unroll
        for (int r = 0; r < 4; ++r)
            addq[mi][r] = (mask[(size_t)b * S_ + qw + mi * 16 + l4 * 4 + r] != 0.f)
                        ? 0.f : NEGB;
    }

    float m2[2][4], lp[2][4];
    f32x4 O[2][4];
    #pragma unroll
    for (int mi = 0; mi < 2; ++mi)
        #pragma unroll
        for (int r = 0; r < 4; ++r) {
            m2[mi][r] = MINIT; lp[mi][r] = 0.f;
            O[mi][r] = (f32x4){0.f, 0.f, 0.f, 0.f};
        }

    for (int kt = 0; kt < S_; kt += 64) {
        __syncthreads();
        // K hi: rows = key; V^T hi: rows = d. Same linear staging pattern.
        #pragma unroll
        for (int t = 0; t < 2; ++t) {
            const int row = w * 16 + t * 8 + (lane >> 3);
            const int kc = (lane & 7) ^ (row & 7);
            gl_lds16(&Kh[((size_t)bh * S_ + kt + row) * 64 + kc * 8],
                     &Ks[(w * 16 + t * 8) * 64]);
            gl_lds16(&Vt[((size_t)bh * 64 + row) * (size_t)S_ + kt + kc * 8],
                     &Vts[(w * 16 + t * 8) * 64]);
        }
        if (tid < 64) mk_s[tid] = mask[(size_t)b * S_ + kt + tid];
        __syncthreads();

        // QK^T (K hi-only): s rows=q (l4,r), cols=key (nf*16+l15)
        f32x4 s[2][4];
        #pragma unroll
        for (int mi = 0; mi < 2; ++mi)
            #pragma unroll
            for (int nf = 0; nf < 4; ++nf) s[mi][nf] = (f32x4){0.f, 0.f, 0.f, 0.f};
        #pragma unroll
        for (int nf = 0; nf < 4; ++nf) {
            const int krow = nf * 16 + l15;
            #pragma unroll
            for (int kk = 0; kk < 2; ++kk) {
                const int off = krow * 64 + (((kk * 4 + l4) ^ (krow & 7)) << 3);
                const bf16x8 kh8 = *(const bf16x8*)&Ks[off];
                #pragma unroll
                for (int mi = 0; mi < 2; ++mi) {
                    s[mi][nf] = MFMA(qh[mi][kk], kh8, s[mi][nf]);
                    s[mi][nf] = MFMA(ql[mi][kk], kh8, s[mi][nf]);
                }
            }
        }

        // additive mask + log2 scale; defer-max gate
        float addk[4];
        #pragma unroll
        for (int nf = 0; nf < 4; ++nf)
            addk[nf] = (mk_s[nf * 16 + l15] != 0.f) ? 0.f : NEGB;

        float lm[2][4];
        bool need = false;
        #pragma unroll
        for (int mi = 0; mi < 2; ++mi)
            #pragma unroll
            for (int r = 0; r < 4; ++r) {
                const float aq = addq[mi][r];
                float v0 = fmaf(s[mi][0][r], SC2, addk[0]) + aq;
                float v1 = fmaf(s[mi][1][r], SC2, addk[1]) + aq;
                float v2 = fmaf(s[mi][2][r], SC2, addk[2]) + aq;
                float v3 = fmaf(s[mi][3][r], SC2, addk[3]) + aq;
                s[mi][0][r] = v0; s[mi][1][r] = v1;
                s[mi][2][r] = v2; s[mi][3][r] = v3;
                const float rm = fmaxf(fmaxf(v0, v1), fmaxf(v2, v3));
                lm[mi][r] = rm;
                need |= (rm > m2[mi][r] + THR2);
            }

        if (__any(need)) {   // occasional: full row-max reduce + rescale
            #pragma unroll
            for (int mi = 0; mi < 2; ++mi)
                #pragma unroll
                for (int r = 0; r < 4; ++r) {
                    float rm = lm[mi][r];
                    rm = fmaxf(rm, __shfl_xor(rm, 1));
                    rm = fmaxf(rm, __shfl_xor(rm, 2));
                    rm = fmaxf(rm, __shfl_xor(rm, 4));
                    rm = fmaxf(rm, __shfl_xor(rm, 8));
                    const float mnew = fmaxf(m2[mi][r], rm);
                    const float sc = fast_exp2(m2[mi][r] - mnew);
                    lp[mi][r] *= sc;
                    m2[mi][r] = mnew;
                    #pragma unroll
                    for (int df = 0; df < 4; ++df) O[mi][df][r] *= sc;
                }
        }

        // exp2 (masked entries underflow to exactly 0) + per-lane partial l
        #pragma unroll
        for (int mi = 0; mi < 2; ++mi)
            #pragma unroll
            for (int r = 0; r < 4; ++r) {
                const float mm = m2[mi][r];
                float rs = 0.f;
                #pragma unroll
                for (int nf = 0; nf < 4; ++nf) {
                    const float pv = fast_exp2(s[mi][nf][r] - mm);
                    s[mi][nf][r] = pv;
                    rs += pv;
                }
                lp[mi][r] += rs;
            }

        // PV per key-half: P via wave-private LDS transpose (hi-only, RNE)
        #pragma unroll
        for (int kk = 0; kk < 2; ++kk) {
            #pragma unroll
            for (int mi = 0; mi < 2; ++mi)
                #pragma unroll
                for (int nh = 0; nh < 2; ++nh)
                    #pragma unroll
                    for (int r = 0; r < 4; ++r)
                        Ps[w * 32 + mi * 16 + l4 * 4 + r][nh * 16 + l15] = s[mi][kk * 2 + nh][r];

            bf16x8 ph[2];
            #pragma unroll
            for (int mi = 0; mi < 2; ++mi) {
                const float* pr = &Ps[w * 32 + mi * 16 + l15][l4 * 8];
                ph[mi] = pack8_rne(*(const float4*)pr, *(const float4*)(pr + 4));
            }

            #pragma unroll
            for (int df = 0; df < 4; ++df) {
                const int vrow = df * 16 + l15;
                const int off = vrow * 64 + (((kk * 4 + l4) ^ (vrow & 7)) << 3);
                const bf16x8 vb = *(const bf16x8*)&Vts[off];
                #pragma unroll
                for (int mi = 0; mi < 2; ++mi)
                    O[mi][df] = MFMA(ph[mi], vb, O[mi][df]);
            }
        }
    }

    // epilogue: reduce l partials across the row's 16 lanes; normalize; write
    #pragma unroll
    for (int mi = 0; mi < 2; ++mi)
        #pragma unroll
        for (int r = 0; r < 4; ++r) {
            float t = lp[mi][r];
            t += __shfl_xor(t, 1);
            t += __shfl_xor(t, 2);
            t += __shfl_xor(t, 4);
            t += __shfl_xor(t, 8);
            const float inv = (t > 0.f) ? 1.f / t : 0.f;
            const int qr = qw + mi * 16 + l4 * 4 + r;
            const size_t base = ((size_t)b * S_ + qr) * D_ + (bh & 15) * DH_;
            #pragma unroll
            for (int df = 0; df < 4; ++df) {
                unsigned short vh, vl;
                split2(O[mi][df][r] * inv, vh, vl);
                Mh[base + df * 16 + l15] = vh;
                Ml[base + df * 16 + l15] = vl;
            }
        }
}

// ---------------------------------------------------------------------------
extern "C" void kernel_launch(void* const* d_in, const int* in_sizes, int n_in,
                              void* d_out, int out_size, void* d_ws, size_t ws_size,
                              hipStream_t stream)
{
    const float* x    = (const float*)d_in[0];
    const float* mask = (const float*)d_in[1];
    const float* Wq   = (const float*)d_in[2];
    const float* bq   = (const float*)d_in[3];
    const float* Wk   = (const float*)d_in[4];
    const float* bk   = (const float*)d_in[5];
    const float* Wv   = (const float*)d_in[6];
    const float* bv   = (const float*)d_in[7];
    const float* Wo   = (const float*)d_in[8];
    const float* bo   = (const float*)d_in[9];
    float* out = (float*)d_out;

    char* ws = (char*)d_ws;
    unsigned short* xh = (unsigned short*)(ws);                      // 8MB (later mh)
    unsigned short* xl = (unsigned short*)(ws + ((size_t) 8 << 20)); // 8MB (later ml)
    unsigned short* qh = (unsigned short*)(ws + ((size_t)16 << 20));
    unsigned short* qll= (unsigned short*)(ws + ((size_t)24 << 20));
    unsigned short* kh = (unsigned short*)(ws + ((size_t)32 << 20));
    unsigned short* vt = (unsigned short*)(ws + ((size_t)40 << 20)); // V^T [bh][d][s]
    unsigned short* wc_h = (unsigned short*)(ws + ((size_t)48 << 20)); // 6MB
    unsigned short* wc_l = (unsigned short*)(ws + ((size_t)54 << 20)); // 6MB
    unsigned short* wo_h = wc_h;            // reuse after QKV GEMM (2MB)
    unsigned short* wo_l = (unsigned short*)(ws + ((size_t)50 << 20));
    unsigned short* mh = xh;                // x dead after QKV GEMM
    unsigned short* ml = xl;

    const dim3 blk(256);
    split_x<<<dim3(M_ * D_ / 4 / 256), blk, 0, stream>>>(x, xh, xl, M_ * D_ / 4);
    tconv_qkv<<<dim3(16, 16, 3), blk, 0, stream>>>(Wq, Wk, Wv, wc_h, wc_l);

    gemm_qkv<<<dim3(M_ / 128, 3 * D_ / 64), blk, 0, stream>>>(
        xh, xl, wc_h, wc_l, bq, bk, bv, qh, qll, kh, vt);

    tconv_w<<<dim3(16, 16), blk, 0, stream>>>(Wo, wo_h, wo_l, D_, OUT_);

    attn_mfma<<<dim3(B_ * H_, S_ / 128), blk, 0, stream>>>(
        qh, qll, kh, vt, mask, mh, ml);

    gemm_out<<<dim3(M_ / 128, OUT_ / 64), blk, 0, stream>>>(
        mh, ml, wo_h, wo_l, bo, out);
}

// Round 7
// 227.707 us; speedup vs baseline: 4.9422x; 1.0087x over previous
//
#include <hip/hip_runtime.h>
#include <math.h>

#define B_   2
#define S_   2048
#define H_   16
#define DH_  64
#define D_   1024
#define OUT_ 1024
#define M_   (B_ * S_)   // 4096

typedef __attribute__((ext_vector_type(8))) short bf16x8;
typedef __attribute__((ext_vector_type(4))) float f32x4;
typedef __attribute__((ext_vector_type(4))) short short4v;

#define MFMA(a, b, c) __builtin_amdgcn_mfma_f32_16x16x32_bf16((a), (b), (c), 0, 0, 0)

// async global->LDS, 16B per lane, LDS dest = wave-uniform base + lane*16
__device__ __forceinline__ void gl_lds16(const void* g, void* l) {
    __builtin_amdgcn_global_load_lds(
        (const __attribute__((address_space(1))) unsigned int*)g,
        (__attribute__((address_space(3))) unsigned int*)l, 16, 0, 0);
}

// truncation split: x = hi(bf16) + lo(bf16) + O(2^-16 x)
__device__ __forceinline__ void split2(float x, unsigned short& h, unsigned short& l) {
    unsigned u = __float_as_uint(x);
    h = (unsigned short)(u >> 16);
    float lo = x - __uint_as_float(u & 0xFFFF0000u);
    l = (unsigned short)(__float_as_uint(lo) >> 16);
}

__device__ __forceinline__ unsigned short bf16_rne(float x) {
    unsigned u = __float_as_uint(x);
    return (unsigned short)((u + 0x7FFFu + ((u >> 16) & 1u)) >> 16);
}

__device__ __forceinline__ float fast_exp2(float x) {
#if __has_builtin(__builtin_amdgcn_exp2f)
    return __builtin_amdgcn_exp2f(x);
#else
    return exp2f(x);
#endif
}

// pack 8 f32 -> bf16x8 with RNE (unbiased; truncation would bias P*V sums)
__device__ __forceinline__ bf16x8 pack8_rne(const float4 a, const float4 b) {
    return (bf16x8){(short)bf16_rne(a.x), (short)bf16_rne(a.y),
                    (short)bf16_rne(a.z), (short)bf16_rne(a.w),
                    (short)bf16_rne(b.x), (short)bf16_rne(b.y),
                    (short)bf16_rne(b.z), (short)bf16_rne(b.w)};
}

// ---------------------------------------------------------------------------
__global__ __launch_bounds__(256)
void split_x(const float* __restrict__ X, unsigned short* __restrict__ Xh,
             unsigned short* __restrict__ Xl, int n4)
{
    const int i = blockIdx.x * 256 + threadIdx.x;
    if (i >= n4) return;
    const float4 v = ((const float4*)X)[i];
    unsigned short h[4], l[4];
    split2(v.x, h[0], l[0]); split2(v.y, h[1], l[1]);
    split2(v.z, h[2], l[2]); split2(v.w, h[3], l[3]);
    ((short4v*)Xh)[i] = (short4v){(short)h[0],(short)h[1],(short)h[2],(short)h[3]};
    ((short4v*)Xl)[i] = (short4v){(short)l[0],(short)l[1],(short)l[2],(short)l[3]};
}

// ---------------------------------------------------------------------------
// transpose + split convert: W[K,N] f32 -> Th/Tl [N,K] bf16 (single weight)
// ---------------------------------------------------------------------------
__global__ __launch_bounds__(256)
void tconv_w(const float* __restrict__ W, unsigned short* __restrict__ Th,
             unsigned short* __restrict__ Tl, int K, int N)
{
    __shared__ float T[64][65];
    const int tid = threadIdx.x;
    const int k0 = blockIdx.x * 64, n0 = blockIdx.y * 64;
    #pragma unroll
    for (int p = 0; p < 4; ++p) {
        const int f = p * 256 + tid;
        const int r = f >> 4, c4 = (f & 15) << 2;
        const float4 v = *(const float4*)&W[(size_t)(k0 + r) * N + n0 + c4];
        T[r][c4] = v.x; T[r][c4 + 1] = v.y; T[r][c4 + 2] = v.z; T[r][c4 + 3] = v.w;
    }
    __syncthreads();
    #pragma unroll
    for (int p = 0; p < 4; ++p) {
        const int f = p * 256 + tid;
        const int r = f >> 4, c4 = (f & 15) << 2;
        unsigned short h[4], l[4];
        #pragma unroll
        for (int i = 0; i < 4; ++i) split2(T[c4 + i][r], h[i], l[i]);
        *(short4v*)&Th[(size_t)(n0 + r) * K + k0 + c4] =
            (short4v){(short)h[0],(short)h[1],(short)h[2],(short)h[3]};
        *(short4v*)&Tl[(size_t)(n0 + r) * K + k0 + c4] =
            (short4v){(short)l[0],(short)l[1],(short)l[2],(short)l[3]};
    }
}

// same, for the 3 QKV weights in one launch (z selects weight; out at z<<20)
__global__ __launch_bounds__(256)
void tconv_qkv(const float* __restrict__ W0, const float* __restrict__ W1,
               const float* __restrict__ W2, unsigned short* __restrict__ Th,
               unsigned short* __restrict__ Tl)
{
    __shared__ float T[64][65];
    const int z = blockIdx.z;
    const float* W = (z == 0) ? W0 : (z == 1) ? W1 : W2;
    unsigned short* th = Th + ((size_t)z << 20);
    unsigned short* tl = Tl + ((size_t)z << 20);
    const int tid = threadIdx.x;
    const int k0 = blockIdx.x * 64, n0 = blockIdx.y * 64;
    #pragma unroll
    for (int p = 0; p < 4; ++p) {
        const int f = p * 256 + tid;
        const int r = f >> 4, c4 = (f & 15) << 2;
        const float4 v = *(const float4*)&W[(size_t)(k0 + r) * D_ + n0 + c4];
        T[r][c4] = v.x; T[r][c4 + 1] = v.y; T[r][c4 + 2] = v.z; T[r][c4 + 3] = v.w;
    }
    __syncthreads();
    #pragma unroll
    for (int p = 0; p < 4; ++p) {
        const int f = p * 256 + tid;
        const int r = f >> 4, c4 = (f & 15) << 2;
        unsigned short h[4], l[4];
        #pragma unroll
        for (int i = 0; i < 4; ++i) split2(T[c4 + i][r], h[i], l[i]);
        *(short4v*)&th[(size_t)(n0 + r) * D_ + k0 + c4] =
            (short4v){(short)h[0],(short)h[1],(short)h[2],(short)h[3]};
        *(short4v*)&tl[(size_t)(n0 + r) * D_ + k0 + c4] =
            (short4v){(short)l[0],(short)l[1],(short)l[2],(short)l[3]};
    }
}

// ---------------------------------------------------------------------------
// Merged QKV GEMM. A = xh/xl [4096][1024], B = wc_h/wc_l [3072][1024].
// Q -> hi/lo head-blocked [bh][s][64]; K -> hi RNE head-blocked;
// V -> hi RNE TRANSPOSED [bh][d][s] (so attention needs no transpose).
// ---------------------------------------------------------------------------
__global__ __launch_bounds__(256, 3)
void gemm_qkv(const unsigned short* __restrict__ Ah, const unsigned short* __restrict__ Al,
              const unsigned short* __restrict__ Bh, const unsigned short* __restrict__ Bl,
              const float* __restrict__ bq, const float* __restrict__ bk,
              const float* __restrict__ bv,
              unsigned short* __restrict__ Oqh, unsigned short* __restrict__ Oql,
              unsigned short* __restrict__ Okh, unsigned short* __restrict__ Ovt)
{
    __shared__ unsigned short As_h[128 * 64], As_l[128 * 64];
    __shared__ unsigned short Bs_h[64 * 64],  Bs_l[64 * 64];

    const int tid = threadIdx.x;
    const int lane = tid & 63, w = tid >> 6;
    const int wm = w >> 1, wn = w & 1;
    const int l15 = lane & 15, l4 = lane >> 4;
    const int lr = lane >> 3, lc = lane & 7;
    const int m0 = blockIdx.x * 128, n0 = blockIdx.y * 64;

    f32x4 acc[4][2];
    #pragma unroll
    for (int i = 0; i < 4; ++i)
        #pragma unroll
        for (int j = 0; j < 2; ++j) acc[i][j] = (f32x4){0.f, 0.f, 0.f, 0.f};

    for (int kt = 0; kt < D_; kt += 64) {
        __syncthreads();
        #pragma unroll
        for (int t = 0; t < 4; ++t) {
            const int row = w * 32 + t * 8 + lr;
            const int kc = lc ^ (row & 7);
            const size_t g = (size_t)(m0 + row) * D_ + kt + kc * 8;
            gl_lds16(&Ah[g], &As_h[(w * 32 + t * 8) * 64]);
            gl_lds16(&Al[g], &As_l[(w * 32 + t * 8) * 64]);
        }
        #pragma unroll
        for (int t = 0; t < 2; ++t) {
            const int row = w * 16 + t * 8 + lr;
            const int kc = lc ^ (row & 7);
            const size_t g = (size_t)(n0 + row) * D_ + kt + kc * 8;
            gl_lds16(&Bh[g], &Bs_h[(w * 16 + t * 8) * 64]);
            gl_lds16(&Bl[g], &Bs_l[(w * 16 + t * 8) * 64]);
        }
        __syncthreads();

        #pragma unroll
        for (int kk = 0; kk < 2; ++kk) {
            bf16x8 ah[4], al[4], bh2[2], bl2[2];
            #pragma unroll
            for (int i = 0; i < 4; ++i) {
                const int row = wm * 64 + i * 16 + l15;
                const int off = row * 64 + (((kk * 4 + l4) ^ (row & 7)) << 3);
                ah[i] = *(const bf16x8*)&As_h[off];
                al[i] = *(const bf16x8*)&As_l[off];
            }
            #pragma unroll
            for (int j = 0; j < 2; ++j) {
                const int row = wn * 32 + j * 16 + l15;
                const int off = row * 64 + (((kk * 4 + l4) ^ (row & 7)) << 3);
                bh2[j] = *(const bf16x8*)&Bs_h[off];
                bl2[j] = *(const bf16x8*)&Bs_l[off];
            }
            #pragma unroll
            for (int i = 0; i < 4; ++i)
                #pragma unroll
                for (int j = 0; j < 2; ++j) {
                    acc[i][j] = MFMA(ah[i], bh2[j], acc[i][j]);
                    acc[i][j] = MFMA(ah[i], bl2[j], acc[i][j]);
                    acc[i][j] = MFMA(al[i], bh2[j], acc[i][j]);
                }
        }
    }

    const int idx = n0 >> 10;   // 0=Q 1=K 2=V (uniform per block)
    const float* bp = (idx == 0) ? bq : (idx == 1) ? bk : bv;
    #pragma unroll
    for (int i = 0; i < 4; ++i) {
        const int m = m0 + wm * 64 + i * 16 + l4 * 4;
        #pragma unroll
        for (int j = 0; j < 2; ++j) {
            const int nG = n0 + wn * 32 + j * 16 + l15;
            const int c = nG & 1023;
            const float bvv = bp[c];
            const int hh = c >> 6, dd = c & 63, bb = m >> 11;
            if (idx == 0) {
                const size_t base = ((size_t)(bb * H_ + hh) * S_ + (m & 2047)) * 64 + dd;
                #pragma unroll
                for (int r = 0; r < 4; ++r) {
                    unsigned short vh, vl;
                    split2(acc[i][j][r] + bvv, vh, vl);
                    Oqh[base + (size_t)r * 64] = vh;
                    Oql[base + (size_t)r * 64] = vl;
                }
            } else if (idx == 1) {
                const size_t base = ((size_t)(bb * H_ + hh) * S_ + (m & 2047)) * 64 + dd;
                #pragma unroll
                for (int r = 0; r < 4; ++r)
                    Okh[base + (size_t)r * 64] = bf16_rne(acc[i][j][r] + bvv);
            } else {
                // V^T: [bh][d][s]; 4 consecutive s -> one 8B store
                unsigned short pv[4];
                #pragma unroll
                for (int r = 0; r < 4; ++r) pv[r] = bf16_rne(acc[i][j][r] + bvv);
                *(short4v*)&Ovt[((size_t)(bb * H_ + hh) * 64 + dd) * (size_t)S_ + (m & 2047)] =
                    (short4v){(short)pv[0],(short)pv[1],(short)pv[2],(short)pv[3]};
            }
        }
    }
}

// ---------------------------------------------------------------------------
// Output GEMM: out[M][1024] f32 = msgs(hi/lo) @ WoT(hi/lo) + bo
// ---------------------------------------------------------------------------
__global__ __launch_bounds__(256, 3)
void gemm_out(const unsigned short* __restrict__ Ah, const unsigned short* __restrict__ Al,
              const unsigned short* __restrict__ Bh, const unsigned short* __restrict__ Bl,
              const float* __restrict__ bias, float* __restrict__ Cf)
{
    __shared__ unsigned short As_h[128 * 64], As_l[128 * 64];
    __shared__ unsigned short Bs_h[64 * 64],  Bs_l[64 * 64];

    const int tid = threadIdx.x;
    const int lane = tid & 63, w = tid >> 6;
    const int wm = w >> 1, wn = w & 1;
    const int l15 = lane & 15, l4 = lane >> 4;
    const int lr = lane >> 3, lc = lane & 7;
    const int m0 = blockIdx.x * 128, n0 = blockIdx.y * 64;

    f32x4 acc[4][2];
    #pragma unroll
    for (int i = 0; i < 4; ++i)
        #pragma unroll
        for (int j = 0; j < 2; ++j) acc[i][j] = (f32x4){0.f, 0.f, 0.f, 0.f};

    for (int kt = 0; kt < D_; kt += 64) {
        __syncthreads();
        #pragma unroll
        for (int t = 0; t < 4; ++t) {
            const int row = w * 32 + t * 8 + lr;
            const int kc = lc ^ (row & 7);
            const size_t g = (size_t)(m0 + row) * D_ + kt + kc * 8;
            gl_lds16(&Ah[g], &As_h[(w * 32 + t * 8) * 64]);
            gl_lds16(&Al[g], &As_l[(w * 32 + t * 8) * 64]);
        }
        #pragma unroll
        for (int t = 0; t < 2; ++t) {
            const int row = w * 16 + t * 8 + lr;
            const int kc = lc ^ (row & 7);
            const size_t g = (size_t)(n0 + row) * D_ + kt + kc * 8;
            gl_lds16(&Bh[g], &Bs_h[(w * 16 + t * 8) * 64]);
            gl_lds16(&Bl[g], &Bs_l[(w * 16 + t * 8) * 64]);
        }
        __syncthreads();

        #pragma unroll
        for (int kk = 0; kk < 2; ++kk) {
            bf16x8 ah[4], al[4], bh2[2], bl2[2];
            #pragma unroll
            for (int i = 0; i < 4; ++i) {
                const int row = wm * 64 + i * 16 + l15;
                const int off = row * 64 + (((kk * 4 + l4) ^ (row & 7)) << 3);
                ah[i] = *(const bf16x8*)&As_h[off];
                al[i] = *(const bf16x8*)&As_l[off];
            }
            #pragma unroll
            for (int j = 0; j < 2; ++j) {
                const int row = wn * 32 + j * 16 + l15;
                const int off = row * 64 + (((kk * 4 + l4) ^ (row & 7)) << 3);
                bh2[j] = *(const bf16x8*)&Bs_h[off];
                bl2[j] = *(const bf16x8*)&Bs_l[off];
            }
            #pragma unroll
            for (int i = 0; i < 4; ++i)
                #pragma unroll
                for (int j = 0; j < 2; ++j) {
                    acc[i][j] = MFMA(ah[i], bh2[j], acc[i][j]);
                    acc[i][j] = MFMA(ah[i], bl2[j], acc[i][j]);
                    acc[i][j] = MFMA(al[i], bh2[j], acc[i][j]);
                }
        }
    }

    #pragma unroll
    for (int i = 0; i < 4; ++i) {
        const int m = m0 + wm * 64 + i * 16 + l4 * 4;
        #pragma unroll
        for (int j = 0; j < 2; ++j) {
            const int n = n0 + wn * 32 + j * 16 + l15;
            const float bvv = bias[n];
            #pragma unroll
            for (int r = 0; r < 4; ++r)
                Cf[(size_t)(m + r) * OUT_ + n] = acc[i][j][r] + bvv;
        }
    }
}

// ---------------------------------------------------------------------------
// Flash attention, 2-PHASE double-buffered staging.
// Q hi/lo [bh][s][64], K hi [bh][s][64], V^T hi [bh][d][s].
// Grid (B*H, S/128); 4 waves x 32 q rows. Per tile: issue next tile's
// global_load_lds FIRST, compute current, then one __syncthreads (vmcnt(0)
// drain lands after ~2000 cyc of compute instead of immediately).
// Log2-domain softmax, additive masking, defer-max, epilogue l-reduce.
// ---------------------------------------------------------------------------
__global__ __launch_bounds__(256, 3)
void attn_mfma(const unsigned short* __restrict__ Qh, const unsigned short* __restrict__ Ql,
               const unsigned short* __restrict__ Kh, const unsigned short* __restrict__ Vt,
               const float* __restrict__ mask,
               unsigned short* __restrict__ Mh, unsigned short* __restrict__ Ml)
{
    __shared__ unsigned short Ks[2][64 * 64];    // [buf][key][k-chunks swizzled]
    __shared__ unsigned short Vts[2][64 * 64];   // [buf][d][key-chunks swizzled]
    __shared__ float Ps[128][36];
    __shared__ float mk_s[2][64];

    const float SC2  = 0.125f * 1.4426950408889634f;  // score->log2 domain
    const float THR2 = 11.5415603f;                   // 8 * log2(e)
    const float MINIT = -1e5f;
    const float NEGB  = -1e30f;

    const int tid = threadIdx.x;
    const int lane = tid & 63, w = tid >> 6;
    const int l15 = lane & 15, l4 = lane >> 4;
    const int bh = blockIdx.x, b = bh >> 4;
    const int q0 = blockIdx.y * 128;
    const int qw = q0 + w * 32;

    // staging decode (constant per thread)
    const int srow = w * 16 + (lane >> 3);           // row within 0..63 (t adds 8)
    const int skc  = (lane & 7) ^ (srow & 7);        // pre-swizzled source chunk

    // Q fragments (hi/lo) from pre-split global; additive q-mask per row
    bf16x8 qh[2][2], ql[2][2];
    float addq[2][4];
    #pragma unroll
    for (int mi = 0; mi < 2; ++mi) {
        const int qr = qw + mi * 16 + l15;
        const size_t qbase = ((size_t)bh * S_ + qr) * 64;
        #pragma unroll
        for (int kk = 0; kk < 2; ++kk) {
            qh[mi][kk] = *(const bf16x8*)&Qh[qbase + kk * 32 + l4 * 8];
            ql[mi][kk] = *(const bf16x8*)&Ql[qbase + kk * 32 + l4 * 8];
        }
        #pragma unroll
        for (int r = 0; r < 4; ++r)
            addq[mi][r] = (mask[(size_t)b * S_ + qw + mi * 16 + l4 * 4 + r] != 0.f)
                        ? 0.f : NEGB;
    }

    float m2[2][4], lp[2][4];
    f32x4 O[2][4];
    #pragma unroll
    for (int mi = 0; mi < 2; ++mi)
        #pragma unroll
        for (int r = 0; r < 4; ++r) {
            m2[mi][r] = MINIT; lp[mi][r] = 0.f;
            O[mi][r] = (f32x4){0.f, 0.f, 0.f, 0.f};
        }

    // ---- staging helper (macro keeps gl_lds dest wave-uniform) ----
#define STAGE(KT, SEL)                                                         \
    do {                                                                       \
        _Pragma("unroll")                                                      \
        for (int t = 0; t < 2; ++t) {                                          \
            const int row = srow + t * 8;                                      \
            gl_lds16(&Kh[((size_t)bh * S_ + (KT) + row) * 64 + skc * 8],       \
                     &Ks[SEL][(w * 16 + t * 8) * 64]);                         \
            gl_lds16(&Vt[((size_t)bh * 64 + row) * (size_t)S_ + (KT) + skc * 8],\
                     &Vts[SEL][(w * 16 + t * 8) * 64]);                        \
        }                                                                      \
        if (tid < 64) mk_s[SEL][tid] = mask[(size_t)b * S_ + (KT) + tid];      \
    } while (0)

    // prologue: stage tile 0 into buffer 0
    STAGE(0, 0);
    __syncthreads();   // vmcnt(0)+lgkmcnt(0) drain + barrier

    int cur = 0;
    for (int kt = 0; kt < S_; kt += 64, cur ^= 1) {
        // issue NEXT tile's async loads first — hidden under this tile's compute
        if (kt + 64 < S_) STAGE(kt + 64, cur ^ 1);

        // QK^T (K hi-only): s rows=q (l4,r), cols=key (nf*16+l15)
        f32x4 s[2][4];
        #pragma unroll
        for (int mi = 0; mi < 2; ++mi)
            #pragma unroll
            for (int nf = 0; nf < 4; ++nf) s[mi][nf] = (f32x4){0.f, 0.f, 0.f, 0.f};
        #pragma unroll
        for (int nf = 0; nf < 4; ++nf) {
            const int krow = nf * 16 + l15;
            #pragma unroll
            for (int kk = 0; kk < 2; ++kk) {
                const int off = krow * 64 + (((kk * 4 + l4) ^ (krow & 7)) << 3);
                const bf16x8 kh8 = *(const bf16x8*)&Ks[cur][off];
                #pragma unroll
                for (int mi = 0; mi < 2; ++mi) {
                    s[mi][nf] = MFMA(qh[mi][kk], kh8, s[mi][nf]);
                    s[mi][nf] = MFMA(ql[mi][kk], kh8, s[mi][nf]);
                }
            }
        }

        // additive mask + log2 scale; defer-max gate
        float addk[4];
        #pragma unroll
        for (int nf = 0; nf < 4; ++nf)
            addk[nf] = (mk_s[cur][nf * 16 + l15] != 0.f) ? 0.f : NEGB;

        float lm[2][4];
        bool need = false;
        #pragma unroll
        for (int mi = 0; mi < 2; ++mi)
            #pragma unroll
            for (int r = 0; r < 4; ++r) {
                const float aq = addq[mi][r];
                float v0 = fmaf(s[mi][0][r], SC2, addk[0]) + aq;
                float v1 = fmaf(s[mi][1][r], SC2, addk[1]) + aq;
                float v2 = fmaf(s[mi][2][r], SC2, addk[2]) + aq;
                float v3 = fmaf(s[mi][3][r], SC2, addk[3]) + aq;
                s[mi][0][r] = v0; s[mi][1][r] = v1;
                s[mi][2][r] = v2; s[mi][3][r] = v3;
                const float rm = fmaxf(fmaxf(v0, v1), fmaxf(v2, v3));
                lm[mi][r] = rm;
                need |= (rm > m2[mi][r] + THR2);
            }

        if (__any(need)) {   // occasional: full row-max reduce + rescale
            #pragma unroll
            for (int mi = 0; mi < 2; ++mi)
                #pragma unroll
                for (int r = 0; r < 4; ++r) {
                    float rm = lm[mi][r];
                    rm = fmaxf(rm, __shfl_xor(rm, 1));
                    rm = fmaxf(rm, __shfl_xor(rm, 2));
                    rm = fmaxf(rm, __shfl_xor(rm, 4));
                    rm = fmaxf(rm, __shfl_xor(rm, 8));
                    const float mnew = fmaxf(m2[mi][r], rm);
                    const float sc = fast_exp2(m2[mi][r] - mnew);
                    lp[mi][r] *= sc;
                    m2[mi][r] = mnew;
                    #pragma unroll
                    for (int df = 0; df < 4; ++df) O[mi][df][r] *= sc;
                }
        }

        // exp2 (masked entries underflow to exactly 0) + per-lane partial l
        #pragma unroll
        for (int mi = 0; mi < 2; ++mi)
            #pragma unroll
            for (int r = 0; r < 4; ++r) {
                const float mm = m2[mi][r];
                float rs = 0.f;
                #pragma unroll
                for (int nf = 0; nf < 4; ++nf) {
                    const float pv = fast_exp2(s[mi][nf][r] - mm);
                    s[mi][nf][r] = pv;
                    rs += pv;
                }
                lp[mi][r] += rs;
            }

        // PV per key-half: P via wave-private LDS transpose (hi-only, RNE)
        #pragma unroll
        for (int kk = 0; kk < 2; ++kk) {
            #pragma unroll
            for (int mi = 0; mi < 2; ++mi)
                #pragma unroll
                for (int nh = 0; nh < 2; ++nh)
                    #pragma unroll
                    for (int r = 0; r < 4; ++r)
                        Ps[w * 32 + mi * 16 + l4 * 4 + r][nh * 16 + l15] = s[mi][kk * 2 + nh][r];

            bf16x8 ph[2];
            #pragma unroll
            for (int mi = 0; mi < 2; ++mi) {
                const float* pr = &Ps[w * 32 + mi * 16 + l15][l4 * 8];
                ph[mi] = pack8_rne(*(const float4*)pr, *(const float4*)(pr + 4));
            }

            #pragma unroll
            for (int df = 0; df < 4; ++df) {
                const int vrow = df * 16 + l15;
                const int off = vrow * 64 + (((kk * 4 + l4) ^ (vrow & 7)) << 3);
                const bf16x8 vb = *(const bf16x8*)&Vts[cur][off];
                #pragma unroll
                for (int mi = 0; mi < 2; ++mi)
                    O[mi][df] = MFMA(ph[mi], vb, O[mi][df]);
            }
        }

        // single barrier per tile: drains prefetch (vmcnt) and LDS reads,
        // making buf[cur] safe to overwrite next iteration.
        __syncthreads();
    }
#undef STAGE

    // epilogue: reduce l partials across the row's 16 lanes; normalize; write
    #pragma unroll
    for (int mi = 0; mi < 2; ++mi)
        #pragma unroll
        for (int r = 0; r < 4; ++r) {
            float t = lp[mi][r];
            t += __shfl_xor(t, 1);
            t += __shfl_xor(t, 2);
            t += __shfl_xor(t, 4);
            t += __shfl_xor(t, 8);
            const float inv = (t > 0.f) ? 1.f / t : 0.f;
            const int qr = qw + mi * 16 + l4 * 4 + r;
            const size_t base = ((size_t)b * S_ + qr) * D_ + (bh & 15) * DH_;
            #pragma unroll
            for (int df = 0; df < 4; ++df) {
                unsigned short vh, vl;
                split2(O[mi][df][r] * inv, vh, vl);
                Mh[base + df * 16 + l15] = vh;
                Ml[base + df * 16 + l15] = vl;
            }
        }
}

// ---------------------------------------------------------------------------
extern "C" void kernel_launch(void* const* d_in, const int* in_sizes, int n_in,
                              void* d_out, int out_size, void* d_ws, size_t ws_size,
                              hipStream_t stream)
{
    const float* x    = (const float*)d_in[0];
    const float* mask = (const float*)d_in[1];
    const float* Wq   = (const float*)d_in[2];
    const float* bq   = (const float*)d_in[3];
    const float* Wk   = (const float*)d_in[4];
    const float* bk   = (const float*)d_in[5];
    const float* Wv   = (const float*)d_in[6];
    const float* bv   = (const float*)d_in[7];
    const float* Wo   = (const float*)d_in[8];
    const float* bo   = (const float*)d_in[9];
    float* out = (float*)d_out;

    char* ws = (char*)d_ws;
    unsigned short* xh = (unsigned short*)(ws);                      // 8MB (later mh)
    unsigned short* xl = (unsigned short*)(ws + ((size_t) 8 << 20)); // 8MB (later ml)
    unsigned short* qh = (unsigned short*)(ws + ((size_t)16 << 20));
    unsigned short* qll= (unsigned short*)(ws + ((size_t)24 << 20));
    unsigned short* kh = (unsigned short*)(ws + ((size_t)32 << 20));
    unsigned short* vt = (unsigned short*)(ws + ((size_t)40 << 20)); // V^T [bh][d][s]
    unsigned short* wc_h = (unsigned short*)(ws + ((size_t)48 << 20)); // 6MB
    unsigned short* wc_l = (unsigned short*)(ws + ((size_t)54 << 20)); // 6MB
    unsigned short* wo_h = wc_h;            // reuse after QKV GEMM (2MB)
    unsigned short* wo_l = (unsigned short*)(ws + ((size_t)50 << 20));
    unsigned short* mh = xh;                // x dead after QKV GEMM
    unsigned short* ml = xl;

    const dim3 blk(256);
    split_x<<<dim3(M_ * D_ / 4 / 256), blk, 0, stream>>>(x, xh, xl, M_ * D_ / 4);
    tconv_qkv<<<dim3(16, 16, 3), blk, 0, stream>>>(Wq, Wk, Wv, wc_h, wc_l);

    gemm_qkv<<<dim3(M_ / 128, 3 * D_ / 64), blk, 0, stream>>>(
        xh, xl, wc_h, wc_l, bq, bk, bv, qh, qll, kh, vt);

    tconv_w<<<dim3(16, 16), blk, 0, stream>>>(Wo, wo_h, wo_l, D_, OUT_);

    attn_mfma<<<dim3(B_ * H_, S_ / 128), blk, 0, stream>>>(
        qh, qll, kh, vt, mask, mh, ml);

    gemm_out<<<dim3(M_ / 128, OUT_ / 64), blk, 0, stream>>>(
        mh, ml, wo_h, wo_l, bo, out);
}

// Round 8
// 218.118 us; speedup vs baseline: 5.1595x; 1.0440x over previous
//
#include <hip/hip_runtime.h>
#include <hip/hip_bf16.h>
#include <math.h>

#define B_   2
#define S_   2048
#define H_   16
#define DH_  64
#define D_   1024
#define OUT_ 1024
#define M_   (B_ * S_)   // 4096

typedef __attribute__((ext_vector_type(8))) short bf16x8;
typedef __attribute__((ext_vector_type(4))) float f32x4;
typedef __attribute__((ext_vector_type(4))) short short4v;

#define MFMA(a, b, c) __builtin_amdgcn_mfma_f32_16x16x32_bf16((a), (b), (c), 0, 0, 0)

// async global->LDS, 16B per lane, LDS dest = wave-uniform base + lane*16
__device__ __forceinline__ void gl_lds16(const void* g, void* l) {
    __builtin_amdgcn_global_load_lds(
        (const __attribute__((address_space(1))) unsigned int*)g,
        (__attribute__((address_space(3))) unsigned int*)l, 16, 0, 0);
}

// truncation split: x = hi(bf16) + lo(bf16) + O(2^-16 x)
__device__ __forceinline__ void split2(float x, unsigned short& h, unsigned short& l) {
    unsigned u = __float_as_uint(x);
    h = (unsigned short)(u >> 16);
    float lo = x - __uint_as_float(u & 0xFFFF0000u);
    l = (unsigned short)(__float_as_uint(lo) >> 16);
}

// RNE f32->bf16 via HW convert (compiler lowers to v_cvt; m240: fast path)
__device__ __forceinline__ unsigned short bf16_rne(float x) {
    return __builtin_bit_cast(unsigned short, __float2bfloat16(x));
}

__device__ __forceinline__ float fast_exp2(float x) {
#if __has_builtin(__builtin_amdgcn_exp2f)
    return __builtin_amdgcn_exp2f(x);
#else
    return exp2f(x);
#endif
}

// pack 8 f32 -> bf16x8 with RNE (unbiased)
__device__ __forceinline__ bf16x8 pack8_rne(const float4 a, const float4 b) {
    return (bf16x8){(short)bf16_rne(a.x), (short)bf16_rne(a.y),
                    (short)bf16_rne(a.z), (short)bf16_rne(a.w),
                    (short)bf16_rne(b.x), (short)bf16_rne(b.y),
                    (short)bf16_rne(b.z), (short)bf16_rne(b.w)};
}

// ---------------------------------------------------------------------------
__global__ __launch_bounds__(256)
void split_x(const float* __restrict__ X, unsigned short* __restrict__ Xh,
             unsigned short* __restrict__ Xl, int n4)
{
    const int i = blockIdx.x * 256 + threadIdx.x;
    if (i >= n4) return;
    const float4 v = ((const float4*)X)[i];
    unsigned short h[4], l[4];
    split2(v.x, h[0], l[0]); split2(v.y, h[1], l[1]);
    split2(v.z, h[2], l[2]); split2(v.w, h[3], l[3]);
    ((short4v*)Xh)[i] = (short4v){(short)h[0],(short)h[1],(short)h[2],(short)h[3]};
    ((short4v*)Xl)[i] = (short4v){(short)l[0],(short)l[1],(short)l[2],(short)l[3]};
}

// ---------------------------------------------------------------------------
// transpose + split convert: W[K,N] f32 -> Th/Tl [N,K] bf16 (single weight)
// ---------------------------------------------------------------------------
__global__ __launch_bounds__(256)
void tconv_w(const float* __restrict__ W, unsigned short* __restrict__ Th,
             unsigned short* __restrict__ Tl, int K, int N)
{
    __shared__ float T[64][65];
    const int tid = threadIdx.x;
    const int k0 = blockIdx.x * 64, n0 = blockIdx.y * 64;
    #pragma unroll
    for (int p = 0; p < 4; ++p) {
        const int f = p * 256 + tid;
        const int r = f >> 4, c4 = (f & 15) << 2;
        const float4 v = *(const float4*)&W[(size_t)(k0 + r) * N + n0 + c4];
        T[r][c4] = v.x; T[r][c4 + 1] = v.y; T[r][c4 + 2] = v.z; T[r][c4 + 3] = v.w;
    }
    __syncthreads();
    #pragma unroll
    for (int p = 0; p < 4; ++p) {
        const int f = p * 256 + tid;
        const int r = f >> 4, c4 = (f & 15) << 2;
        unsigned short h[4], l[4];
        #pragma unroll
        for (int i = 0; i < 4; ++i) split2(T[c4 + i][r], h[i], l[i]);
        *(short4v*)&Th[(size_t)(n0 + r) * K + k0 + c4] =
            (short4v){(short)h[0],(short)h[1],(short)h[2],(short)h[3]};
        *(short4v*)&Tl[(size_t)(n0 + r) * K + k0 + c4] =
            (short4v){(short)l[0],(short)l[1],(short)l[2],(short)l[3]};
    }
}

// same, for the 3 QKV weights in one launch (z selects weight; out at z<<20)
__global__ __launch_bounds__(256)
void tconv_qkv(const float* __restrict__ W0, const float* __restrict__ W1,
               const float* __restrict__ W2, unsigned short* __restrict__ Th,
               unsigned short* __restrict__ Tl)
{
    __shared__ float T[64][65];
    const int z = blockIdx.z;
    const float* W = (z == 0) ? W0 : (z == 1) ? W1 : W2;
    unsigned short* th = Th + ((size_t)z << 20);
    unsigned short* tl = Tl + ((size_t)z << 20);
    const int tid = threadIdx.x;
    const int k0 = blockIdx.x * 64, n0 = blockIdx.y * 64;
    #pragma unroll
    for (int p = 0; p < 4; ++p) {
        const int f = p * 256 + tid;
        const int r = f >> 4, c4 = (f & 15) << 2;
        const float4 v = *(const float4*)&W[(size_t)(k0 + r) * D_ + n0 + c4];
        T[r][c4] = v.x; T[r][c4 + 1] = v.y; T[r][c4 + 2] = v.z; T[r][c4 + 3] = v.w;
    }
    __syncthreads();
    #pragma unroll
    for (int p = 0; p < 4; ++p) {
        const int f = p * 256 + tid;
        const int r = f >> 4, c4 = (f & 15) << 2;
        unsigned short h[4], l[4];
        #pragma unroll
        for (int i = 0; i < 4; ++i) split2(T[c4 + i][r], h[i], l[i]);
        *(short4v*)&th[(size_t)(n0 + r) * D_ + k0 + c4] =
            (short4v){(short)h[0],(short)h[1],(short)h[2],(short)h[3]};
        *(short4v*)&tl[(size_t)(n0 + r) * D_ + k0 + c4] =
            (short4v){(short)l[0],(short)l[1],(short)l[2],(short)l[3]};
    }
}

// ---------------------------------------------------------------------------
// Merged QKV GEMM. A = xh/xl [4096][1024], B = wc_h/wc_l [3072][1024].
// Q -> hi/lo head-blocked [bh][s][64]; K -> hi RNE head-blocked;
// V -> hi RNE TRANSPOSED [bh][d][s] (so attention needs no transpose).
// ---------------------------------------------------------------------------
__global__ __launch_bounds__(256, 3)
void gemm_qkv(const unsigned short* __restrict__ Ah, const unsigned short* __restrict__ Al,
              const unsigned short* __restrict__ Bh, const unsigned short* __restrict__ Bl,
              const float* __restrict__ bq, const float* __restrict__ bk,
              const float* __restrict__ bv,
              unsigned short* __restrict__ Oqh, unsigned short* __restrict__ Oql,
              unsigned short* __restrict__ Okh, unsigned short* __restrict__ Ovt)
{
    __shared__ unsigned short As_h[128 * 64], As_l[128 * 64];
    __shared__ unsigned short Bs_h[64 * 64],  Bs_l[64 * 64];

    const int tid = threadIdx.x;
    const int lane = tid & 63, w = tid >> 6;
    const int wm = w >> 1, wn = w & 1;
    const int l15 = lane & 15, l4 = lane >> 4;
    const int lr = lane >> 3, lc = lane & 7;
    const int m0 = blockIdx.x * 128, n0 = blockIdx.y * 64;

    f32x4 acc[4][2];
    #pragma unroll
    for (int i = 0; i < 4; ++i)
        #pragma unroll
        for (int j = 0; j < 2; ++j) acc[i][j] = (f32x4){0.f, 0.f, 0.f, 0.f};

    for (int kt = 0; kt < D_; kt += 64) {
        __syncthreads();
        #pragma unroll
        for (int t = 0; t < 4; ++t) {
            const int row = w * 32 + t * 8 + lr;
            const int kc = lc ^ (row & 7);
            const size_t g = (size_t)(m0 + row) * D_ + kt + kc * 8;
            gl_lds16(&Ah[g], &As_h[(w * 32 + t * 8) * 64]);
            gl_lds16(&Al[g], &As_l[(w * 32 + t * 8) * 64]);
        }
        #pragma unroll
        for (int t = 0; t < 2; ++t) {
            const int row = w * 16 + t * 8 + lr;
            const int kc = lc ^ (row & 7);
            const size_t g = (size_t)(n0 + row) * D_ + kt + kc * 8;
            gl_lds16(&Bh[g], &Bs_h[(w * 16 + t * 8) * 64]);
            gl_lds16(&Bl[g], &Bs_l[(w * 16 + t * 8) * 64]);
        }
        __syncthreads();

        #pragma unroll
        for (int kk = 0; kk < 2; ++kk) {
            bf16x8 ah[4], al[4], bh2[2], bl2[2];
            #pragma unroll
            for (int i = 0; i < 4; ++i) {
                const int row = wm * 64 + i * 16 + l15;
                const int off = row * 64 + (((kk * 4 + l4) ^ (row & 7)) << 3);
                ah[i] = *(const bf16x8*)&As_h[off];
                al[i] = *(const bf16x8*)&As_l[off];
            }
            #pragma unroll
            for (int j = 0; j < 2; ++j) {
                const int row = wn * 32 + j * 16 + l15;
                const int off = row * 64 + (((kk * 4 + l4) ^ (row & 7)) << 3);
                bh2[j] = *(const bf16x8*)&Bs_h[off];
                bl2[j] = *(const bf16x8*)&Bs_l[off];
            }
            #pragma unroll
            for (int i = 0; i < 4; ++i)
                #pragma unroll
                for (int j = 0; j < 2; ++j) {
                    acc[i][j] = MFMA(ah[i], bh2[j], acc[i][j]);
                    acc[i][j] = MFMA(ah[i], bl2[j], acc[i][j]);
                    acc[i][j] = MFMA(al[i], bh2[j], acc[i][j]);
                }
        }
    }

    const int idx = n0 >> 10;   // 0=Q 1=K 2=V (uniform per block)
    const float* bp = (idx == 0) ? bq : (idx == 1) ? bk : bv;
    #pragma unroll
    for (int i = 0; i < 4; ++i) {
        const int m = m0 + wm * 64 + i * 16 + l4 * 4;
        #pragma unroll
        for (int j = 0; j < 2; ++j) {
            const int nG = n0 + wn * 32 + j * 16 + l15;
            const int c = nG & 1023;
            const float bvv = bp[c];
            const int hh = c >> 6, dd = c & 63, bb = m >> 11;
            if (idx == 0) {
                const size_t base = ((size_t)(bb * H_ + hh) * S_ + (m & 2047)) * 64 + dd;
                #pragma unroll
                for (int r = 0; r < 4; ++r) {
                    unsigned short vh, vl;
                    split2(acc[i][j][r] + bvv, vh, vl);
                    Oqh[base + (size_t)r * 64] = vh;
                    Oql[base + (size_t)r * 64] = vl;
                }
            } else if (idx == 1) {
                const size_t base = ((size_t)(bb * H_ + hh) * S_ + (m & 2047)) * 64 + dd;
                #pragma unroll
                for (int r = 0; r < 4; ++r)
                    Okh[base + (size_t)r * 64] = bf16_rne(acc[i][j][r] + bvv);
            } else {
                // V^T: [bh][d][s]; 4 consecutive s -> one 8B store
                unsigned short pv[4];
                #pragma unroll
                for (int r = 0; r < 4; ++r) pv[r] = bf16_rne(acc[i][j][r] + bvv);
                *(short4v*)&Ovt[((size_t)(bb * H_ + hh) * 64 + dd) * (size_t)S_ + (m & 2047)] =
                    (short4v){(short)pv[0],(short)pv[1],(short)pv[2],(short)pv[3]};
            }
        }
    }
}

// ---------------------------------------------------------------------------
// Output GEMM: out[M][1024] f32 = msgs(hi/lo) @ WoT(hi/lo) + bo
// ---------------------------------------------------------------------------
__global__ __launch_bounds__(256, 3)
void gemm_out(const unsigned short* __restrict__ Ah, const unsigned short* __restrict__ Al,
              const unsigned short* __restrict__ Bh, const unsigned short* __restrict__ Bl,
              const float* __restrict__ bias, float* __restrict__ Cf)
{
    __shared__ unsigned short As_h[128 * 64], As_l[128 * 64];
    __shared__ unsigned short Bs_h[64 * 64],  Bs_l[64 * 64];

    const int tid = threadIdx.x;
    const int lane = tid & 63, w = tid >> 6;
    const int wm = w >> 1, wn = w & 1;
    const int l15 = lane & 15, l4 = lane >> 4;
    const int lr = lane >> 3, lc = lane & 7;
    const int m0 = blockIdx.x * 128, n0 = blockIdx.y * 64;

    f32x4 acc[4][2];
    #pragma unroll
    for (int i = 0; i < 4; ++i)
        #pragma unroll
        for (int j = 0; j < 2; ++j) acc[i][j] = (f32x4){0.f, 0.f, 0.f, 0.f};

    for (int kt = 0; kt < D_; kt += 64) {
        __syncthreads();
        #pragma unroll
        for (int t = 0; t < 4; ++t) {
            const int row = w * 32 + t * 8 + lr;
            const int kc = lc ^ (row & 7);
            const size_t g = (size_t)(m0 + row) * D_ + kt + kc * 8;
            gl_lds16(&Ah[g], &As_h[(w * 32 + t * 8) * 64]);
            gl_lds16(&Al[g], &As_l[(w * 32 + t * 8) * 64]);
        }
        #pragma unroll
        for (int t = 0; t < 2; ++t) {
            const int row = w * 16 + t * 8 + lr;
            const int kc = lc ^ (row & 7);
            const size_t g = (size_t)(n0 + row) * D_ + kt + kc * 8;
            gl_lds16(&Bh[g], &Bs_h[(w * 16 + t * 8) * 64]);
            gl_lds16(&Bl[g], &Bs_l[(w * 16 + t * 8) * 64]);
        }
        __syncthreads();

        #pragma unroll
        for (int kk = 0; kk < 2; ++kk) {
            bf16x8 ah[4], al[4], bh2[2], bl2[2];
            #pragma unroll
            for (int i = 0; i < 4; ++i) {
                const int row = wm * 64 + i * 16 + l15;
                const int off = row * 64 + (((kk * 4 + l4) ^ (row & 7)) << 3);
                ah[i] = *(const bf16x8*)&As_h[off];
                al[i] = *(const bf16x8*)&As_l[off];
            }
            #pragma unroll
            for (int j = 0; j < 2; ++j) {
                const int row = wn * 32 + j * 16 + l15;
                const int off = row * 64 + (((kk * 4 + l4) ^ (row & 7)) << 3);
                bh2[j] = *(const bf16x8*)&Bs_h[off];
                bl2[j] = *(const bf16x8*)&Bs_l[off];
            }
            #pragma unroll
            for (int i = 0; i < 4; ++i)
                #pragma unroll
                for (int j = 0; j < 2; ++j) {
                    acc[i][j] = MFMA(ah[i], bh2[j], acc[i][j]);
                    acc[i][j] = MFMA(ah[i], bl2[j], acc[i][j]);
                    acc[i][j] = MFMA(al[i], bh2[j], acc[i][j]);
                }
        }
    }

    #pragma unroll
    for (int i = 0; i < 4; ++i) {
        const int m = m0 + wm * 64 + i * 16 + l4 * 4;
        #pragma unroll
        for (int j = 0; j < 2; ++j) {
            const int n = n0 + wn * 32 + j * 16 + l15;
            const float bvv = bias[n];
            #pragma unroll
            for (int r = 0; r < 4; ++r)
                Cf[(size_t)(m + r) * OUT_ + n] = acc[i][j][r] + bvv;
        }
    }
}

// ---------------------------------------------------------------------------
// Flash attention, 8 waves x 16 q-rows (4 waves/SIMD occupancy), 2-phase
// double-buffered staging. Q hi/lo, K hi, V^T hi (head-blocked).
// Grid (B*H, S/128), block 512. Log2 softmax, additive k-mask; q-mask
// applied in epilogue only (inv=0). Defer-max; l reduced in epilogue.
// ---------------------------------------------------------------------------
__global__ __launch_bounds__(512, 4)
void attn_mfma(const unsigned short* __restrict__ Qh, const unsigned short* __restrict__ Ql,
               const unsigned short* __restrict__ Kh, const unsigned short* __restrict__ Vt,
               const float* __restrict__ mask,
               unsigned short* __restrict__ Mh, unsigned short* __restrict__ Ml)
{
    __shared__ unsigned short Ks[2][64 * 64];    // [buf][key][k-chunks swizzled]
    __shared__ unsigned short Vts[2][64 * 64];   // [buf][d][key-chunks swizzled]
    __shared__ float Ps[128][36];
    __shared__ float mk_s[2][64];

    const float SC2  = 0.125f * 1.4426950408889634f;  // score->log2 domain
    const float THR2 = 11.5415603f;                   // 8 * log2(e)
    const float MINIT = -1e5f;
    const float NEGB  = -1e30f;

    const int tid = threadIdx.x;
    const int lane = tid & 63, w = tid >> 6;          // w = 0..7
    const int l15 = lane & 15, l4 = lane >> 4;
    const int bh = blockIdx.x, b = bh >> 4;
    const int q0 = blockIdx.y * 128;
    const int qw = q0 + w * 16;                       // 16 q rows per wave

    // staging decode: each wave stages 8 K rows + 8 V^T rows per tile
    const int srow = w * 8 + (lane >> 3);             // 0..63
    const int skc  = (lane & 7) ^ (srow & 7);

    // Q fragments (hi/lo); q-mask flag per owned row (epilogue only)
    bf16x8 qh[2], ql[2];
    float mq[4];
    {
        const size_t qbase = ((size_t)bh * S_ + qw + l15) * 64;
        #pragma unroll
        for (int kk = 0; kk < 2; ++kk) {
            qh[kk] = *(const bf16x8*)&Qh[qbase + kk * 32 + l4 * 8];
            ql[kk] = *(const bf16x8*)&Ql[qbase + kk * 32 + l4 * 8];
        }
        #pragma unroll
        for (int r = 0; r < 4; ++r)
            mq[r] = mask[(size_t)b * S_ + qw + l4 * 4 + r];
    }

    float m2[4], lp[4];
    f32x4 O[4];
    #pragma unroll
    for (int r = 0; r < 4; ++r) { m2[r] = MINIT; lp[r] = 0.f; }
    #pragma unroll
    for (int df = 0; df < 4; ++df) O[df] = (f32x4){0.f, 0.f, 0.f, 0.f};

#define STAGE(KT, SEL)                                                          \
    do {                                                                        \
        gl_lds16(&Kh[((size_t)bh * S_ + (KT) + srow) * 64 + skc * 8],           \
                 &Ks[SEL][(w * 8) * 64]);                                       \
        gl_lds16(&Vt[((size_t)bh * 64 + srow) * (size_t)S_ + (KT) + skc * 8],   \
                 &Vts[SEL][(w * 8) * 64]);                                      \
        if (tid < 64) mk_s[SEL][tid] = mask[(size_t)b * S_ + (KT) + tid];       \
    } while (0)

    STAGE(0, 0);
    __syncthreads();

    int cur = 0;
    for (int kt = 0; kt < S_; kt += 64, cur ^= 1) {
        if (kt + 64 < S_) STAGE(kt + 64, cur ^ 1);

        // QK^T (K hi-only): s rows=q (l4,r), cols=key (nf*16+l15)
        f32x4 s[4];
        #pragma unroll
        for (int nf = 0; nf < 4; ++nf) s[nf] = (f32x4){0.f, 0.f, 0.f, 0.f};
        #pragma unroll
        for (int nf = 0; nf < 4; ++nf) {
            const int krow = nf * 16 + l15;
            #pragma unroll
            for (int kk = 0; kk < 2; ++kk) {
                const int off = krow * 64 + (((kk * 4 + l4) ^ (krow & 7)) << 3);
                const bf16x8 kh8 = *(const bf16x8*)&Ks[cur][off];
                s[nf] = MFMA(qh[kk], kh8, s[nf]);
                s[nf] = MFMA(ql[kk], kh8, s[nf]);
            }
        }

        // additive k-mask + log2 scale; defer-max gate
        float addk[4];
        #pragma unroll
        for (int nf = 0; nf < 4; ++nf)
            addk[nf] = (mk_s[cur][nf * 16 + l15] != 0.f) ? 0.f : NEGB;

        float lm[4];
        bool need = false;
        #pragma unroll
        for (int r = 0; r < 4; ++r) {
            float v0 = fmaf(s[0][r], SC2, addk[0]);
            float v1 = fmaf(s[1][r], SC2, addk[1]);
            float v2 = fmaf(s[2][r], SC2, addk[2]);
            float v3 = fmaf(s[3][r], SC2, addk[3]);
            s[0][r] = v0; s[1][r] = v1; s[2][r] = v2; s[3][r] = v3;
            const float rm = fmaxf(fmaxf(v0, v1), fmaxf(v2, v3));
            lm[r] = rm;
            need |= (rm > m2[r] + THR2);
        }

        if (__any(need)) {   // occasional: full row-max reduce + rescale
            #pragma unroll
            for (int r = 0; r < 4; ++r) {
                float rm = lm[r];
                rm = fmaxf(rm, __shfl_xor(rm, 1));
                rm = fmaxf(rm, __shfl_xor(rm, 2));
                rm = fmaxf(rm, __shfl_xor(rm, 4));
                rm = fmaxf(rm, __shfl_xor(rm, 8));
                const float mnew = fmaxf(m2[r], rm);
                const float sc = fast_exp2(m2[r] - mnew);
                lp[r] *= sc;
                m2[r] = mnew;
                #pragma unroll
                for (int df = 0; df < 4; ++df) O[df][r] *= sc;
            }
        }

        // exp2 (masked keys underflow to exactly 0) + per-lane partial l
        #pragma unroll
        for (int r = 0; r < 4; ++r) {
            const float mm = m2[r];
            float rs = 0.f;
            #pragma unroll
            for (int nf = 0; nf < 4; ++nf) {
                const float pv = fast_exp2(s[nf][r] - mm);
                s[nf][r] = pv;
                rs += pv;
            }
            lp[r] += rs;
        }

        // PV per key-half: P via wave-private LDS transpose (hi-only, RNE)
        #pragma unroll
        for (int kk = 0; kk < 2; ++kk) {
            #pragma unroll
            for (int nh = 0; nh < 2; ++nh)
                #pragma unroll
                for (int r = 0; r < 4; ++r)
                    Ps[w * 16 + l4 * 4 + r][nh * 16 + l15] = s[kk * 2 + nh][r];

            const float* pr = &Ps[w * 16 + l15][l4 * 8];
            const bf16x8 ph = pack8_rne(*(const float4*)pr, *(const float4*)(pr + 4));

            #pragma unroll
            for (int df = 0; df < 4; ++df) {
                const int vrow = df * 16 + l15;
                const int off = vrow * 64 + (((kk * 4 + l4) ^ (vrow & 7)) << 3);
                const bf16x8 vb = *(const bf16x8*)&Vts[cur][off];
                O[df] = MFMA(ph, vb, O[df]);
            }
        }

        // single barrier per tile: drains prefetch + all LDS reads of buf[cur]
        __syncthreads();
    }
#undef STAGE

    // epilogue: reduce l partials; q-mask + empty-row filter; normalize; write
    #pragma unroll
    for (int r = 0; r < 4; ++r) {
        float t = lp[r];
        t += __shfl_xor(t, 1);
        t += __shfl_xor(t, 2);
        t += __shfl_xor(t, 4);
        t += __shfl_xor(t, 8);
        const float inv = (mq[r] != 0.f && t > 0.f) ? 1.f / t : 0.f;
        const int qr = qw + l4 * 4 + r;
        const size_t base = ((size_t)b * S_ + qr) * D_ + (bh & 15) * DH_;
        #pragma unroll
        for (int df = 0; df < 4; ++df) {
            unsigned short vh, vl;
            split2(O[df][r] * inv, vh, vl);
            Mh[base + df * 16 + l15] = vh;
            Ml[base + df * 16 + l15] = vl;
        }
    }
}

// ---------------------------------------------------------------------------
extern "C" void kernel_launch(void* const* d_in, const int* in_sizes, int n_in,
                              void* d_out, int out_size, void* d_ws, size_t ws_size,
                              hipStream_t stream)
{
    const float* x    = (const float*)d_in[0];
    const float* mask = (const float*)d_in[1];
    const float* Wq   = (const float*)d_in[2];
    const float* bq   = (const float*)d_in[3];
    const float* Wk   = (const float*)d_in[4];
    const float* bk   = (const float*)d_in[5];
    const float* Wv   = (const float*)d_in[6];
    const float* bv   = (const float*)d_in[7];
    const float* Wo   = (const float*)d_in[8];
    const float* bo   = (const float*)d_in[9];
    float* out = (float*)d_out;

    char* ws = (char*)d_ws;
    unsigned short* xh = (unsigned short*)(ws);                      // 8MB (later mh)
    unsigned short* xl = (unsigned short*)(ws + ((size_t) 8 << 20)); // 8MB (later ml)
    unsigned short* qh = (unsigned short*)(ws + ((size_t)16 << 20));
    unsigned short* qll= (unsigned short*)(ws + ((size_t)24 << 20));
    unsigned short* kh = (unsigned short*)(ws + ((size_t)32 << 20));
    unsigned short* vt = (unsigned short*)(ws + ((size_t)40 << 20)); // V^T [bh][d][s]
    unsigned short* wc_h = (unsigned short*)(ws + ((size_t)48 << 20)); // 6MB
    unsigned short* wc_l = (unsigned short*)(ws + ((size_t)54 << 20)); // 6MB
    unsigned short* wo_h = wc_h;            // reuse after QKV GEMM (2MB)
    unsigned short* wo_l = (unsigned short*)(ws + ((size_t)50 << 20));
    unsigned short* mh = xh;                // x dead after QKV GEMM
    unsigned short* ml = xl;

    const dim3 blk(256);
    split_x<<<dim3(M_ * D_ / 4 / 256), blk, 0, stream>>>(x, xh, xl, M_ * D_ / 4);
    tconv_qkv<<<dim3(16, 16, 3), blk, 0, stream>>>(Wq, Wk, Wv, wc_h, wc_l);

    gemm_qkv<<<dim3(M_ / 128, 3 * D_ / 64), blk, 0, stream>>>(
        xh, xl, wc_h, wc_l, bq, bk, bv, qh, qll, kh, vt);

    tconv_w<<<dim3(16, 16), blk, 0, stream>>>(Wo, wo_h, wo_l, D_, OUT_);

    attn_mfma<<<dim3(B_ * H_, S_ / 128), dim3(512), 0, stream>>>(
        qh, qll, kh, vt, mask, mh, ml);

    gemm_out<<<dim3(M_ / 128, OUT_ / 64), blk, 0, stream>>>(
        mh, ml, wo_h, wo_l, bo, out);
}

// Round 9
// 209.141 us; speedup vs baseline: 5.3810x; 1.0429x over previous
//
#include <hip/hip_runtime.h>
#include <hip/hip_bf16.h>
#include <math.h>

#define B_   2
#define S_   2048
#define H_   16
#define DH_  64
#define D_   1024
#define OUT_ 1024
#define M_   (B_ * S_)   // 4096

typedef __attribute__((ext_vector_type(8))) short bf16x8;
typedef __attribute__((ext_vector_type(4))) float f32x4;
typedef __attribute__((ext_vector_type(4))) short short4v;

#define MFMA(a, b, c) __builtin_amdgcn_mfma_f32_16x16x32_bf16((a), (b), (c), 0, 0, 0)

// async global->LDS, 16B per lane, LDS dest = wave-uniform base + lane*16
__device__ __forceinline__ void gl_lds16(const void* g, void* l) {
    __builtin_amdgcn_global_load_lds(
        (const __attribute__((address_space(1))) unsigned int*)g,
        (__attribute__((address_space(3))) unsigned int*)l, 16, 0, 0);
}

// truncation split: x = hi(bf16) + lo(bf16) + O(2^-16 x)
__device__ __forceinline__ void split2(float x, unsigned short& h, unsigned short& l) {
    unsigned u = __float_as_uint(x);
    h = (unsigned short)(u >> 16);
    float lo = x - __uint_as_float(u & 0xFFFF0000u);
    l = (unsigned short)(__float_as_uint(lo) >> 16);
}

// RNE f32->bf16 via HW convert
__device__ __forceinline__ unsigned short bf16_rne(float x) {
    return __builtin_bit_cast(unsigned short, __float2bfloat16(x));
}

__device__ __forceinline__ float fast_exp2(float x) {
#if __has_builtin(__builtin_amdgcn_exp2f)
    return __builtin_amdgcn_exp2f(x);
#else
    return exp2f(x);
#endif
}

// ---------------------------------------------------------------------------
__global__ __launch_bounds__(256)
void split_x(const float* __restrict__ X, unsigned short* __restrict__ Xh,
             unsigned short* __restrict__ Xl, int n4)
{
    const int i = blockIdx.x * 256 + threadIdx.x;
    if (i >= n4) return;
    const float4 v = ((const float4*)X)[i];
    unsigned short h[4], l[4];
    split2(v.x, h[0], l[0]); split2(v.y, h[1], l[1]);
    split2(v.z, h[2], l[2]); split2(v.w, h[3], l[3]);
    ((short4v*)Xh)[i] = (short4v){(short)h[0],(short)h[1],(short)h[2],(short)h[3]};
    ((short4v*)Xl)[i] = (short4v){(short)l[0],(short)l[1],(short)l[2],(short)l[3]};
}

// ---------------------------------------------------------------------------
// transpose + split convert: W[K,N] f32 -> Th/Tl [N,K] bf16 (single weight)
// ---------------------------------------------------------------------------
__global__ __launch_bounds__(256)
void tconv_w(const float* __restrict__ W, unsigned short* __restrict__ Th,
             unsigned short* __restrict__ Tl, int K, int N)
{
    __shared__ float T[64][65];
    const int tid = threadIdx.x;
    const int k0 = blockIdx.x * 64, n0 = blockIdx.y * 64;
    #pragma unroll
    for (int p = 0; p < 4; ++p) {
        const int f = p * 256 + tid;
        const int r = f >> 4, c4 = (f & 15) << 2;
        const float4 v = *(const float4*)&W[(size_t)(k0 + r) * N + n0 + c4];
        T[r][c4] = v.x; T[r][c4 + 1] = v.y; T[r][c4 + 2] = v.z; T[r][c4 + 3] = v.w;
    }
    __syncthreads();
    #pragma unroll
    for (int p = 0; p < 4; ++p) {
        const int f = p * 256 + tid;
        const int r = f >> 4, c4 = (f & 15) << 2;
        unsigned short h[4], l[4];
        #pragma unroll
        for (int i = 0; i < 4; ++i) split2(T[c4 + i][r], h[i], l[i]);
        *(short4v*)&Th[(size_t)(n0 + r) * K + k0 + c4] =
            (short4v){(short)h[0],(short)h[1],(short)h[2],(short)h[3]};
        *(short4v*)&Tl[(size_t)(n0 + r) * K + k0 + c4] =
            (short4v){(short)l[0],(short)l[1],(short)l[2],(short)l[3]};
    }
}

// same, for the 3 QKV weights in one launch (z selects weight; out at z<<20)
__global__ __launch_bounds__(256)
void tconv_qkv(const float* __restrict__ W0, const float* __restrict__ W1,
               const float* __restrict__ W2, unsigned short* __restrict__ Th,
               unsigned short* __restrict__ Tl)
{
    __shared__ float T[64][65];
    const int z = blockIdx.z;
    const float* W = (z == 0) ? W0 : (z == 1) ? W1 : W2;
    unsigned short* th = Th + ((size_t)z << 20);
    unsigned short* tl = Tl + ((size_t)z << 20);
    const int tid = threadIdx.x;
    const int k0 = blockIdx.x * 64, n0 = blockIdx.y * 64;
    #pragma unroll
    for (int p = 0; p < 4; ++p) {
        const int f = p * 256 + tid;
        const int r = f >> 4, c4 = (f & 15) << 2;
        const float4 v = *(const float4*)&W[(size_t)(k0 + r) * D_ + n0 + c4];
        T[r][c4] = v.x; T[r][c4 + 1] = v.y; T[r][c4 + 2] = v.z; T[r][c4 + 3] = v.w;
    }
    __syncthreads();
    #pragma unroll
    for (int p = 0; p < 4; ++p) {
        const int f = p * 256 + tid;
        const int r = f >> 4, c4 = (f & 15) << 2;
        unsigned short h[4], l[4];
        #pragma unroll
        for (int i = 0; i < 4; ++i) split2(T[c4 + i][r], h[i], l[i]);
        *(short4v*)&th[(size_t)(n0 + r) * D_ + k0 + c4] =
            (short4v){(short)h[0],(short)h[1],(short)h[2],(short)h[3]};
        *(short4v*)&tl[(size_t)(n0 + r) * D_ + k0 + c4] =
            (short4v){(short)l[0],(short)l[1],(short)l[2],(short)l[3]};
    }
}

// ---------------------------------------------------------------------------
// Split GEMM, 128x128 tile, 4 waves (2x2), wave tile 64x64 (4x4 frags).
// 48 MFMA : 16 b128 per kk (3:1 vs round-8's 2:1 — LDS-pipe relief).
// MODE 0: f32 out + bias (gemm_out). MODE 1: QKV routed epilogue.
// ---------------------------------------------------------------------------
template<int MODE>
__global__ __launch_bounds__(256, 2)
void gemm128(const unsigned short* __restrict__ Ah, const unsigned short* __restrict__ Al,
             const unsigned short* __restrict__ Bh, const unsigned short* __restrict__ Bl,
             const float* __restrict__ b0, const float* __restrict__ b1,
             const float* __restrict__ b2, float* __restrict__ Cf,
             unsigned short* __restrict__ Oqh, unsigned short* __restrict__ Oql,
             unsigned short* __restrict__ Okh, unsigned short* __restrict__ Ovt,
             int N)
{
    __shared__ unsigned short As_h[128 * 64], As_l[128 * 64];
    __shared__ unsigned short Bs_h[128 * 64], Bs_l[128 * 64];

    const int tid = threadIdx.x;
    const int lane = tid & 63, w = tid >> 6;
    const int wm = w >> 1, wn = w & 1;
    const int l15 = lane & 15, l4 = lane >> 4;
    const int lr = lane >> 3, lc = lane & 7;
    const int m0 = blockIdx.x * 128, n0 = blockIdx.y * 128;

    f32x4 acc[4][4];
    #pragma unroll
    for (int i = 0; i < 4; ++i)
        #pragma unroll
        for (int j = 0; j < 4; ++j) acc[i][j] = (f32x4){0.f, 0.f, 0.f, 0.f};

    for (int kt = 0; kt < D_; kt += 64) {
        __syncthreads();
        #pragma unroll
        for (int t = 0; t < 4; ++t) {
            const int row = w * 32 + t * 8 + lr;
            const int kc = lc ^ (row & 7);
            const size_t ga = (size_t)(m0 + row) * D_ + kt + kc * 8;
            gl_lds16(&Ah[ga], &As_h[(w * 32 + t * 8) * 64]);
            gl_lds16(&Al[ga], &As_l[(w * 32 + t * 8) * 64]);
            const size_t gb = (size_t)(n0 + row) * D_ + kt + kc * 8;
            gl_lds16(&Bh[gb], &Bs_h[(w * 32 + t * 8) * 64]);
            gl_lds16(&Bl[gb], &Bs_l[(w * 32 + t * 8) * 64]);
        }
        __syncthreads();

        #pragma unroll
        for (int kk = 0; kk < 2; ++kk) {
            bf16x8 ah[4], al[4], bh4[4], bl4[4];
            #pragma unroll
            for (int i = 0; i < 4; ++i) {
                const int row = wm * 64 + i * 16 + l15;
                const int off = row * 64 + (((kk * 4 + l4) ^ (row & 7)) << 3);
                ah[i] = *(const bf16x8*)&As_h[off];
                al[i] = *(const bf16x8*)&As_l[off];
            }
            #pragma unroll
            for (int j = 0; j < 4; ++j) {
                const int row = wn * 64 + j * 16 + l15;
                const int off = row * 64 + (((kk * 4 + l4) ^ (row & 7)) << 3);
                bh4[j] = *(const bf16x8*)&Bs_h[off];
                bl4[j] = *(const bf16x8*)&Bs_l[off];
            }
            #pragma unroll
            for (int i = 0; i < 4; ++i)
                #pragma unroll
                for (int j = 0; j < 4; ++j) {
                    acc[i][j] = MFMA(ah[i], bh4[j], acc[i][j]);
                    acc[i][j] = MFMA(ah[i], bl4[j], acc[i][j]);
                    acc[i][j] = MFMA(al[i], bh4[j], acc[i][j]);
                }
        }
    }

    if constexpr (MODE == 0) {
        #pragma unroll
        for (int i = 0; i < 4; ++i) {
            const int m = m0 + wm * 64 + i * 16 + l4 * 4;
            #pragma unroll
            for (int j = 0; j < 4; ++j) {
                const int n = n0 + wn * 64 + j * 16 + l15;
                const float bvv = b0[n];
                #pragma unroll
                for (int r = 0; r < 4; ++r)
                    Cf[(size_t)(m + r) * OUT_ + n] = acc[i][j][r] + bvv;
            }
        }
    } else {
        const int idx = n0 >> 10;   // 0=Q 1=K 2=V (tile of 128 within 1024)
        const float* bp = (idx == 0) ? b0 : (idx == 1) ? b1 : b2;
        #pragma unroll
        for (int i = 0; i < 4; ++i) {
            const int m = m0 + wm * 64 + i * 16 + l4 * 4;
            #pragma unroll
            for (int j = 0; j < 4; ++j) {
                const int nG = n0 + wn * 64 + j * 16 + l15;
                const int c = nG & 1023;
                const float bvv = bp[c];
                const int hh = c >> 6, dd = c & 63, bb = m >> 11;
                if (idx == 0) {
                    const size_t base = ((size_t)(bb * H_ + hh) * S_ + (m & 2047)) * 64 + dd;
                    #pragma unroll
                    for (int r = 0; r < 4; ++r) {
                        unsigned short vh, vl;
                        split2(acc[i][j][r] + bvv, vh, vl);
                        Oqh[base + (size_t)r * 64] = vh;
                        Oql[base + (size_t)r * 64] = vl;
                    }
                } else if (idx == 1) {
                    const size_t base = ((size_t)(bb * H_ + hh) * S_ + (m & 2047)) * 64 + dd;
                    #pragma unroll
                    for (int r = 0; r < 4; ++r)
                        Okh[base + (size_t)r * 64] = bf16_rne(acc[i][j][r] + bvv);
                } else {
                    unsigned short pv[4];
                    #pragma unroll
                    for (int r = 0; r < 4; ++r) pv[r] = bf16_rne(acc[i][j][r] + bvv);
                    *(short4v*)&Ovt[((size_t)(bb * H_ + hh) * 64 + dd) * (size_t)S_ + (m & 2047)] =
                        (short4v){(short)pv[0],(short)pv[1],(short)pv[2],(short)pv[3]};
                }
            }
        }
    }
}

// ---------------------------------------------------------------------------
// Flash attention, 8 waves x 16 q-rows, 2-phase dbuf staging.
// Q hi/lo, K hi, V^T hi (head-blocked). Grid (B*H, S/128), block 512.
// P staged in LDS as bf16 with XOR-swizzled 16B chunks (conflict-free),
// all 64 keys at once; PV reads P fragments directly as bf16x8.
// Log2 softmax, additive k-mask, defer-max, epilogue l-reduce + q-mask.
// ---------------------------------------------------------------------------
__global__ __launch_bounds__(512, 4)
void attn_mfma(const unsigned short* __restrict__ Qh, const unsigned short* __restrict__ Ql,
               const unsigned short* __restrict__ Kh, const unsigned short* __restrict__ Vt,
               const float* __restrict__ mask,
               unsigned short* __restrict__ Mh, unsigned short* __restrict__ Ml)
{
    __shared__ unsigned short Ks[2][64 * 64];    // [buf][key][k-chunks swizzled]
    __shared__ unsigned short Vts[2][64 * 64];   // [buf][d][key-chunks swizzled]
    __shared__ unsigned short Psb[128 * 72];     // [q][64 keys + pad], swizzled
    __shared__ float mk_s[2][64];

    const float SC2  = 0.125f * 1.4426950408889634f;  // score->log2 domain
    const float THR2 = 11.5415603f;                   // 8 * log2(e)
    const float MINIT = -1e5f;
    const float NEGB  = -1e30f;

    const int tid = threadIdx.x;
    const int lane = tid & 63, w = tid >> 6;          // w = 0..7
    const int l15 = lane & 15, l4 = lane >> 4;
    const int bh = blockIdx.x, b = bh >> 4;
    const int q0 = blockIdx.y * 128;
    const int qw = q0 + w * 16;                       // 16 q rows per wave

    // staging decode: each wave stages 8 K rows + 8 V^T rows per tile
    const int srow = w * 8 + (lane >> 3);             // 0..63
    const int skc  = (lane & 7) ^ (srow & 7);

    // Q fragments (hi/lo); q-mask flag per owned row (epilogue only)
    bf16x8 qh[2], ql[2];
    float mq[4];
    {
        const size_t qbase = ((size_t)bh * S_ + qw + l15) * 64;
        #pragma unroll
        for (int kk = 0; kk < 2; ++kk) {
            qh[kk] = *(const bf16x8*)&Qh[qbase + kk * 32 + l4 * 8];
            ql[kk] = *(const bf16x8*)&Ql[qbase + kk * 32 + l4 * 8];
        }
        #pragma unroll
        for (int r = 0; r < 4; ++r)
            mq[r] = mask[(size_t)b * S_ + qw + l4 * 4 + r];
    }

    float m2[4], lp[4];
    f32x4 O[4];
    #pragma unroll
    for (int r = 0; r < 4; ++r) { m2[r] = MINIT; lp[r] = 0.f; }
    #pragma unroll
    for (int df = 0; df < 4; ++df) O[df] = (f32x4){0.f, 0.f, 0.f, 0.f};

#define STAGE(KT, SEL)                                                          \
    do {                                                                        \
        gl_lds16(&Kh[((size_t)bh * S_ + (KT) + srow) * 64 + skc * 8],           \
                 &Ks[SEL][(w * 8) * 64]);                                       \
        gl_lds16(&Vt[((size_t)bh * 64 + srow) * (size_t)S_ + (KT) + skc * 8],   \
                 &Vts[SEL][(w * 8) * 64]);                                      \
        if (tid < 64) mk_s[SEL][tid] = mask[(size_t)b * S_ + (KT) + tid];       \
    } while (0)

    STAGE(0, 0);
    __syncthreads();

    int cur = 0;
    for (int kt = 0; kt < S_; kt += 64, cur ^= 1) {
        if (kt + 64 < S_) STAGE(kt + 64, cur ^ 1);

        // QK^T (K hi-only): s rows=q (l4,r), cols=key (nf*16+l15)
        f32x4 s[4];
        #pragma unroll
        for (int nf = 0; nf < 4; ++nf) s[nf] = (f32x4){0.f, 0.f, 0.f, 0.f};
        #pragma unroll
        for (int nf = 0; nf < 4; ++nf) {
            const int krow = nf * 16 + l15;
            #pragma unroll
            for (int kk = 0; kk < 2; ++kk) {
                const int off = krow * 64 + (((kk * 4 + l4) ^ (krow & 7)) << 3);
                const bf16x8 kh8 = *(const bf16x8*)&Ks[cur][off];
                s[nf] = MFMA(qh[kk], kh8, s[nf]);
                s[nf] = MFMA(ql[kk], kh8, s[nf]);
            }
        }

        // additive k-mask + log2 scale; defer-max gate
        float addk[4];
        #pragma unroll
        for (int nf = 0; nf < 4; ++nf)
            addk[nf] = (mk_s[cur][nf * 16 + l15] != 0.f) ? 0.f : NEGB;

        float lm[4];
        bool need = false;
        #pragma unroll
        for (int r = 0; r < 4; ++r) {
            float v0 = fmaf(s[0][r], SC2, addk[0]);
            float v1 = fmaf(s[1][r], SC2, addk[1]);
            float v2 = fmaf(s[2][r], SC2, addk[2]);
            float v3 = fmaf(s[3][r], SC2, addk[3]);
            s[0][r] = v0; s[1][r] = v1; s[2][r] = v2; s[3][r] = v3;
            const float rm = fmaxf(fmaxf(v0, v1), fmaxf(v2, v3));
            lm[r] = rm;
            need |= (rm > m2[r] + THR2);
        }

        if (__any(need)) {   // occasional: full row-max reduce + rescale
            #pragma unroll
            for (int r = 0; r < 4; ++r) {
                float rm = lm[r];
                rm = fmaxf(rm, __shfl_xor(rm, 1));
                rm = fmaxf(rm, __shfl_xor(rm, 2));
                rm = fmaxf(rm, __shfl_xor(rm, 4));
                rm = fmaxf(rm, __shfl_xor(rm, 8));
                const float mnew = fmaxf(m2[r], rm);
                const float sc = fast_exp2(m2[r] - mnew);
                lp[r] *= sc;
                m2[r] = mnew;
                #pragma unroll
                for (int df = 0; df < 4; ++df) O[df][r] *= sc;
            }
        }

        // exp2 + partial l; write P (bf16, RNE) to swizzled Psb — all 64 keys
        #pragma unroll
        for (int r = 0; r < 4; ++r) {
            const float mm = m2[r];
            const int qq = w * 16 + l4 * 4 + r;
            const int qbase = qq * 72;
            const int qswz = qq & 7;
            float rs = 0.f;
            #pragma unroll
            for (int nf = 0; nf < 4; ++nf) {
                const float pv = fast_exp2(s[nf][r] - mm);
                rs += pv;
                const int key = nf * 16 + l15;
                Psb[qbase + (((key >> 3) ^ qswz) << 3) + (key & 7)] = bf16_rne(pv);
            }
            lp[r] += rs;
        }

        // PV per key-half: P fragment read straight from swizzled Psb
        #pragma unroll
        for (int kk = 0; kk < 2; ++kk) {
            const int qq = w * 16 + l15;
            const bf16x8 ph = *(const bf16x8*)
                &Psb[qq * 72 + ((((kk * 4) + l4) ^ (qq & 7)) << 3)];
            #pragma unroll
            for (int df = 0; df < 4; ++df) {
                const int vrow = df * 16 + l15;
                const int off = vrow * 64 + (((kk * 4 + l4) ^ (vrow & 7)) << 3);
                const bf16x8 vb = *(const bf16x8*)&Vts[cur][off];
                O[df] = MFMA(ph, vb, O[df]);
            }
        }

        // single barrier per tile: drains prefetch + LDS reads of buf[cur]/Psb
        __syncthreads();
    }
#undef STAGE

    // epilogue: reduce l partials; q-mask + empty-row filter; normalize; write
    #pragma unroll
    for (int r = 0; r < 4; ++r) {
        float t = lp[r];
        t += __shfl_xor(t, 1);
        t += __shfl_xor(t, 2);
        t += __shfl_xor(t, 4);
        t += __shfl_xor(t, 8);
        const float inv = (mq[r] != 0.f && t > 0.f) ? 1.f / t : 0.f;
        const int qr = qw + l4 * 4 + r;
        const size_t base = ((size_t)b * S_ + qr) * D_ + (bh & 15) * DH_;
        #pragma unroll
        for (int df = 0; df < 4; ++df) {
            unsigned short vh, vl;
            split2(O[df][r] * inv, vh, vl);
            Mh[base + df * 16 + l15] = vh;
            Ml[base + df * 16 + l15] = vl;
        }
    }
}

// ---------------------------------------------------------------------------
extern "C" void kernel_launch(void* const* d_in, const int* in_sizes, int n_in,
                              void* d_out, int out_size, void* d_ws, size_t ws_size,
                              hipStream_t stream)
{
    const float* x    = (const float*)d_in[0];
    const float* mask = (const float*)d_in[1];
    const float* Wq   = (const float*)d_in[2];
    const float* bq   = (const float*)d_in[3];
    const float* Wk   = (const float*)d_in[4];
    const float* bk   = (const float*)d_in[5];
    const float* Wv   = (const float*)d_in[6];
    const float* bv   = (const float*)d_in[7];
    const float* Wo   = (const float*)d_in[8];
    const float* bo   = (const float*)d_in[9];
    float* out = (float*)d_out;

    char* ws = (char*)d_ws;
    unsigned short* xh = (unsigned short*)(ws);                      // 8MB (later mh)
    unsigned short* xl = (unsigned short*)(ws + ((size_t) 8 << 20)); // 8MB (later ml)
    unsigned short* qh = (unsigned short*)(ws + ((size_t)16 << 20));
    unsigned short* qll= (unsigned short*)(ws + ((size_t)24 << 20));
    unsigned short* kh = (unsigned short*)(ws + ((size_t)32 << 20));
    unsigned short* vt = (unsigned short*)(ws + ((size_t)40 << 20)); // V^T [bh][d][s]
    unsigned short* wc_h = (unsigned short*)(ws + ((size_t)48 << 20)); // 6MB
    unsigned short* wc_l = (unsigned short*)(ws + ((size_t)54 << 20)); // 6MB
    unsigned short* wo_h = wc_h;            // reuse after QKV GEMM (2MB)
    unsigned short* wo_l = (unsigned short*)(ws + ((size_t)50 << 20));
    unsigned short* mh = xh;                // x dead after QKV GEMM
    unsigned short* ml = xl;

    const dim3 blk(256);
    split_x<<<dim3(M_ * D_ / 4 / 256), blk, 0, stream>>>(x, xh, xl, M_ * D_ / 4);
    tconv_qkv<<<dim3(16, 16, 3), blk, 0, stream>>>(Wq, Wk, Wv, wc_h, wc_l);

    gemm128<1><<<dim3(M_ / 128, 3 * D_ / 128), blk, 0, stream>>>(
        xh, xl, wc_h, wc_l, bq, bk, bv, nullptr, qh, qll, kh, vt, 3 * D_);

    tconv_w<<<dim3(16, 16), blk, 0, stream>>>(Wo, wo_h, wo_l, D_, OUT_);

    attn_mfma<<<dim3(B_ * H_, S_ / 128), dim3(512), 0, stream>>>(
        qh, qll, kh, vt, mask, mh, ml);

    gemm128<0><<<dim3(M_ / 128, OUT_ / 128), blk, 0, stream>>>(
        mh, ml, wo_h, wo_l, bo, nullptr, nullptr, out,
        nullptr, nullptr, nullptr, nullptr, OUT_);
}

// Round 10
// 177.098 us; speedup vs baseline: 6.3546x; 1.1809x over previous
//
#include <hip/hip_runtime.h>
#include <hip/hip_bf16.h>
#include <math.h>

#define B_   2
#define S_   2048
#define H_   16
#define DH_  64
#define D_   1024
#define OUT_ 1024
#define M_   (B_ * S_)   // 4096

typedef __attribute__((ext_vector_type(8))) short bf16x8;
typedef __attribute__((ext_vector_type(4))) float f32x4;
typedef __attribute__((ext_vector_type(4))) short short4v;

#define MFMA(a, b, c) __builtin_amdgcn_mfma_f32_16x16x32_bf16((a), (b), (c), 0, 0, 0)

__device__ __forceinline__ void gl_lds16(const void* g, void* l) {
    __builtin_amdgcn_global_load_lds(
        (const __attribute__((address_space(1))) unsigned int*)g,
        (__attribute__((address_space(3))) unsigned int*)l, 16, 0, 0);
}

__device__ __forceinline__ void split2(float x, unsigned short& h, unsigned short& l) {
    unsigned u = __float_as_uint(x);
    h = (unsigned short)(u >> 16);
    float lo = x - __uint_as_float(u & 0xFFFF0000u);
    l = (unsigned short)(__float_as_uint(lo) >> 16);
}

__device__ __forceinline__ unsigned short bf16_rne(float x) {
    return __builtin_bit_cast(unsigned short, __float2bfloat16(x));
}

__device__ __forceinline__ float fast_exp2(float x) {
#if __has_builtin(__builtin_amdgcn_exp2f)
    return __builtin_amdgcn_exp2f(x);
#else
    return exp2f(x);
#endif
}

// ---------------------------------------------------------------------------
// per-batch prefix sum of mask: cpos[b][s] = # valid before s, opos[b][j] =
// original pos of j-th valid, nv[b] = count. One 256-thr block per batch.
// ---------------------------------------------------------------------------
__global__ __launch_bounds__(256)
void scan_mask(const float* __restrict__ mask, int* __restrict__ cpos,
               int* __restrict__ opos, int* __restrict__ nv)
{
    __shared__ int cnt[256];
    const int b = blockIdx.x, tid = threadIdx.x;
    const int base = b * 2048 + tid * 8;
    int mloc = 0, c = 0;
    #pragma unroll
    for (int i = 0; i < 8; ++i) {
        const int v = (mask[base + i] != 0.f) ? 1 : 0;
        mloc |= v << i;
        c += v;
    }
    cnt[tid] = c;
    __syncthreads();
    for (int off = 1; off < 256; off <<= 1) {
        const int v = cnt[tid];
        const int add = (tid >= off) ? cnt[tid - off] : 0;
        __syncthreads();
        cnt[tid] = v + add;
        __syncthreads();
    }
    int excl = cnt[tid] - c;
    #pragma unroll
    for (int i = 0; i < 8; ++i) {
        cpos[base + i] = excl;
        if ((mloc >> i) & 1) {
            opos[b * 2048 + excl] = tid * 8 + i;
            ++excl;
        }
    }
    if (tid == 255) nv[b] = cnt[255];
}

// ---------------------------------------------------------------------------
// x f32 -> xh/xl bf16, COMPACTED rows (masked rows dropped). 1 row per block.
// ---------------------------------------------------------------------------
__global__ __launch_bounds__(256)
void split_x_c(const float* __restrict__ X, const float* __restrict__ mask,
               const int* __restrict__ cpos,
               unsigned short* __restrict__ Xh, unsigned short* __restrict__ Xl)
{
    const int row = blockIdx.x;            // 0..4095
    const int b = row >> 11, s = row & 2047;
    if (mask[(size_t)b * 2048 + s] == 0.f) return;
    const int cr = b * 2048 + cpos[b * 2048 + s];
    const int c4 = threadIdx.x * 4;
    const float4 v = *(const float4*)&X[(size_t)row * D_ + c4];
    unsigned short h[4], l[4];
    split2(v.x, h[0], l[0]); split2(v.y, h[1], l[1]);
    split2(v.z, h[2], l[2]); split2(v.w, h[3], l[3]);
    *(short4v*)&Xh[(size_t)cr * D_ + c4] =
        (short4v){(short)h[0],(short)h[1],(short)h[2],(short)h[3]};
    *(short4v*)&Xl[(size_t)cr * D_ + c4] =
        (short4v){(short)l[0],(short)l[1],(short)l[2],(short)l[3]};
}

// ---------------------------------------------------------------------------
// out[m][n] = bo[n] for all m (the exact result for masked rows).
// ---------------------------------------------------------------------------
__global__ __launch_bounds__(256)
void fill_out(float* __restrict__ out, const float* __restrict__ bo)
{
    const int i = blockIdx.x * 256 + threadIdx.x;   // float4 index
    ((float4*)out)[i] = ((const float4*)bo)[i & 255];
}

// ---------------------------------------------------------------------------
// transpose + split convert: W[K,N] f32 -> Th/Tl [N,K] bf16 (single weight)
// ---------------------------------------------------------------------------
__global__ __launch_bounds__(256)
void tconv_w(const float* __restrict__ W, unsigned short* __restrict__ Th,
             unsigned short* __restrict__ Tl, int K, int N)
{
    __shared__ float T[64][65];
    const int tid = threadIdx.x;
    const int k0 = blockIdx.x * 64, n0 = blockIdx.y * 64;
    #pragma unroll
    for (int p = 0; p < 4; ++p) {
        const int f = p * 256 + tid;
        const int r = f >> 4, c4 = (f & 15) << 2;
        const float4 v = *(const float4*)&W[(size_t)(k0 + r) * N + n0 + c4];
        T[r][c4] = v.x; T[r][c4 + 1] = v.y; T[r][c4 + 2] = v.z; T[r][c4 + 3] = v.w;
    }
    __syncthreads();
    #pragma unroll
    for (int p = 0; p < 4; ++p) {
        const int f = p * 256 + tid;
        const int r = f >> 4, c4 = (f & 15) << 2;
        unsigned short h[4], l[4];
        #pragma unroll
        for (int i = 0; i < 4; ++i) split2(T[c4 + i][r], h[i], l[i]);
        *(short4v*)&Th[(size_t)(n0 + r) * K + k0 + c4] =
            (short4v){(short)h[0],(short)h[1],(short)h[2],(short)h[3]};
        *(short4v*)&Tl[(size_t)(n0 + r) * K + k0 + c4] =
            (short4v){(short)l[0],(short)l[1],(short)l[2],(short)l[3]};
    }
}

__global__ __launch_bounds__(256)
void tconv_qkv(const float* __restrict__ W0, const float* __restrict__ W1,
               const float* __restrict__ W2, unsigned short* __restrict__ Th,
               unsigned short* __restrict__ Tl)
{
    __shared__ float T[64][65];
    const int z = blockIdx.z;
    const float* W = (z == 0) ? W0 : (z == 1) ? W1 : W2;
    unsigned short* th = Th + ((size_t)z << 20);
    unsigned short* tl = Tl + ((size_t)z << 20);
    const int tid = threadIdx.x;
    const int k0 = blockIdx.x * 64, n0 = blockIdx.y * 64;
    #pragma unroll
    for (int p = 0; p < 4; ++p) {
        const int f = p * 256 + tid;
        const int r = f >> 4, c4 = (f & 15) << 2;
        const float4 v = *(const float4*)&W[(size_t)(k0 + r) * D_ + n0 + c4];
        T[r][c4] = v.x; T[r][c4 + 1] = v.y; T[r][c4 + 2] = v.z; T[r][c4 + 3] = v.w;
    }
    __syncthreads();
    #pragma unroll
    for (int p = 0; p < 4; ++p) {
        const int f = p * 256 + tid;
        const int r = f >> 4, c4 = (f & 15) << 2;
        unsigned short h[4], l[4];
        #pragma unroll
        for (int i = 0; i < 4; ++i) split2(T[c4 + i][r], h[i], l[i]);
        *(short4v*)&th[(size_t)(n0 + r) * D_ + k0 + c4] =
            (short4v){(short)h[0],(short)h[1],(short)h[2],(short)h[3]};
        *(short4v*)&tl[(size_t)(n0 + r) * D_ + k0 + c4] =
            (short4v){(short)l[0],(short)l[1],(short)l[2],(short)l[3]};
    }
}

// ---------------------------------------------------------------------------
// Split GEMM, 128x128 tile, 4 waves (2x2), wave tile 64x64. Rows COMPACTED
// per batch; row-blocks entirely beyond nv[b] exit early; tail stores
// predicated. MODE 0: f32 out scattered to original rows via opos (+bias).
// MODE 1: QKV routed epilogue (Q hi/lo, K hi, V^T hi), compacted positions.
// ---------------------------------------------------------------------------
template<int MODE>
__global__ __launch_bounds__(256, 2)
void gemm128(const unsigned short* __restrict__ Ah, const unsigned short* __restrict__ Al,
             const unsigned short* __restrict__ Bh, const unsigned short* __restrict__ Bl,
             const float* __restrict__ b0, const float* __restrict__ b1,
             const float* __restrict__ b2, float* __restrict__ Cf,
             unsigned short* __restrict__ Oqh, unsigned short* __restrict__ Oql,
             unsigned short* __restrict__ Okh, unsigned short* __restrict__ Ovt,
             const int* __restrict__ nv, const int* __restrict__ opos)
{
    const int m0 = blockIdx.x * 128, n0 = blockIdx.y * 128;
    const int bb = m0 >> 11;
    const int nvb = nv[bb];
    if ((m0 & 2047) >= nvb) return;   // whole row-block masked out

    __shared__ unsigned short As_h[128 * 64], As_l[128 * 64];
    __shared__ unsigned short Bs_h[128 * 64], Bs_l[128 * 64];

    const int tid = threadIdx.x;
    const int lane = tid & 63, w = tid >> 6;
    const int wm = w >> 1, wn = w & 1;
    const int l15 = lane & 15, l4 = lane >> 4;
    const int lr = lane >> 3, lc = lane & 7;

    f32x4 acc[4][4];
    #pragma unroll
    for (int i = 0; i < 4; ++i)
        #pragma unroll
        for (int j = 0; j < 4; ++j) acc[i][j] = (f32x4){0.f, 0.f, 0.f, 0.f};

    for (int kt = 0; kt < D_; kt += 64) {
        __syncthreads();
        #pragma unroll
        for (int t = 0; t < 4; ++t) {
            const int row = w * 32 + t * 8 + lr;
            const int kc = lc ^ (row & 7);
            const size_t ga = (size_t)(m0 + row) * D_ + kt + kc * 8;
            gl_lds16(&Ah[ga], &As_h[(w * 32 + t * 8) * 64]);
            gl_lds16(&Al[ga], &As_l[(w * 32 + t * 8) * 64]);
            const size_t gb = (size_t)(n0 + row) * D_ + kt + kc * 8;
            gl_lds16(&Bh[gb], &Bs_h[(w * 32 + t * 8) * 64]);
            gl_lds16(&Bl[gb], &Bs_l[(w * 32 + t * 8) * 64]);
        }
        __syncthreads();

        #pragma unroll
        for (int kk = 0; kk < 2; ++kk) {
            bf16x8 ah[4], al[4], bh4[4], bl4[4];
            #pragma unroll
            for (int i = 0; i < 4; ++i) {
                const int row = wm * 64 + i * 16 + l15;
                const int off = row * 64 + (((kk * 4 + l4) ^ (row & 7)) << 3);
                ah[i] = *(const bf16x8*)&As_h[off];
                al[i] = *(const bf16x8*)&As_l[off];
            }
            #pragma unroll
            for (int j = 0; j < 4; ++j) {
                const int row = wn * 64 + j * 16 + l15;
                const int off = row * 64 + (((kk * 4 + l4) ^ (row & 7)) << 3);
                bh4[j] = *(const bf16x8*)&Bs_h[off];
                bl4[j] = *(const bf16x8*)&Bs_l[off];
            }
            #pragma unroll
            for (int i = 0; i < 4; ++i)
                #pragma unroll
                for (int j = 0; j < 4; ++j) {
                    acc[i][j] = MFMA(ah[i], bh4[j], acc[i][j]);
                    acc[i][j] = MFMA(ah[i], bl4[j], acc[i][j]);
                    acc[i][j] = MFMA(al[i], bh4[j], acc[i][j]);
                }
        }
    }

    if constexpr (MODE == 0) {
        const int* op = opos + bb * 2048;
        #pragma unroll
        for (int i = 0; i < 4; ++i) {
            const int m = m0 + wm * 64 + i * 16 + l4 * 4;
            #pragma unroll
            for (int j = 0; j < 4; ++j) {
                const int n = n0 + wn * 64 + j * 16 + l15;
                const float bvv = b0[n];
                #pragma unroll
                for (int r = 0; r < 4; ++r) {
                    const int jr = (m & 2047) + r;
                    if (jr < nvb)
                        Cf[((size_t)bb * 2048 + op[jr]) * OUT_ + n] = acc[i][j][r] + bvv;
                }
            }
        }
    } else {
        const int idx = n0 >> 10;   // 0=Q 1=K 2=V
        const float* bp = (idx == 0) ? b0 : (idx == 1) ? b1 : b2;
        #pragma unroll
        for (int i = 0; i < 4; ++i) {
            const int m = m0 + wm * 64 + i * 16 + l4 * 4;
            const int jm = m & 2047;
            #pragma unroll
            for (int j = 0; j < 4; ++j) {
                const int nG = n0 + wn * 64 + j * 16 + l15;
                const int c = nG & 1023;
                const float bvv = bp[c];
                const int hh = c >> 6, dd = c & 63;
                if (idx == 0) {
                    const size_t base = ((size_t)(bb * H_ + hh) * S_ + jm) * 64 + dd;
                    #pragma unroll
                    for (int r = 0; r < 4; ++r)
                        if (jm + r < nvb) {
                            unsigned short vh, vl;
                            split2(acc[i][j][r] + bvv, vh, vl);
                            Oqh[base + (size_t)r * 64] = vh;
                            Oql[base + (size_t)r * 64] = vl;
                        }
                } else if (idx == 1) {
                    const size_t base = ((size_t)(bb * H_ + hh) * S_ + jm) * 64 + dd;
                    #pragma unroll
                    for (int r = 0; r < 4; ++r)
                        if (jm + r < nvb)
                            Okh[base + (size_t)r * 64] = bf16_rne(acc[i][j][r] + bvv);
                } else {
                    unsigned short pv[4];
                    #pragma unroll
                    for (int r = 0; r < 4; ++r) pv[r] = bf16_rne(acc[i][j][r] + bvv);
                    const size_t vb = ((size_t)(bb * H_ + hh) * 64 + dd) * (size_t)S_ + jm;
                    if (jm + 3 < nvb) {
                        *(short4v*)&Ovt[vb] =
                            (short4v){(short)pv[0],(short)pv[1],(short)pv[2],(short)pv[3]};
                    } else {
                        #pragma unroll
                        for (int r = 0; r < 4; ++r)
                            if (jm + r < nvb) Ovt[vb + r] = pv[r];
                    }
                }
            }
        }
    }
}

// ---------------------------------------------------------------------------
// Flash attention on COMPACTED q/k (all valid): no mask logic except a tail
// integer compare. 8 waves x 16 q-rows, 2-phase dbuf. Writes msgs compacted.
// ---------------------------------------------------------------------------
__global__ __launch_bounds__(512, 4)
void attn_mfma(const unsigned short* __restrict__ Qh, const unsigned short* __restrict__ Ql,
               const unsigned short* __restrict__ Kh, const unsigned short* __restrict__ Vt,
               const int* __restrict__ nv,
               unsigned short* __restrict__ Mh, unsigned short* __restrict__ Ml)
{
    const int bh = blockIdx.x, b = bh >> 4;
    const int nvb = nv[b];
    const int q0 = blockIdx.y * 128;
    if (q0 >= nvb) return;

    __shared__ unsigned short Ks[2][64 * 64];
    __shared__ unsigned short Vts[2][64 * 64];
    __shared__ unsigned short Psb[128 * 72];

    const float SC2  = 0.125f * 1.4426950408889634f;
    const float THR2 = 11.5415603f;
    const float MINIT = -1e5f;
    const float NEGB  = -1e30f;

    const int tid = threadIdx.x;
    const int lane = tid & 63, w = tid >> 6;
    const int l15 = lane & 15, l4 = lane >> 4;
    const int qw = q0 + w * 16;

    const int srow = w * 8 + (lane >> 3);
    const int skc  = (lane & 7) ^ (srow & 7);

    // Q fragments; rows beyond nv clamp to last valid row (discarded at write)
    bf16x8 qh[2], ql[2];
    {
        const int qr = min(qw + l15, nvb - 1);
        const size_t qbase = ((size_t)bh * S_ + qr) * 64;
        #pragma unroll
        for (int kk = 0; kk < 2; ++kk) {
            qh[kk] = *(const bf16x8*)&Qh[qbase + kk * 32 + l4 * 8];
            ql[kk] = *(const bf16x8*)&Ql[qbase + kk * 32 + l4 * 8];
        }
    }

    float m2[4], lp[4];
    f32x4 O[4];
    #pragma unroll
    for (int r = 0; r < 4; ++r) { m2[r] = MINIT; lp[r] = 0.f; }
    #pragma unroll
    for (int df = 0; df < 4; ++df) O[df] = (f32x4){0.f, 0.f, 0.f, 0.f};

    const int NT = (nvb + 63) >> 6;

#define STAGE(KT, SEL)                                                          \
    do {                                                                        \
        gl_lds16(&Kh[((size_t)bh * S_ + (KT) + srow) * 64 + skc * 8],           \
                 &Ks[SEL][(w * 8) * 64]);                                       \
        gl_lds16(&Vt[((size_t)bh * 64 + srow) * (size_t)S_ + (KT) + skc * 8],   \
                 &Vts[SEL][(w * 8) * 64]);                                      \
    } while (0)

    STAGE(0, 0);
    __syncthreads();

    int cur = 0;
    for (int ti = 0; ti < NT; ++ti, cur ^= 1) {
        const int kt = ti * 64;
        if (ti + 1 < NT) STAGE((ti + 1) * 64, cur ^ 1);

        // QK^T (K hi-only)
        f32x4 s[4];
        #pragma unroll
        for (int nf = 0; nf < 4; ++nf) s[nf] = (f32x4){0.f, 0.f, 0.f, 0.f};
        #pragma unroll
        for (int nf = 0; nf < 4; ++nf) {
            const int krow = nf * 16 + l15;
            #pragma unroll
            for (int kk = 0; kk < 2; ++kk) {
                const int off = krow * 64 + (((kk * 4 + l4) ^ (krow & 7)) << 3);
                const bf16x8 kh8 = *(const bf16x8*)&Ks[cur][off];
                s[nf] = MFMA(qh[kk], kh8, s[nf]);
                s[nf] = MFMA(ql[kk], kh8, s[nf]);
            }
        }

        // tail padding mask (integer compare) + log2 scale; defer-max gate
        float addk[4];
        #pragma unroll
        for (int nf = 0; nf < 4; ++nf)
            addk[nf] = (kt + nf * 16 + l15 < nvb) ? 0.f : NEGB;

        float lm[4];
        bool need = false;
        #pragma unroll
        for (int r = 0; r < 4; ++r) {
            float v0 = fmaf(s[0][r], SC2, addk[0]);
            float v1 = fmaf(s[1][r], SC2, addk[1]);
            float v2 = fmaf(s[2][r], SC2, addk[2]);
            float v3 = fmaf(s[3][r], SC2, addk[3]);
            s[0][r] = v0; s[1][r] = v1; s[2][r] = v2; s[3][r] = v3;
            const float rm = fmaxf(fmaxf(v0, v1), fmaxf(v2, v3));
            lm[r] = rm;
            need |= (rm > m2[r] + THR2);
        }

        if (__any(need)) {
            #pragma unroll
            for (int r = 0; r < 4; ++r) {
                float rm = lm[r];
                rm = fmaxf(rm, __shfl_xor(rm, 1));
                rm = fmaxf(rm, __shfl_xor(rm, 2));
                rm = fmaxf(rm, __shfl_xor(rm, 4));
                rm = fmaxf(rm, __shfl_xor(rm, 8));
                const float mnew = fmaxf(m2[r], rm);
                const float sc = fast_exp2(m2[r] - mnew);
                lp[r] *= sc;
                m2[r] = mnew;
                #pragma unroll
                for (int df = 0; df < 4; ++df) O[df][r] *= sc;
            }
        }

        // exp2 + partial l; write P (bf16 RNE) to swizzled Psb
        #pragma unroll
        for (int r = 0; r < 4; ++r) {
            const float mm = m2[r];
            const int qq = w * 16 + l4 * 4 + r;
            const int qbase = qq * 72;
            const int qswz = qq & 7;
            float rs = 0.f;
            #pragma unroll
            for (int nf = 0; nf < 4; ++nf) {
                const float pv = fast_exp2(s[nf][r] - mm);
                rs += pv;
                const int key = nf * 16 + l15;
                Psb[qbase + (((key >> 3) ^ qswz) << 3) + (key & 7)] = bf16_rne(pv);
            }
            lp[r] += rs;
        }

        // PV per key-half
        #pragma unroll
        for (int kk = 0; kk < 2; ++kk) {
            const int qq = w * 16 + l15;
            const bf16x8 ph = *(const bf16x8*)
                &Psb[qq * 72 + ((((kk * 4) + l4) ^ (qq & 7)) << 3)];
            #pragma unroll
            for (int df = 0; df < 4; ++df) {
                const int vrow = df * 16 + l15;
                const int off = vrow * 64 + (((kk * 4 + l4) ^ (vrow & 7)) << 3);
                const bf16x8 vb = *(const bf16x8*)&Vts[cur][off];
                O[df] = MFMA(ph, vb, O[df]);
            }
        }

        __syncthreads();
    }
#undef STAGE

    // epilogue: l-reduce; write valid compacted rows only
    #pragma unroll
    for (int r = 0; r < 4; ++r) {
        float t = lp[r];
        t += __shfl_xor(t, 1);
        t += __shfl_xor(t, 2);
        t += __shfl_xor(t, 4);
        t += __shfl_xor(t, 8);
        const int j = qw + l4 * 4 + r;
        if (j < nvb) {
            const float inv = (t > 0.f) ? 1.f / t : 0.f;
            const size_t base = ((size_t)b * S_ + j) * D_ + (bh & 15) * DH_;
            #pragma unroll
            for (int df = 0; df < 4; ++df) {
                unsigned short vh, vl;
                split2(O[df][r] * inv, vh, vl);
                Mh[base + df * 16 + l15] = vh;
                Ml[base + df * 16 + l15] = vl;
            }
        }
    }
}

// ---------------------------------------------------------------------------
extern "C" void kernel_launch(void* const* d_in, const int* in_sizes, int n_in,
                              void* d_out, int out_size, void* d_ws, size_t ws_size,
                              hipStream_t stream)
{
    const float* x    = (const float*)d_in[0];
    const float* mask = (const float*)d_in[1];
    const float* Wq   = (const float*)d_in[2];
    const float* bq   = (const float*)d_in[3];
    const float* Wk   = (const float*)d_in[4];
    const float* bk   = (const float*)d_in[5];
    const float* Wv   = (const float*)d_in[6];
    const float* bv   = (const float*)d_in[7];
    const float* Wo   = (const float*)d_in[8];
    const float* bo   = (const float*)d_in[9];
    float* out = (float*)d_out;

    char* ws = (char*)d_ws;
    unsigned short* xh = (unsigned short*)(ws);                      // 8MB (later mh)
    unsigned short* xl = (unsigned short*)(ws + ((size_t) 8 << 20)); // 8MB (later ml)
    unsigned short* qh = (unsigned short*)(ws + ((size_t)16 << 20));
    unsigned short* qll= (unsigned short*)(ws + ((size_t)24 << 20));
    unsigned short* kh = (unsigned short*)(ws + ((size_t)32 << 20));
    unsigned short* vt = (unsigned short*)(ws + ((size_t)40 << 20)); // V^T [bh][d][s]
    unsigned short* wc_h = (unsigned short*)(ws + ((size_t)48 << 20)); // 6MB
    unsigned short* wc_l = (unsigned short*)(ws + ((size_t)54 << 20)); // 6MB
    unsigned short* wo_h = wc_h;            // reuse after QKV GEMM
    unsigned short* wo_l = (unsigned short*)(ws + ((size_t)50 << 20));
    unsigned short* mh = xh;                // x dead after QKV GEMM
    unsigned short* ml = xl;
    int* cpos = (int*)(ws + ((size_t)60 << 20));          // 16KB
    int* opos = (int*)(ws + ((size_t)60 << 20) + 16384);  // 16KB
    int* nv   = (int*)(ws + ((size_t)60 << 20) + 32768);  // 8B

    const dim3 blk(256);
    scan_mask<<<dim3(B_), blk, 0, stream>>>(mask, cpos, opos, nv);
    split_x_c<<<dim3(M_), blk, 0, stream>>>(x, mask, cpos, xh, xl);
    tconv_qkv<<<dim3(16, 16, 3), blk, 0, stream>>>(Wq, Wk, Wv, wc_h, wc_l);

    gemm128<1><<<dim3(M_ / 128, 3 * D_ / 128), blk, 0, stream>>>(
        xh, xl, wc_h, wc_l, bq, bk, bv, nullptr, qh, qll, kh, vt, nv, nullptr);

    tconv_w<<<dim3(16, 16), blk, 0, stream>>>(Wo, wo_h, wo_l, D_, OUT_);

    attn_mfma<<<dim3(B_ * H_, S_ / 128), dim3(512), 0, stream>>>(
        qh, qll, kh, vt, nv, mh, ml);

    fill_out<<<dim3(M_ * OUT_ / 4 / 256), blk, 0, stream>>>(out, bo);

    gemm128<0><<<dim3(M_ / 128, OUT_ / 128), blk, 0, stream>>>(
        mh, ml, wo_h, wo_l, bo, nullptr, nullptr, out,
        nullptr, nullptr, nullptr, nullptr, nv, opos);
}

// Round 11
// 158.389 us; speedup vs baseline: 7.1052x; 1.1181x over previous
//
#include <hip/hip_runtime.h>
#include <hip/hip_bf16.h>
#include <math.h>

#define B_   2
#define S_   2048
#define H_   16
#define DH_  64
#define D_   1024
#define OUT_ 1024
#define M_   (B_ * S_)   // 4096

typedef __attribute__((ext_vector_type(8))) short bf16x8;
typedef __attribute__((ext_vector_type(4))) float f32x4;
typedef __attribute__((ext_vector_type(4))) short short4v;

#define MFMA(a, b, c) __builtin_amdgcn_mfma_f32_16x16x32_bf16((a), (b), (c), 0, 0, 0)

__device__ __forceinline__ void gl_lds16(const void* g, void* l) {
    __builtin_amdgcn_global_load_lds(
        (const __attribute__((address_space(1))) unsigned int*)g,
        (__attribute__((address_space(3))) unsigned int*)l, 16, 0, 0);
}

__device__ __forceinline__ void split2(float x, unsigned short& h, unsigned short& l) {
    unsigned u = __float_as_uint(x);
    h = (unsigned short)(u >> 16);
    float lo = x - __uint_as_float(u & 0xFFFF0000u);
    l = (unsigned short)(__float_as_uint(lo) >> 16);
}

__device__ __forceinline__ unsigned short bf16_rne(float x) {
    return __builtin_bit_cast(unsigned short, __float2bfloat16(x));
}

__device__ __forceinline__ float fast_exp2(float x) {
#if __has_builtin(__builtin_amdgcn_exp2f)
    return __builtin_amdgcn_exp2f(x);
#else
    return exp2f(x);
#endif
}

// ---------------------------------------------------------------------------
// per-batch prefix sum of mask
// ---------------------------------------------------------------------------
__global__ __launch_bounds__(256)
void scan_mask(const float* __restrict__ mask, int* __restrict__ cpos,
               int* __restrict__ opos, int* __restrict__ nv)
{
    __shared__ int cnt[256];
    const int b = blockIdx.x, tid = threadIdx.x;
    const int base = b * 2048 + tid * 8;
    int mloc = 0, c = 0;
    #pragma unroll
    for (int i = 0; i < 8; ++i) {
        const int v = (mask[base + i] != 0.f) ? 1 : 0;
        mloc |= v << i;
        c += v;
    }
    cnt[tid] = c;
    __syncthreads();
    for (int off = 1; off < 256; off <<= 1) {
        const int v = cnt[tid];
        const int add = (tid >= off) ? cnt[tid - off] : 0;
        __syncthreads();
        cnt[tid] = v + add;
        __syncthreads();
    }
    int excl = cnt[tid] - c;
    #pragma unroll
    for (int i = 0; i < 8; ++i) {
        cpos[base + i] = excl;
        if ((mloc >> i) & 1) {
            opos[b * 2048 + excl] = tid * 8 + i;
            ++excl;
        }
    }
    if (tid == 255) nv[b] = cnt[255];
}

// ---------------------------------------------------------------------------
__global__ __launch_bounds__(256)
void split_x_c(const float* __restrict__ X, const float* __restrict__ mask,
               const int* __restrict__ cpos,
               unsigned short* __restrict__ Xh, unsigned short* __restrict__ Xl)
{
    const int row = blockIdx.x;            // 0..4095
    const int b = row >> 11, s = row & 2047;
    if (mask[(size_t)b * 2048 + s] == 0.f) return;
    const int cr = b * 2048 + cpos[b * 2048 + s];
    const int c4 = threadIdx.x * 4;
    const float4 v = *(const float4*)&X[(size_t)row * D_ + c4];
    unsigned short h[4], l[4];
    split2(v.x, h[0], l[0]); split2(v.y, h[1], l[1]);
    split2(v.z, h[2], l[2]); split2(v.w, h[3], l[3]);
    *(short4v*)&Xh[(size_t)cr * D_ + c4] =
        (short4v){(short)h[0],(short)h[1],(short)h[2],(short)h[3]};
    *(short4v*)&Xl[(size_t)cr * D_ + c4] =
        (short4v){(short)l[0],(short)l[1],(short)l[2],(short)l[3]};
}

// ---------------------------------------------------------------------------
__global__ __launch_bounds__(256)
void fill_out(float* __restrict__ out, const float* __restrict__ bo)
{
    const int i = blockIdx.x * 256 + threadIdx.x;   // float4 index
    ((float4*)out)[i] = ((const float4*)bo)[i & 255];
}

// ---------------------------------------------------------------------------
__global__ __launch_bounds__(256)
void tconv_w(const float* __restrict__ W, unsigned short* __restrict__ Th,
             unsigned short* __restrict__ Tl, int K, int N)
{
    __shared__ float T[64][65];
    const int tid = threadIdx.x;
    const int k0 = blockIdx.x * 64, n0 = blockIdx.y * 64;
    #pragma unroll
    for (int p = 0; p < 4; ++p) {
        const int f = p * 256 + tid;
        const int r = f >> 4, c4 = (f & 15) << 2;
        const float4 v = *(const float4*)&W[(size_t)(k0 + r) * N + n0 + c4];
        T[r][c4] = v.x; T[r][c4 + 1] = v.y; T[r][c4 + 2] = v.z; T[r][c4 + 3] = v.w;
    }
    __syncthreads();
    #pragma unroll
    for (int p = 0; p < 4; ++p) {
        const int f = p * 256 + tid;
        const int r = f >> 4, c4 = (f & 15) << 2;
        unsigned short h[4], l[4];
        #pragma unroll
        for (int i = 0; i < 4; ++i) split2(T[c4 + i][r], h[i], l[i]);
        *(short4v*)&Th[(size_t)(n0 + r) * K + k0 + c4] =
            (short4v){(short)h[0],(short)h[1],(short)h[2],(short)h[3]};
        *(short4v*)&Tl[(size_t)(n0 + r) * K + k0 + c4] =
            (short4v){(short)l[0],(short)l[1],(short)l[2],(short)l[3]};
    }
}

__global__ __launch_bounds__(256)
void tconv_qkv(const float* __restrict__ W0, const float* __restrict__ W1,
               const float* __restrict__ W2, unsigned short* __restrict__ Th,
               unsigned short* __restrict__ Tl)
{
    __shared__ float T[64][65];
    const int z = blockIdx.z;
    const float* W = (z == 0) ? W0 : (z == 1) ? W1 : W2;
    unsigned short* th = Th + ((size_t)z << 20);
    unsigned short* tl = Tl + ((size_t)z << 20);
    const int tid = threadIdx.x;
    const int k0 = blockIdx.x * 64, n0 = blockIdx.y * 64;
    #pragma unroll
    for (int p = 0; p < 4; ++p) {
        const int f = p * 256 + tid;
        const int r = f >> 4, c4 = (f & 15) << 2;
        const float4 v = *(const float4*)&W[(size_t)(k0 + r) * D_ + n0 + c4];
        T[r][c4] = v.x; T[r][c4 + 1] = v.y; T[r][c4 + 2] = v.z; T[r][c4 + 3] = v.w;
    }
    __syncthreads();
    #pragma unroll
    for (int p = 0; p < 4; ++p) {
        const int f = p * 256 + tid;
        const int r = f >> 4, c4 = (f & 15) << 2;
        unsigned short h[4], l[4];
        #pragma unroll
        for (int i = 0; i < 4; ++i) split2(T[c4 + i][r], h[i], l[i]);
        *(short4v*)&th[(size_t)(n0 + r) * D_ + k0 + c4] =
            (short4v){(short)h[0],(short)h[1],(short)h[2],(short)h[3]};
        *(short4v*)&tl[(size_t)(n0 + r) * D_ + k0 + c4] =
            (short4v){(short)l[0],(short)l[1],(short)l[2],(short)l[3]};
    }
}

// ---------------------------------------------------------------------------
// QKV GEMM, 128x128 tile, 8 WAVES (512 thr), wave tile 32x64 (acc 2x4).
// Waves 0-3 stage A (hi/lo), waves 4-7 stage B. Compacted rows; early exit.
// Q cols: 3-term split (stored hi/lo). K/V cols: 2-term (stored bf16-RNE
// anyway, so 2-term error ~2^-9 matches the storage rounding).
// ---------------------------------------------------------------------------
__global__ __launch_bounds__(512, 2)
void gemm_qkv512(const unsigned short* __restrict__ Ah, const unsigned short* __restrict__ Al,
                 const unsigned short* __restrict__ Bh, const unsigned short* __restrict__ Bl,
                 const float* __restrict__ bq, const float* __restrict__ bk,
                 const float* __restrict__ bv,
                 unsigned short* __restrict__ Oqh, unsigned short* __restrict__ Oql,
                 unsigned short* __restrict__ Okh, unsigned short* __restrict__ Ovt,
                 const int* __restrict__ nv)
{
    const int m0 = blockIdx.x * 128, n0 = blockIdx.y * 128;
    const int bb = m0 >> 11;
    const int nvb = nv[bb];
    if ((m0 & 2047) >= nvb) return;

    __shared__ unsigned short As_h[128 * 64], As_l[128 * 64];
    __shared__ unsigned short Bs_h[128 * 64], Bs_l[128 * 64];

    const int tid = threadIdx.x;
    const int lane = tid & 63, w = tid >> 6;          // 8 waves
    const int wm = w >> 1, wn = w & 1;                // 4x2 wave grid, 32x64 each
    const int l15 = lane & 15, l4 = lane >> 4;
    const int lr = lane >> 3, lc = lane & 7;
    const int idx = n0 >> 10;                         // 0=Q 1=K 2=V

    f32x4 acc[2][4];
    #pragma unroll
    for (int i = 0; i < 2; ++i)
        #pragma unroll
        for (int j = 0; j < 4; ++j) acc[i][j] = (f32x4){0.f, 0.f, 0.f, 0.f};

    for (int kt = 0; kt < D_; kt += 64) {
        __syncthreads();
        if (w < 4) {       // A: 128 rows hi + lo; wave w covers rows w*32..+31
            #pragma unroll
            for (int t = 0; t < 4; ++t) {
                const int row = w * 32 + t * 8 + lr;
                const int kc = lc ^ (row & 7);
                const size_t g = (size_t)(m0 + row) * D_ + kt + kc * 8;
                gl_lds16(&Ah[g], &As_h[(w * 32 + t * 8) * 64]);
                gl_lds16(&Al[g], &As_l[(w * 32 + t * 8) * 64]);
            }
        } else {           // B
            const int w2 = w - 4;
            #pragma unroll
            for (int t = 0; t < 4; ++t) {
                const int row = w2 * 32 + t * 8 + lr;
                const int kc = lc ^ (row & 7);
                const size_t g = (size_t)(n0 + row) * D_ + kt + kc * 8;
                gl_lds16(&Bh[g], &Bs_h[(w2 * 32 + t * 8) * 64]);
                gl_lds16(&Bl[g], &Bs_l[(w2 * 32 + t * 8) * 64]);
            }
        }
        __syncthreads();

        #pragma unroll
        for (int kk = 0; kk < 2; ++kk) {
            bf16x8 ah[2], al[2], bh4[4], bl4[4];
            #pragma unroll
            for (int i = 0; i < 2; ++i) {
                const int row = wm * 32 + i * 16 + l15;
                const int off = row * 64 + (((kk * 4 + l4) ^ (row & 7)) << 3);
                ah[i] = *(const bf16x8*)&As_h[off];
                al[i] = *(const bf16x8*)&As_l[off];
            }
            #pragma unroll
            for (int j = 0; j < 4; ++j) {
                const int row = wn * 64 + j * 16 + l15;
                const int off = row * 64 + (((kk * 4 + l4) ^ (row & 7)) << 3);
                bh4[j] = *(const bf16x8*)&Bs_h[off];
                bl4[j] = *(const bf16x8*)&Bs_l[off];
            }
            #pragma unroll
            for (int i = 0; i < 2; ++i)
                #pragma unroll
                for (int j = 0; j < 4; ++j) {
                    acc[i][j] = MFMA(ah[i], bh4[j], acc[i][j]);
                    acc[i][j] = MFMA(ah[i], bl4[j], acc[i][j]);
                }
            if (idx == 0) {   // Q needs the 3rd term (stored hi/lo)
                #pragma unroll
                for (int i = 0; i < 2; ++i)
                    #pragma unroll
                    for (int j = 0; j < 4; ++j)
                        acc[i][j] = MFMA(al[i], bh4[j], acc[i][j]);
            }
        }
    }

    const float* bp = (idx == 0) ? bq : (idx == 1) ? bk : bv;
    #pragma unroll
    for (int i = 0; i < 2; ++i) {
        const int m = m0 + wm * 32 + i * 16 + l4 * 4;
        const int jm = m & 2047;
        #pragma unroll
        for (int j = 0; j < 4; ++j) {
            const int nG = n0 + wn * 64 + j * 16 + l15;
            const int c = nG & 1023;
            const float bvv = bp[c];
            const int hh = c >> 6, dd = c & 63;
            if (idx == 0) {
                const size_t base = ((size_t)(bb * H_ + hh) * S_ + jm) * 64 + dd;
                #pragma unroll
                for (int r = 0; r < 4; ++r)
                    if (jm + r < nvb) {
                        unsigned short vh, vl;
                        split2(acc[i][j][r] + bvv, vh, vl);
                        Oqh[base + (size_t)r * 64] = vh;
                        Oql[base + (size_t)r * 64] = vl;
                    }
            } else if (idx == 1) {
                const size_t base = ((size_t)(bb * H_ + hh) * S_ + jm) * 64 + dd;
                #pragma unroll
                for (int r = 0; r < 4; ++r)
                    if (jm + r < nvb)
                        Okh[base + (size_t)r * 64] = bf16_rne(acc[i][j][r] + bvv);
            } else {
                unsigned short pv[4];
                #pragma unroll
                for (int r = 0; r < 4; ++r) pv[r] = bf16_rne(acc[i][j][r] + bvv);
                const size_t vb = ((size_t)(bb * H_ + hh) * 64 + dd) * (size_t)S_ + jm;
                if (jm + 3 < nvb) {
                    *(short4v*)&Ovt[vb] =
                        (short4v){(short)pv[0],(short)pv[1],(short)pv[2],(short)pv[3]};
                } else {
                    #pragma unroll
                    for (int r = 0; r < 4; ++r)
                        if (jm + r < nvb) Ovt[vb + r] = pv[r];
                }
            }
        }
    }
}

// ---------------------------------------------------------------------------
// Output GEMM, 64x64 tile (more blocks -> occupancy), 4 waves, wave 32x32.
// 3-term split. Scatter to original rows via opos (+bias), predicated.
// ---------------------------------------------------------------------------
__global__ __launch_bounds__(256, 4)
void gemm_out64(const unsigned short* __restrict__ Ah, const unsigned short* __restrict__ Al,
                const unsigned short* __restrict__ Bh, const unsigned short* __restrict__ Bl,
                const float* __restrict__ bias, float* __restrict__ Cf,
                const int* __restrict__ nv, const int* __restrict__ opos)
{
    const int m0 = blockIdx.x * 64, n0 = blockIdx.y * 64;
    const int bb = m0 >> 11;
    const int nvb = nv[bb];
    if ((m0 & 2047) >= nvb) return;

    __shared__ unsigned short As_h[64 * 64], As_l[64 * 64];
    __shared__ unsigned short Bs_h[64 * 64], Bs_l[64 * 64];

    const int tid = threadIdx.x;
    const int lane = tid & 63, w = tid >> 6;
    const int wm = w >> 1, wn = w & 1;                // 2x2 wave grid, 32x32 each
    const int l15 = lane & 15, l4 = lane >> 4;
    const int lr = lane >> 3, lc = lane & 7;

    f32x4 acc[2][2];
    #pragma unroll
    for (int i = 0; i < 2; ++i)
        #pragma unroll
        for (int j = 0; j < 2; ++j) acc[i][j] = (f32x4){0.f, 0.f, 0.f, 0.f};

    for (int kt = 0; kt < D_; kt += 64) {
        __syncthreads();
        #pragma unroll
        for (int t = 0; t < 2; ++t) {
            const int row = w * 16 + t * 8 + lr;
            const int kc = lc ^ (row & 7);
            const size_t ga = (size_t)(m0 + row) * D_ + kt + kc * 8;
            gl_lds16(&Ah[ga], &As_h[(w * 16 + t * 8) * 64]);
            gl_lds16(&Al[ga], &As_l[(w * 16 + t * 8) * 64]);
            const size_t gb = (size_t)(n0 + row) * D_ + kt + kc * 8;
            gl_lds16(&Bh[gb], &Bs_h[(w * 16 + t * 8) * 64]);
            gl_lds16(&Bl[gb], &Bs_l[(w * 16 + t * 8) * 64]);
        }
        __syncthreads();

        #pragma unroll
        for (int kk = 0; kk < 2; ++kk) {
            bf16x8 ah[2], al[2], bh2[2], bl2[2];
            #pragma unroll
            for (int i = 0; i < 2; ++i) {
                const int row = wm * 32 + i * 16 + l15;
                const int off = row * 64 + (((kk * 4 + l4) ^ (row & 7)) << 3);
                ah[i] = *(const bf16x8*)&As_h[off];
                al[i] = *(const bf16x8*)&As_l[off];
            }
            #pragma unroll
            for (int j = 0; j < 2; ++j) {
                const int row = wn * 32 + j * 16 + l15;
                const int off = row * 64 + (((kk * 4 + l4) ^ (row & 7)) << 3);
                bh2[j] = *(const bf16x8*)&Bs_h[off];
                bl2[j] = *(const bf16x8*)&Bs_l[off];
            }
            #pragma unroll
            for (int i = 0; i < 2; ++i)
                #pragma unroll
                for (int j = 0; j < 2; ++j) {
                    acc[i][j] = MFMA(ah[i], bh2[j], acc[i][j]);
                    acc[i][j] = MFMA(ah[i], bl2[j], acc[i][j]);
                    acc[i][j] = MFMA(al[i], bh2[j], acc[i][j]);
                }
        }
    }

    const int* op = opos + bb * 2048;
    #pragma unroll
    for (int i = 0; i < 2; ++i) {
        const int m = m0 + wm * 32 + i * 16 + l4 * 4;
        #pragma unroll
        for (int j = 0; j < 2; ++j) {
            const int n = n0 + wn * 32 + j * 16 + l15;
            const float bvv = bias[n];
            #pragma unroll
            for (int r = 0; r < 4; ++r) {
                const int jr = (m & 2047) + r;
                if (jr < nvb)
                    Cf[((size_t)bb * 2048 + op[jr]) * OUT_ + n] = acc[i][j][r] + bvv;
            }
        }
    }
}

// ---------------------------------------------------------------------------
// Flash attention on COMPACTED q/k. 8 waves x 16 q-rows, 2-phase dbuf.
// ---------------------------------------------------------------------------
__global__ __launch_bounds__(512, 4)
void attn_mfma(const unsigned short* __restrict__ Qh, const unsigned short* __restrict__ Ql,
               const unsigned short* __restrict__ Kh, const unsigned short* __restrict__ Vt,
               const int* __restrict__ nv,
               unsigned short* __restrict__ Mh, unsigned short* __restrict__ Ml)
{
    const int bh = blockIdx.x, b = bh >> 4;
    const int nvb = nv[b];
    const int q0 = blockIdx.y * 128;
    if (q0 >= nvb) return;

    __shared__ unsigned short Ks[2][64 * 64];
    __shared__ unsigned short Vts[2][64 * 64];
    __shared__ unsigned short Psb[128 * 72];

    const float SC2  = 0.125f * 1.4426950408889634f;
    const float THR2 = 11.5415603f;
    const float MINIT = -1e5f;
    const float NEGB  = -1e30f;

    const int tid = threadIdx.x;
    const int lane = tid & 63, w = tid >> 6;
    const int l15 = lane & 15, l4 = lane >> 4;
    const int qw = q0 + w * 16;

    const int srow = w * 8 + (lane >> 3);
    const int skc  = (lane & 7) ^ (srow & 7);

    bf16x8 qh[2], ql[2];
    {
        const int qr = min(qw + l15, nvb - 1);
        const size_t qbase = ((size_t)bh * S_ + qr) * 64;
        #pragma unroll
        for (int kk = 0; kk < 2; ++kk) {
            qh[kk] = *(const bf16x8*)&Qh[qbase + kk * 32 + l4 * 8];
            ql[kk] = *(const bf16x8*)&Ql[qbase + kk * 32 + l4 * 8];
        }
    }

    float m2[4], lp[4];
    f32x4 O[4];
    #pragma unroll
    for (int r = 0; r < 4; ++r) { m2[r] = MINIT; lp[r] = 0.f; }
    #pragma unroll
    for (int df = 0; df < 4; ++df) O[df] = (f32x4){0.f, 0.f, 0.f, 0.f};

    const int NT = (nvb + 63) >> 6;

#define STAGE(KT, SEL)                                                          \
    do {                                                                        \
        gl_lds16(&Kh[((size_t)bh * S_ + (KT) + srow) * 64 + skc * 8],           \
                 &Ks[SEL][(w * 8) * 64]);                                       \
        gl_lds16(&Vt[((size_t)bh * 64 + srow) * (size_t)S_ + (KT) + skc * 8],   \
                 &Vts[SEL][(w * 8) * 64]);                                      \
    } while (0)

    STAGE(0, 0);
    __syncthreads();

    int cur = 0;
    for (int ti = 0; ti < NT; ++ti, cur ^= 1) {
        const int kt = ti * 64;
        if (ti + 1 < NT) STAGE((ti + 1) * 64, cur ^ 1);

        f32x4 s[4];
        #pragma unroll
        for (int nf = 0; nf < 4; ++nf) s[nf] = (f32x4){0.f, 0.f, 0.f, 0.f};
        #pragma unroll
        for (int nf = 0; nf < 4; ++nf) {
            const int krow = nf * 16 + l15;
            #pragma unroll
            for (int kk = 0; kk < 2; ++kk) {
                const int off = krow * 64 + (((kk * 4 + l4) ^ (krow & 7)) << 3);
                const bf16x8 kh8 = *(const bf16x8*)&Ks[cur][off];
                s[nf] = MFMA(qh[kk], kh8, s[nf]);
                s[nf] = MFMA(ql[kk], kh8, s[nf]);
            }
        }

        float addk[4];
        #pragma unroll
        for (int nf = 0; nf < 4; ++nf)
            addk[nf] = (kt + nf * 16 + l15 < nvb) ? 0.f : NEGB;

        float lm[4];
        bool need = false;
        #pragma unroll
        for (int r = 0; r < 4; ++r) {
            float v0 = fmaf(s[0][r], SC2, addk[0]);
            float v1 = fmaf(s[1][r], SC2, addk[1]);
            float v2 = fmaf(s[2][r], SC2, addk[2]);
            float v3 = fmaf(s[3][r], SC2, addk[3]);
            s[0][r] = v0; s[1][r] = v1; s[2][r] = v2; s[3][r] = v3;
            const float rm = fmaxf(fmaxf(v0, v1), fmaxf(v2, v3));
            lm[r] = rm;
            need |= (rm > m2[r] + THR2);
        }

        if (__any(need)) {
            #pragma unroll
            for (int r = 0; r < 4; ++r) {
                float rm = lm[r];
                rm = fmaxf(rm, __shfl_xor(rm, 1));
                rm = fmaxf(rm, __shfl_xor(rm, 2));
                rm = fmaxf(rm, __shfl_xor(rm, 4));
                rm = fmaxf(rm, __shfl_xor(rm, 8));
                const float mnew = fmaxf(m2[r], rm);
                const float sc = fast_exp2(m2[r] - mnew);
                lp[r] *= sc;
                m2[r] = mnew;
                #pragma unroll
                for (int df = 0; df < 4; ++df) O[df][r] *= sc;
            }
        }

        #pragma unroll
        for (int r = 0; r < 4; ++r) {
            const float mm = m2[r];
            const int qq = w * 16 + l4 * 4 + r;
            const int qbase = qq * 72;
            const int qswz = qq & 7;
            float rs = 0.f;
            #pragma unroll
            for (int nf = 0; nf < 4; ++nf) {
                const float pv = fast_exp2(s[nf][r] - mm);
                rs += pv;
                const int key = nf * 16 + l15;
                Psb[qbase + (((key >> 3) ^ qswz) << 3) + (key & 7)] = bf16_rne(pv);
            }
            lp[r] += rs;
        }

        #pragma unroll
        for (int kk = 0; kk < 2; ++kk) {
            const int qq = w * 16 + l15;
            const bf16x8 ph = *(const bf16x8*)
                &Psb[qq * 72 + ((((kk * 4) + l4) ^ (qq & 7)) << 3)];
            #pragma unroll
            for (int df = 0; df < 4; ++df) {
                const int vrow = df * 16 + l15;
                const int off = vrow * 64 + (((kk * 4 + l4) ^ (vrow & 7)) << 3);
                const bf16x8 vb = *(const bf16x8*)&Vts[cur][off];
                O[df] = MFMA(ph, vb, O[df]);
            }
        }

        __syncthreads();
    }
#undef STAGE

    #pragma unroll
    for (int r = 0; r < 4; ++r) {
        float t = lp[r];
        t += __shfl_xor(t, 1);
        t += __shfl_xor(t, 2);
        t += __shfl_xor(t, 4);
        t += __shfl_xor(t, 8);
        const int j = qw + l4 * 4 + r;
        if (j < nvb) {
            const float inv = (t > 0.f) ? 1.f / t : 0.f;
            const size_t base = ((size_t)b * S_ + j) * D_ + (bh & 15) * DH_;
            #pragma unroll
            for (int df = 0; df < 4; ++df) {
                unsigned short vh, vl;
                split2(O[df][r] * inv, vh, vl);
                Mh[base + df * 16 + l15] = vh;
                Ml[base + df * 16 + l15] = vl;
            }
        }
    }
}

// ---------------------------------------------------------------------------
extern "C" void kernel_launch(void* const* d_in, const int* in_sizes, int n_in,
                              void* d_out, int out_size, void* d_ws, size_t ws_size,
                              hipStream_t stream)
{
    const float* x    = (const float*)d_in[0];
    const float* mask = (const float*)d_in[1];
    const float* Wq   = (const float*)d_in[2];
    const float* bq   = (const float*)d_in[3];
    const float* Wk   = (const float*)d_in[4];
    const float* bk   = (const float*)d_in[5];
    const float* Wv   = (const float*)d_in[6];
    const float* bv   = (const float*)d_in[7];
    const float* Wo   = (const float*)d_in[8];
    const float* bo   = (const float*)d_in[9];
    float* out = (float*)d_out;

    char* ws = (char*)d_ws;
    unsigned short* xh = (unsigned short*)(ws);                      // 8MB (later mh)
    unsigned short* xl = (unsigned short*)(ws + ((size_t) 8 << 20)); // 8MB (later ml)
    unsigned short* qh = (unsigned short*)(ws + ((size_t)16 << 20));
    unsigned short* qll= (unsigned short*)(ws + ((size_t)24 << 20));
    unsigned short* kh = (unsigned short*)(ws + ((size_t)32 << 20));
    unsigned short* vt = (unsigned short*)(ws + ((size_t)40 << 20)); // V^T [bh][d][s]
    unsigned short* wc_h = (unsigned short*)(ws + ((size_t)48 << 20)); // 6MB
    unsigned short* wc_l = (unsigned short*)(ws + ((size_t)54 << 20)); // 6MB
    unsigned short* wo_h = wc_h;            // reuse after QKV GEMM
    unsigned short* wo_l = (unsigned short*)(ws + ((size_t)50 << 20));
    unsigned short* mh = xh;                // x dead after QKV GEMM
    unsigned short* ml = xl;
    int* cpos = (int*)(ws + ((size_t)60 << 20));          // 16KB
    int* opos = (int*)(ws + ((size_t)60 << 20) + 16384);  // 16KB
    int* nv   = (int*)(ws + ((size_t)60 << 20) + 32768);  // 8B

    const dim3 blk(256);
    scan_mask<<<dim3(B_), blk, 0, stream>>>(mask, cpos, opos, nv);
    split_x_c<<<dim3(M_), blk, 0, stream>>>(x, mask, cpos, xh, xl);
    tconv_qkv<<<dim3(16, 16, 3), blk, 0, stream>>>(Wq, Wk, Wv, wc_h, wc_l);

    gemm_qkv512<<<dim3(M_ / 128, 3 * D_ / 128), dim3(512), 0, stream>>>(
        xh, xl, wc_h, wc_l, bq, bk, bv, qh, qll, kh, vt, nv);

    tconv_w<<<dim3(16, 16), blk, 0, stream>>>(Wo, wo_h, wo_l, D_, OUT_);

    attn_mfma<<<dim3(B_ * H_, S_ / 128), dim3(512), 0, stream>>>(
        qh, qll, kh, vt, nv, mh, ml);

    fill_out<<<dim3(M_ * OUT_ / 4 / 256), blk, 0, stream>>>(out, bo);

    gemm_out64<<<dim3(M_ / 64, OUT_ / 64), blk, 0, stream>>>(
        mh, ml, wo_h, wo_l, bo, out, nv, opos);
}

// Round 12
// 147.177 us; speedup vs baseline: 7.6464x; 1.0762x over previous
//
#include <hip/hip_runtime.h>
#include <hip/hip_bf16.h>
#include <math.h>

#define B_   2
#define S_   2048
#define H_   16
#define DH_  64
#define D_   1024
#define OUT_ 1024
#define M_   (B_ * S_)   // 4096

typedef __attribute__((ext_vector_type(8))) short bf16x8;
typedef __attribute__((ext_vector_type(4))) float f32x4;
typedef __attribute__((ext_vector_type(4))) short short4v;

#define MFMA(a, b, c) __builtin_amdgcn_mfma_f32_16x16x32_bf16((a), (b), (c), 0, 0, 0)

__device__ __forceinline__ void gl_lds16(const void* g, void* l) {
    __builtin_amdgcn_global_load_lds(
        (const __attribute__((address_space(1))) unsigned int*)g,
        (__attribute__((address_space(3))) unsigned int*)l, 16, 0, 0);
}

__device__ __forceinline__ void split2(float x, unsigned short& h, unsigned short& l) {
    unsigned u = __float_as_uint(x);
    h = (unsigned short)(u >> 16);
    float lo = x - __uint_as_float(u & 0xFFFF0000u);
    l = (unsigned short)(__float_as_uint(lo) >> 16);
}

__device__ __forceinline__ unsigned short bf16_rne(float x) {
    return __builtin_bit_cast(unsigned short, __float2bfloat16(x));
}

__device__ __forceinline__ float fast_exp2(float x) {
#if __has_builtin(__builtin_amdgcn_exp2f)
    return __builtin_amdgcn_exp2f(x);
#else
    return exp2f(x);
#endif
}

// ---------------------------------------------------------------------------
// per-batch prefix sum of mask
// ---------------------------------------------------------------------------
__global__ __launch_bounds__(256)
void scan_mask(const float* __restrict__ mask, int* __restrict__ cpos,
               int* __restrict__ opos, int* __restrict__ nv)
{
    __shared__ int cnt[256];
    const int b = blockIdx.x, tid = threadIdx.x;
    const int base = b * 2048 + tid * 8;
    int mloc = 0, c = 0;
    #pragma unroll
    for (int i = 0; i < 8; ++i) {
        const int v = (mask[base + i] != 0.f) ? 1 : 0;
        mloc |= v << i;
        c += v;
    }
    cnt[tid] = c;
    __syncthreads();
    for (int off = 1; off < 256; off <<= 1) {
        const int v = cnt[tid];
        const int add = (tid >= off) ? cnt[tid - off] : 0;
        __syncthreads();
        cnt[tid] = v + add;
        __syncthreads();
    }
    int excl = cnt[tid] - c;
    #pragma unroll
    for (int i = 0; i < 8; ++i) {
        cpos[base + i] = excl;
        if ((mloc >> i) & 1) {
            opos[b * 2048 + excl] = tid * 8 + i;
            ++excl;
        }
    }
    if (tid == 255) nv[b] = cnt[255];
}

// ---------------------------------------------------------------------------
__global__ __launch_bounds__(256)
void split_x_c(const float* __restrict__ X, const float* __restrict__ mask,
               const int* __restrict__ cpos,
               unsigned short* __restrict__ Xh, unsigned short* __restrict__ Xl)
{
    const int row = blockIdx.x;            // 0..4095
    const int b = row >> 11, s = row & 2047;
    if (mask[(size_t)b * 2048 + s] == 0.f) return;
    const int cr = b * 2048 + cpos[b * 2048 + s];
    const int c4 = threadIdx.x * 4;
    const float4 v = *(const float4*)&X[(size_t)row * D_ + c4];
    unsigned short h[4], l[4];
    split2(v.x, h[0], l[0]); split2(v.y, h[1], l[1]);
    split2(v.z, h[2], l[2]); split2(v.w, h[3], l[3]);
    *(short4v*)&Xh[(size_t)cr * D_ + c4] =
        (short4v){(short)h[0],(short)h[1],(short)h[2],(short)h[3]};
    *(short4v*)&Xl[(size_t)cr * D_ + c4] =
        (short4v){(short)l[0],(short)l[1],(short)l[2],(short)l[3]};
}

// ---------------------------------------------------------------------------
__global__ __launch_bounds__(256)
void fill_out(float* __restrict__ out, const float* __restrict__ bo)
{
    const int i = blockIdx.x * 256 + threadIdx.x;   // float4 index
    ((float4*)out)[i] = ((const float4*)bo)[i & 255];
}

// ---------------------------------------------------------------------------
__global__ __launch_bounds__(256)
void tconv_w(const float* __restrict__ W, unsigned short* __restrict__ Th,
             unsigned short* __restrict__ Tl, int K, int N)
{
    __shared__ float T[64][65];
    const int tid = threadIdx.x;
    const int k0 = blockIdx.x * 64, n0 = blockIdx.y * 64;
    #pragma unroll
    for (int p = 0; p < 4; ++p) {
        const int f = p * 256 + tid;
        const int r = f >> 4, c4 = (f & 15) << 2;
        const float4 v = *(const float4*)&W[(size_t)(k0 + r) * N + n0 + c4];
        T[r][c4] = v.x; T[r][c4 + 1] = v.y; T[r][c4 + 2] = v.z; T[r][c4 + 3] = v.w;
    }
    __syncthreads();
    #pragma unroll
    for (int p = 0; p < 4; ++p) {
        const int f = p * 256 + tid;
        const int r = f >> 4, c4 = (f & 15) << 2;
        unsigned short h[4], l[4];
        #pragma unroll
        for (int i = 0; i < 4; ++i) split2(T[c4 + i][r], h[i], l[i]);
        *(short4v*)&Th[(size_t)(n0 + r) * K + k0 + c4] =
            (short4v){(short)h[0],(short)h[1],(short)h[2],(short)h[3]};
        *(short4v*)&Tl[(size_t)(n0 + r) * K + k0 + c4] =
            (short4v){(short)l[0],(short)l[1],(short)l[2],(short)l[3]};
    }
}

__global__ __launch_bounds__(256)
void tconv_qkv(const float* __restrict__ W0, const float* __restrict__ W1,
               const float* __restrict__ W2, unsigned short* __restrict__ Th,
               unsigned short* __restrict__ Tl)
{
    __shared__ float T[64][65];
    const int z = blockIdx.z;
    const float* W = (z == 0) ? W0 : (z == 1) ? W1 : W2;
    unsigned short* th = Th + ((size_t)z << 20);
    unsigned short* tl = Tl + ((size_t)z << 20);
    const int tid = threadIdx.x;
    const int k0 = blockIdx.x * 64, n0 = blockIdx.y * 64;
    #pragma unroll
    for (int p = 0; p < 4; ++p) {
        const int f = p * 256 + tid;
        const int r = f >> 4, c4 = (f & 15) << 2;
        const float4 v = *(const float4*)&W[(size_t)(k0 + r) * D_ + n0 + c4];
        T[r][c4] = v.x; T[r][c4 + 1] = v.y; T[r][c4 + 2] = v.z; T[r][c4 + 3] = v.w;
    }
    __syncthreads();
    #pragma unroll
    for (int p = 0; p < 4; ++p) {
        const int f = p * 256 + tid;
        const int r = f >> 4, c4 = (f & 15) << 2;
        unsigned short h[4], l[4];
        #pragma unroll
        for (int i = 0; i < 4; ++i) split2(T[c4 + i][r], h[i], l[i]);
        *(short4v*)&th[(size_t)(n0 + r) * D_ + k0 + c4] =
            (short4v){(short)h[0],(short)h[1],(short)h[2],(short)h[3]};
        *(short4v*)&tl[(size_t)(n0 + r) * D_ + k0 + c4] =
            (short4v){(short)l[0],(short)l[1],(short)l[2],(short)l[3]};
    }
}

// ---------------------------------------------------------------------------
// QKV GEMM, BM=128 BN=64, 256 thr / 4 waves, wave tile 64x32 (acc 4x2).
// 768 active blocks -> 3 blocks/CU (the round-9 occupancy that hit ~966 TF).
// Q cols: 3-term split. K/V cols: 2-term (A-lo neither staged nor used).
// ---------------------------------------------------------------------------
__global__ __launch_bounds__(256, 3)
void gemm_qkv(const unsigned short* __restrict__ Ah, const unsigned short* __restrict__ Al,
              const unsigned short* __restrict__ Bh, const unsigned short* __restrict__ Bl,
              const float* __restrict__ bq, const float* __restrict__ bk,
              const float* __restrict__ bv,
              unsigned short* __restrict__ Oqh, unsigned short* __restrict__ Oql,
              unsigned short* __restrict__ Okh, unsigned short* __restrict__ Ovt,
              const int* __restrict__ nv)
{
    const int m0 = blockIdx.x * 128, n0 = blockIdx.y * 64;
    const int bb = m0 >> 11;
    const int nvb = nv[bb];
    if ((m0 & 2047) >= nvb) return;

    __shared__ unsigned short As_h[128 * 64], As_l[128 * 64];
    __shared__ unsigned short Bs_h[64 * 64],  Bs_l[64 * 64];

    const int tid = threadIdx.x;
    const int lane = tid & 63, w = tid >> 6;
    const int wm = w >> 1, wn = w & 1;          // 2x2 wave grid, 64x32 each
    const int l15 = lane & 15, l4 = lane >> 4;
    const int lr = lane >> 3, lc = lane & 7;
    const int idx = n0 >> 10;                   // 0=Q 1=K 2=V

    f32x4 acc[4][2];
    #pragma unroll
    for (int i = 0; i < 4; ++i)
        #pragma unroll
        for (int j = 0; j < 2; ++j) acc[i][j] = (f32x4){0.f, 0.f, 0.f, 0.f};

    for (int kt = 0; kt < D_; kt += 64) {
        __syncthreads();
        #pragma unroll
        for (int t = 0; t < 4; ++t) {           // A: 128 rows, wave covers 32
            const int row = w * 32 + t * 8 + lr;
            const int kc = lc ^ (row & 7);
            const size_t g = (size_t)(m0 + row) * D_ + kt + kc * 8;
            gl_lds16(&Ah[g], &As_h[(w * 32 + t * 8) * 64]);
            if (idx == 0)                        // A-lo only needed for Q
                gl_lds16(&Al[g], &As_l[(w * 32 + t * 8) * 64]);
        }
        #pragma unroll
        for (int t = 0; t < 2; ++t) {           // B: 64 rows, wave covers 16
            const int row = w * 16 + t * 8 + lr;
            const int kc = lc ^ (row & 7);
            const size_t g = (size_t)(n0 + row) * D_ + kt + kc * 8;
            gl_lds16(&Bh[g], &Bs_h[(w * 16 + t * 8) * 64]);
            gl_lds16(&Bl[g], &Bs_l[(w * 16 + t * 8) * 64]);
        }
        __syncthreads();

        #pragma unroll
        for (int kk = 0; kk < 2; ++kk) {
            bf16x8 ah[4], bh2[2], bl2[2];
            #pragma unroll
            for (int i = 0; i < 4; ++i) {
                const int row = wm * 64 + i * 16 + l15;
                const int off = row * 64 + (((kk * 4 + l4) ^ (row & 7)) << 3);
                ah[i] = *(const bf16x8*)&As_h[off];
            }
            #pragma unroll
            for (int j = 0; j < 2; ++j) {
                const int row = wn * 32 + j * 16 + l15;
                const int off = row * 64 + (((kk * 4 + l4) ^ (row & 7)) << 3);
                bh2[j] = *(const bf16x8*)&Bs_h[off];
                bl2[j] = *(const bf16x8*)&Bs_l[off];
            }
            #pragma unroll
            for (int i = 0; i < 4; ++i)
                #pragma unroll
                for (int j = 0; j < 2; ++j) {
                    acc[i][j] = MFMA(ah[i], bh2[j], acc[i][j]);
                    acc[i][j] = MFMA(ah[i], bl2[j], acc[i][j]);
                }
            if (idx == 0) {   // Q: 3rd term with A-lo
                #pragma unroll
                for (int i = 0; i < 4; ++i) {
                    const int row = wm * 64 + i * 16 + l15;
                    const int off = row * 64 + (((kk * 4 + l4) ^ (row & 7)) << 3);
                    const bf16x8 al = *(const bf16x8*)&As_l[off];
                    #pragma unroll
                    for (int j = 0; j < 2; ++j)
                        acc[i][j] = MFMA(al, bh2[j], acc[i][j]);
                }
            }
        }
    }

    const float* bp = (idx == 0) ? bq : (idx == 1) ? bk : bv;
    #pragma unroll
    for (int i = 0; i < 4; ++i) {
        const int m = m0 + wm * 64 + i * 16 + l4 * 4;
        const int jm = m & 2047;
        #pragma unroll
        for (int j = 0; j < 2; ++j) {
            const int nG = n0 + wn * 32 + j * 16 + l15;
            const int c = nG & 1023;
            const float bvv = bp[c];
            const int hh = c >> 6, dd = c & 63;
            if (idx == 0) {
                const size_t base = ((size_t)(bb * H_ + hh) * S_ + jm) * 64 + dd;
                #pragma unroll
                for (int r = 0; r < 4; ++r)
                    if (jm + r < nvb) {
                        unsigned short vh, vl;
                        split2(acc[i][j][r] + bvv, vh, vl);
                        Oqh[base + (size_t)r * 64] = vh;
                        Oql[base + (size_t)r * 64] = vl;
                    }
            } else if (idx == 1) {
                const size_t base = ((size_t)(bb * H_ + hh) * S_ + jm) * 64 + dd;
                #pragma unroll
                for (int r = 0; r < 4; ++r)
                    if (jm + r < nvb)
                        Okh[base + (size_t)r * 64] = bf16_rne(acc[i][j][r] + bvv);
            } else {
                unsigned short pv[4];
                #pragma unroll
                for (int r = 0; r < 4; ++r) pv[r] = bf16_rne(acc[i][j][r] + bvv);
                const size_t vb = ((size_t)(bb * H_ + hh) * 64 + dd) * (size_t)S_ + jm;
                if (jm + 3 < nvb) {
                    *(short4v*)&Ovt[vb] =
                        (short4v){(short)pv[0],(short)pv[1],(short)pv[2],(short)pv[3]};
                } else {
                    #pragma unroll
                    for (int r = 0; r < 4; ++r)
                        if (jm + r < nvb) Ovt[vb + r] = pv[r];
                }
            }
        }
    }
}

// ---------------------------------------------------------------------------
// Output GEMM, 64x64 tile, 4 waves, wave 32x32, 3-term. Scatter via opos.
// ---------------------------------------------------------------------------
__global__ __launch_bounds__(256, 4)
void gemm_out64(const unsigned short* __restrict__ Ah, const unsigned short* __restrict__ Al,
                const unsigned short* __restrict__ Bh, const unsigned short* __restrict__ Bl,
                const float* __restrict__ bias, float* __restrict__ Cf,
                const int* __restrict__ nv, const int* __restrict__ opos)
{
    const int m0 = blockIdx.x * 64, n0 = blockIdx.y * 64;
    const int bb = m0 >> 11;
    const int nvb = nv[bb];
    if ((m0 & 2047) >= nvb) return;

    __shared__ unsigned short As_h[64 * 64], As_l[64 * 64];
    __shared__ unsigned short Bs_h[64 * 64], Bs_l[64 * 64];

    const int tid = threadIdx.x;
    const int lane = tid & 63, w = tid >> 6;
    const int wm = w >> 1, wn = w & 1;                // 2x2 wave grid, 32x32 each
    const int l15 = lane & 15, l4 = lane >> 4;
    const int lr = lane >> 3, lc = lane & 7;

    f32x4 acc[2][2];
    #pragma unroll
    for (int i = 0; i < 2; ++i)
        #pragma unroll
        for (int j = 0; j < 2; ++j) acc[i][j] = (f32x4){0.f, 0.f, 0.f, 0.f};

    for (int kt = 0; kt < D_; kt += 64) {
        __syncthreads();
        #pragma unroll
        for (int t = 0; t < 2; ++t) {
            const int row = w * 16 + t * 8 + lr;
            const int kc = lc ^ (row & 7);
            const size_t ga = (size_t)(m0 + row) * D_ + kt + kc * 8;
            gl_lds16(&Ah[ga], &As_h[(w * 16 + t * 8) * 64]);
            gl_lds16(&Al[ga], &As_l[(w * 16 + t * 8) * 64]);
            const size_t gb = (size_t)(n0 + row) * D_ + kt + kc * 8;
            gl_lds16(&Bh[gb], &Bs_h[(w * 16 + t * 8) * 64]);
            gl_lds16(&Bl[gb], &Bs_l[(w * 16 + t * 8) * 64]);
        }
        __syncthreads();

        #pragma unroll
        for (int kk = 0; kk < 2; ++kk) {
            bf16x8 ah[2], al[2], bh2[2], bl2[2];
            #pragma unroll
            for (int i = 0; i < 2; ++i) {
                const int row = wm * 32 + i * 16 + l15;
                const int off = row * 64 + (((kk * 4 + l4) ^ (row & 7)) << 3);
                ah[i] = *(const bf16x8*)&As_h[off];
                al[i] = *(const bf16x8*)&As_l[off];
            }
            #pragma unroll
            for (int j = 0; j < 2; ++j) {
                const int row = wn * 32 + j * 16 + l15;
                const int off = row * 64 + (((kk * 4 + l4) ^ (row & 7)) << 3);
                bh2[j] = *(const bf16x8*)&Bs_h[off];
                bl2[j] = *(const bf16x8*)&Bs_l[off];
            }
            #pragma unroll
            for (int i = 0; i < 2; ++i)
                #pragma unroll
                for (int j = 0; j < 2; ++j) {
                    acc[i][j] = MFMA(ah[i], bh2[j], acc[i][j]);
                    acc[i][j] = MFMA(ah[i], bl2[j], acc[i][j]);
                    acc[i][j] = MFMA(al[i], bh2[j], acc[i][j]);
                }
        }
    }

    const int* op = opos + bb * 2048;
    #pragma unroll
    for (int i = 0; i < 2; ++i) {
        const int m = m0 + wm * 32 + i * 16 + l4 * 4;
        #pragma unroll
        for (int j = 0; j < 2; ++j) {
            const int n = n0 + wn * 32 + j * 16 + l15;
            const float bvv = bias[n];
            #pragma unroll
            for (int r = 0; r < 4; ++r) {
                const int jr = (m & 2047) + r;
                if (jr < nvb)
                    Cf[((size_t)bb * 2048 + op[jr]) * OUT_ + n] = acc[i][j][r] + bvv;
            }
        }
    }
}

// ---------------------------------------------------------------------------
// Flash attention on COMPACTED q/k. 8 waves x 16 q-rows, 2-phase dbuf.
// ---------------------------------------------------------------------------
__global__ __launch_bounds__(512, 4)
void attn_mfma(const unsigned short* __restrict__ Qh, const unsigned short* __restrict__ Ql,
               const unsigned short* __restrict__ Kh, const unsigned short* __restrict__ Vt,
               const int* __restrict__ nv,
               unsigned short* __restrict__ Mh, unsigned short* __restrict__ Ml)
{
    const int bh = blockIdx.x, b = bh >> 4;
    const int nvb = nv[b];
    const int q0 = blockIdx.y * 128;
    if (q0 >= nvb) return;

    __shared__ unsigned short Ks[2][64 * 64];
    __shared__ unsigned short Vts[2][64 * 64];
    __shared__ unsigned short Psb[128 * 72];

    const float SC2  = 0.125f * 1.4426950408889634f;
    const float THR2 = 11.5415603f;
    const float MINIT = -1e5f;
    const float NEGB  = -1e30f;

    const int tid = threadIdx.x;
    const int lane = tid & 63, w = tid >> 6;
    const int l15 = lane & 15, l4 = lane >> 4;
    const int qw = q0 + w * 16;

    const int srow = w * 8 + (lane >> 3);
    const int skc  = (lane & 7) ^ (srow & 7);

    bf16x8 qh[2], ql[2];
    {
        const int qr = min(qw + l15, nvb - 1);
        const size_t qbase = ((size_t)bh * S_ + qr) * 64;
        #pragma unroll
        for (int kk = 0; kk < 2; ++kk) {
            qh[kk] = *(const bf16x8*)&Qh[qbase + kk * 32 + l4 * 8];
            ql[kk] = *(const bf16x8*)&Ql[qbase + kk * 32 + l4 * 8];
        }
    }

    float m2[4], lp[4];
    f32x4 O[4];
    #pragma unroll
    for (int r = 0; r < 4; ++r) { m2[r] = MINIT; lp[r] = 0.f; }
    #pragma unroll
    for (int df = 0; df < 4; ++df) O[df] = (f32x4){0.f, 0.f, 0.f, 0.f};

    const int NT = (nvb + 63) >> 6;

#define STAGE(KT, SEL)                                                          \
    do {                                                                        \
        gl_lds16(&Kh[((size_t)bh * S_ + (KT) + srow) * 64 + skc * 8],           \
                 &Ks[SEL][(w * 8) * 64]);                                       \
        gl_lds16(&Vt[((size_t)bh * 64 + srow) * (size_t)S_ + (KT) + skc * 8],   \
                 &Vts[SEL][(w * 8) * 64]);                                      \
    } while (0)

    STAGE(0, 0);
    __syncthreads();

    int cur = 0;
    for (int ti = 0; ti < NT; ++ti, cur ^= 1) {
        const int kt = ti * 64;
        if (ti + 1 < NT) STAGE((ti + 1) * 64, cur ^ 1);

        f32x4 s[4];
        #pragma unroll
        for (int nf = 0; nf < 4; ++nf) s[nf] = (f32x4){0.f, 0.f, 0.f, 0.f};
        #pragma unroll
        for (int nf = 0; nf < 4; ++nf) {
            const int krow = nf * 16 + l15;
            #pragma unroll
            for (int kk = 0; kk < 2; ++kk) {
                const int off = krow * 64 + (((kk * 4 + l4) ^ (krow & 7)) << 3);
                const bf16x8 kh8 = *(const bf16x8*)&Ks[cur][off];
                s[nf] = MFMA(qh[kk], kh8, s[nf]);
                s[nf] = MFMA(ql[kk], kh8, s[nf]);
            }
        }

        float addk[4];
        #pragma unroll
        for (int nf = 0; nf < 4; ++nf)
            addk[nf] = (kt + nf * 16 + l15 < nvb) ? 0.f : NEGB;

        float lm[4];
        bool need = false;
        #pragma unroll
        for (int r = 0; r < 4; ++r) {
            float v0 = fmaf(s[0][r], SC2, addk[0]);
            float v1 = fmaf(s[1][r], SC2, addk[1]);
            float v2 = fmaf(s[2][r], SC2, addk[2]);
            float v3 = fmaf(s[3][r], SC2, addk[3]);
            s[0][r] = v0; s[1][r] = v1; s[2][r] = v2; s[3][r] = v3;
            const float rm = fmaxf(fmaxf(v0, v1), fmaxf(v2, v3));
            lm[r] = rm;
            need |= (rm > m2[r] + THR2);
        }

        if (__any(need)) {
            #pragma unroll
            for (int r = 0; r < 4; ++r) {
                float rm = lm[r];
                rm = fmaxf(rm, __shfl_xor(rm, 1));
                rm = fmaxf(rm, __shfl_xor(rm, 2));
                rm = fmaxf(rm, __shfl_xor(rm, 4));
                rm = fmaxf(rm, __shfl_xor(rm, 8));
                const float mnew = fmaxf(m2[r], rm);
                const float sc = fast_exp2(m2[r] - mnew);
                lp[r] *= sc;
                m2[r] = mnew;
                #pragma unroll
                for (int df = 0; df < 4; ++df) O[df][r] *= sc;
            }
        }

        #pragma unroll
        for (int r = 0; r < 4; ++r) {
            const float mm = m2[r];
            const int qq = w * 16 + l4 * 4 + r;
            const int qbase = qq * 72;
            const int qswz = qq & 7;
            float rs = 0.f;
            #pragma unroll
            for (int nf = 0; nf < 4; ++nf) {
                const float pv = fast_exp2(s[nf][r] - mm);
                rs += pv;
                const int key = nf * 16 + l15;
                Psb[qbase + (((key >> 3) ^ qswz) << 3) + (key & 7)] = bf16_rne(pv);
            }
            lp[r] += rs;
        }

        #pragma unroll
        for (int kk = 0; kk < 2; ++kk) {
            const int qq = w * 16 + l15;
            const bf16x8 ph = *(const bf16x8*)
                &Psb[qq * 72 + ((((kk * 4) + l4) ^ (qq & 7)) << 3)];
            #pragma unroll
            for (int df = 0; df < 4; ++df) {
                const int vrow = df * 16 + l15;
                const int off = vrow * 64 + (((kk * 4 + l4) ^ (vrow & 7)) << 3);
                const bf16x8 vb = *(const bf16x8*)&Vts[cur][off];
                O[df] = MFMA(ph, vb, O[df]);
            }
        }

        __syncthreads();
    }
#undef STAGE

    #pragma unroll
    for (int r = 0; r < 4; ++r) {
        float t = lp[r];
        t += __shfl_xor(t, 1);
        t += __shfl_xor(t, 2);
        t += __shfl_xor(t, 4);
        t += __shfl_xor(t, 8);
        const int j = qw + l4 * 4 + r;
        if (j < nvb) {
            const float inv = (t > 0.f) ? 1.f / t : 0.f;
            const size_t base = ((size_t)b * S_ + j) * D_ + (bh & 15) * DH_;
            #pragma unroll
            for (int df = 0; df < 4; ++df) {
                unsigned short vh, vl;
                split2(O[df][r] * inv, vh, vl);
                Mh[base + df * 16 + l15] = vh;
                Ml[base + df * 16 + l15] = vl;
            }
        }
    }
}

// ---------------------------------------------------------------------------
extern "C" void kernel_launch(void* const* d_in, const int* in_sizes, int n_in,
                              void* d_out, int out_size, void* d_ws, size_t ws_size,
                              hipStream_t stream)
{
    const float* x    = (const float*)d_in[0];
    const float* mask = (const float*)d_in[1];
    const float* Wq   = (const float*)d_in[2];
    const float* bq   = (const float*)d_in[3];
    const float* Wk   = (const float*)d_in[4];
    const float* bk   = (const float*)d_in[5];
    const float* Wv   = (const float*)d_in[6];
    const float* bv   = (const float*)d_in[7];
    const float* Wo   = (const float*)d_in[8];
    const float* bo   = (const float*)d_in[9];
    float* out = (float*)d_out;

    char* ws = (char*)d_ws;
    unsigned short* xh = (unsigned short*)(ws);                      // 8MB (later mh)
    unsigned short* xl = (unsigned short*)(ws + ((size_t) 8 << 20)); // 8MB (later ml)
    unsigned short* qh = (unsigned short*)(ws + ((size_t)16 << 20));
    unsigned short* qll= (unsigned short*)(ws + ((size_t)24 << 20));
    unsigned short* kh = (unsigned short*)(ws + ((size_t)32 << 20));
    unsigned short* vt = (unsigned short*)(ws + ((size_t)40 << 20)); // V^T [bh][d][s]
    unsigned short* wc_h = (unsigned short*)(ws + ((size_t)48 << 20)); // 6MB
    unsigned short* wc_l = (unsigned short*)(ws + ((size_t)54 << 20)); // 6MB
    unsigned short* wo_h = wc_h;            // reuse after QKV GEMM
    unsigned short* wo_l = (unsigned short*)(ws + ((size_t)50 << 20));
    unsigned short* mh = xh;                // x dead after QKV GEMM
    unsigned short* ml = xl;
    int* cpos = (int*)(ws + ((size_t)60 << 20));          // 16KB
    int* opos = (int*)(ws + ((size_t)60 << 20) + 16384);  // 16KB
    int* nv   = (int*)(ws + ((size_t)60 << 20) + 32768);  // 8B

    const dim3 blk(256);
    scan_mask<<<dim3(B_), blk, 0, stream>>>(mask, cpos, opos, nv);
    split_x_c<<<dim3(M_), blk, 0, stream>>>(x, mask, cpos, xh, xl);
    tconv_qkv<<<dim3(16, 16, 3), blk, 0, stream>>>(Wq, Wk, Wv, wc_h, wc_l);

    gemm_qkv<<<dim3(M_ / 128, 3 * D_ / 64), blk, 0, stream>>>(
        xh, xl, wc_h, wc_l, bq, bk, bv, qh, qll, kh, vt, nv);

    tconv_w<<<dim3(16, 16), blk, 0, stream>>>(Wo, wo_h, wo_l, D_, OUT_);

    attn_mfma<<<dim3(B_ * H_, S_ / 128), dim3(512), 0, stream>>>(
        qh, qll, kh, vt, nv, mh, ml);

    fill_out<<<dim3(M_ * OUT_ / 4 / 256), blk, 0, stream>>>(out, bo);

    gemm_out64<<<dim3(M_ / 64, OUT_ / 64), blk, 0, stream>>>(
        mh, ml, wo_h, wo_l, bo, out, nv, opos);
}